// Round 4
// baseline (518.849 us; speedup 1.0000x reference)
//
#include <hip/hip_runtime.h>
#include <hip/hip_bf16.h>
#include <stdint.h>

// ---------------- problem constants (fixed by setup_inputs) ----------------
#define NHD   12        // heads
#define NPT   4         // points
#define CDIM  768
#define HDIM  64
#define NLVL  3
#define LQ    4096
#define NB    4
#define LIN   21504     // 128*128 + 64*64 + 32*32
#define MQ    (NB*LQ)   // 16384 query rows
#define MF    (NB*LIN)  // 86016 feat rows
#define SO_N    288
#define SO_NPAD 384
#define AW_N    144
#define AW_NPAD 256

typedef __bf16 bfx8 __attribute__((ext_vector_type(8)));
typedef float  f32x4 __attribute__((ext_vector_type(4)));

__device__ __forceinline__ ushort f2bf(float x) {
  union { float f; uint32_t u; } v; v.f = x;
  uint32_t r = v.u + 0x7fffu + ((v.u >> 16) & 1u);   // RNE
  return (ushort)(r >> 16);
}

// ---------------- weight transpose + cast:  Wt[n][k] = bf16(W[k][n]) -------
__global__ void transpose_cast(const float* __restrict__ W, ushort* __restrict__ Wt,
                               int K, int Nsrc, int Npad) {
  int t = blockIdx.x * 256 + threadIdx.x;
  if (t >= Npad * K) return;
  int n = t / K, k = t - n * K;
  Wt[t] = (n < Nsrc) ? f2bf(W[(size_t)k * Nsrc + n]) : (ushort)0;
}

__global__ void pad_bias(const float* __restrict__ src, float* __restrict__ dst,
                         int nReal, int nPad) {
  int i = blockIdx.x * 256 + threadIdx.x;
  if (i < nPad) dst[i] = (i < nReal) ? src[i] : 0.f;
}

// ---------------- LayerNorm + cast to bf16 (one block per row) -------------
__global__ __launch_bounds__(192) void ln_cast(const float* __restrict__ x,
                                               const float* __restrict__ w,
                                               const float* __restrict__ b,
                                               ushort* __restrict__ y) {
  const int row = blockIdx.x;
  const int tid = threadIdx.x;                  // 192 threads * float4 = 768
  const float4 v = ((const float4*)(x + (size_t)row * CDIM))[tid];
  float s1 = v.x + v.y + v.z + v.w;
  float s2 = v.x*v.x + v.y*v.y + v.z*v.z + v.w*v.w;
#pragma unroll
  for (int o = 32; o > 0; o >>= 1) { s1 += __shfl_down(s1, o); s2 += __shfl_down(s2, o); }
  __shared__ float r1[3], r2[3];
  const int lane = tid & 63, wv = tid >> 6;
  if (lane == 0) { r1[wv] = s1; r2[wv] = s2; }
  __syncthreads();
  s1 = r1[0] + r1[1] + r1[2];
  s2 = r2[0] + r2[1] + r2[2];
  const float mu = s1 * (1.f / CDIM);
  const float rs = rsqrtf(s2 * (1.f / CDIM) - mu * mu + 1e-6f);
  const float4 w4 = ((const float4*)w)[tid];
  const float4 b4 = ((const float4*)b)[tid];
  ushort4 o4;
  o4.x = f2bf((v.x - mu) * rs * w4.x + b4.x);
  o4.y = f2bf((v.y - mu) * rs * w4.y + b4.y);
  o4.z = f2bf((v.z - mu) * rs * w4.z + b4.z);
  o4.w = f2bf((v.w - mu) * rs * w4.w + b4.w);
  ((ushort4*)(y + (size_t)row * CDIM))[tid] = o4;
}

// ====================== 8-phase 256x256 bf16 GEMM ===========================
// C[M][N] = A[M][K] * Wt[N][K]^T + bias. 512 threads = 8 waves (2M x 4N),
// per-wave 128x64 output. BK=64, LDS = 2 bufs x (A 256x64 + B 256x64) bf16
// = 128 KiB. Per K-tile: 4 phases, each {ds_read subtile || stage 1 half-tile
// -> s_barrier -> setprio(1) + 16 MFMA + setprio(0) -> [vmcnt(0) @p3] barrier}.
// LDS XOR-swizzle (T2): 16B-slot g at row r holds global slot g^(r&7); reader
// XORs the same -> 2-way (free) bank aliasing instead of 16-way.
// Stage order per tile: A-half0, A-half1 (HBM, long cover), B0, B1 (L2-hot).
// MODE 0: bf16 store. MODE 2: f32, out = resid + gamma*(acc+bias).
template<int MODE>
__global__ __launch_bounds__(512, 2) void gemm8_bt(
    const ushort* __restrict__ A, const ushort* __restrict__ Wt,
    const float* __restrict__ bias, void* __restrict__ Cout,
    int M, int N, int K, int nTN,
    const float* __restrict__ resid, const float* __restrict__ gammav)
{
  __shared__ __align__(16) ushort lds[2][32768];   // 128 KiB

  int bid = blockIdx.x;
  const int nwg = gridDim.x;
  if ((nwg & 7) == 0) {                 // XCD-chunked swizzle (bijective)
    const int chunk = nwg >> 3;
    bid = (bid & 7) * chunk + (bid >> 3);
  }
  const int mt = bid / nTN, ntl = bid - mt * nTN;
  const int m0 = mt * 256, n0 = ntl * 256;
  const int tid  = threadIdx.x;
  const int lane = tid & 63, wid = tid >> 6;
  const int wm = wid >> 2, wn = wid & 3;           // 2x4 wave grid
  const int lr = lane & 15, lk = lane >> 4;

  f32x4 acc[8][4] = {};

  // half h of K-tile kt -> buf. h: 0=A rows 0-127, 1=A rows 128-255, 2=B0, 3=B1
  auto stage_half = [&](int kt, int h, int buf) {
    const int k0 = kt * 64;
    const ushort* srcM = (h < 2) ? A : Wt;
    const int base0 = (h < 2) ? m0 : n0;
    const int rowoff = (h & 1) * 128;
    ushort* dst0 = &lds[buf][(h >= 2 ? 16384 : 0) + rowoff * 64];
#pragma unroll
    for (int it = 0; it < 2; ++it) {
      const int c = it * 512 + tid;               // 16B chunk id in half-tile
      const int row = c >> 3, g = c & 7;
      const ushort* src = srcM + (size_t)(base0 + rowoff + row) * K
                               + k0 + ((g ^ (row & 7)) << 3);   // pre-swizzled src
      ushort* dst = dst0 + (it * 512 + wid * 64) * 8;           // wave-uniform base
      __builtin_amdgcn_global_load_lds(
          (const __attribute__((address_space(1))) uint32_t*)src,
          (__attribute__((address_space(3))) uint32_t*)dst, 16, 0, 0);
    }
  };
  // swizzled ds_read of one bf16x8 fragment
  auto rdA = [&](int buf, int m, int kk) -> bfx8 {
    const int row = wm * 128 + m * 16 + lr;
    const int col = (kk * 32 + lk * 8) ^ ((lr & 7) * 8);
    return *(const bfx8*)&lds[buf][row * 64 + col];
  };
  auto rdB = [&](int buf, int n, int kk) -> bfx8 {
    const int row = wn * 64 + n * 16 + lr;
    const int col = (kk * 32 + lk * 8) ^ ((lr & 7) * 8);
    return *(const bfx8*)&lds[buf][16384 + row * 64 + col];
  };

  // prologue: tile 0 fully staged into buf 0
  stage_half(0, 0, 0); stage_half(0, 1, 0); stage_half(0, 2, 0); stage_half(0, 3, 0);
  asm volatile("s_waitcnt vmcnt(0)" ::: "memory");
  __builtin_amdgcn_s_barrier();
  asm volatile("" ::: "memory");

  const int nk = K >> 6;                           // K-tiles of 64
  bfx8 bfr[4][2];
  for (int t = 0; t < nk; ++t) {
    const int cur = t & 1;
#pragma unroll
    for (int p = 0; p < 4; ++p) {
      bfx8 afr[2][2];
      if (p == 0) {
#pragma unroll
        for (int n = 0; n < 4; ++n) { bfr[n][0] = rdB(cur, n, 0); bfr[n][1] = rdB(cur, n, 1); }
      }
#pragma unroll
      for (int mm = 0; mm < 2; ++mm) {
        afr[mm][0] = rdA(cur, p * 2 + mm, 0);
        afr[mm][1] = rdA(cur, p * 2 + mm, 1);
      }
      if (t + 1 < nk) stage_half(t + 1, p, cur ^ 1);
      __builtin_amdgcn_s_barrier();
      asm volatile("" ::: "memory");
      __builtin_amdgcn_s_setprio(1);
#pragma unroll
      for (int mm = 0; mm < 2; ++mm)
#pragma unroll
        for (int n = 0; n < 4; ++n) {
          acc[p*2+mm][n] = __builtin_amdgcn_mfma_f32_16x16x32_bf16(afr[mm][0], bfr[n][0], acc[p*2+mm][n], 0, 0, 0);
          acc[p*2+mm][n] = __builtin_amdgcn_mfma_f32_16x16x32_bf16(afr[mm][1], bfr[n][1], acc[p*2+mm][n], 0, 0, 0);
        }
      __builtin_amdgcn_s_setprio(0);
      if (p == 3) asm volatile("s_waitcnt vmcnt(0)" ::: "memory");  // once per K-tile
      __builtin_amdgcn_s_barrier();
      asm volatile("" ::: "memory");
    }
  }

  // epilogue (same verified D layout: row = +lk*4+i, col = +lr)
#pragma unroll
  for (int n = 0; n < 4; ++n) {
    const int col = n0 + wn * 64 + n * 16 + lr;
    const float bcol = bias[col];
    float gcol = 0.f;
    if constexpr (MODE == 2) gcol = gammav[col];
#pragma unroll
    for (int m = 0; m < 8; ++m) {
      const int rbase = m0 + wm * 128 + m * 16 + lk * 4;
#pragma unroll
      for (int i = 0; i < 4; ++i) {
        const size_t o = (size_t)(rbase + i) * N + col;
        const float v = acc[m][n][i] + bcol;
        if constexpr (MODE == 0)      ((ushort*)Cout)[o] = f2bf(v);
        else                          ((float*)Cout)[o]  = resid[o] + gcol * v;
      }
    }
  }
}

// ---------------- 2-phase 128x128 GEMM (small-N: so/aw) --------------------
// MODE 1: store f32.
template<int MODE>
__global__ __launch_bounds__(256) void gemm_bt(
    const ushort* __restrict__ A, const ushort* __restrict__ Wt,
    const float* __restrict__ bias, void* __restrict__ Cout,
    int M, int N, int K, int nTN,
    const float* __restrict__ resid, const float* __restrict__ gammav)
{
  int bid = blockIdx.x;
  const int nwg = gridDim.x;
  if ((nwg & 7) == 0) {
    const int chunk = nwg >> 3;
    bid = (bid & 7) * chunk + (bid >> 3);
  }
  const int mt = bid / nTN;
  const int nt = bid - mt * nTN;
  const int m0 = mt * 128, n0 = nt * 128;
  const int tid  = threadIdx.x;
  const int lane = tid & 63, wid = tid >> 6;
  const int wm = wid >> 1, wn = wid & 1;
  const int lr = lane & 15, lk = lane >> 4;

  __shared__ __align__(16) ushort lds[2][8192];

  f32x4 acc[4][4] = {};

  auto stage = [&](int kt, int buf) {
    const int k0 = kt * 32;
#pragma unroll
    for (int it = 0; it < 2; ++it) {
      const int c   = it * 256 + wid * 64 + lane;
      const int row = c >> 2, g = c & 3;
      const ushort* srcA = A + (size_t)(m0 + row) * K + (k0 + g * 8);
      ushort* dstA = &lds[buf][(it * 256 + wid * 64) * 8];
      __builtin_amdgcn_global_load_lds(
          (const __attribute__((address_space(1))) uint32_t*)srcA,
          (__attribute__((address_space(3))) uint32_t*)dstA, 16, 0, 0);
      const ushort* srcB = Wt + (size_t)(n0 + row) * K + (k0 + g * 8);
      ushort* dstB = &lds[buf][4096 + (it * 256 + wid * 64) * 8];
      __builtin_amdgcn_global_load_lds(
          (const __attribute__((address_space(1))) uint32_t*)srcB,
          (__attribute__((address_space(3))) uint32_t*)dstB, 16, 0, 0);
    }
  };

  stage(0, 0);
  __syncthreads();
  const int nk = K >> 5;
  for (int kt = 0; kt < nk; ++kt) {
    const int cur = kt & 1;
    if (kt + 1 < nk) stage(kt + 1, cur ^ 1);
    const ushort* As = &lds[cur][0];
    const ushort* Bs = &lds[cur][4096];
    bfx8 af[4], bv[4];
#pragma unroll
    for (int m = 0; m < 4; ++m)
      af[m] = *(const bfx8*)(As + (wm * 64 + m * 16 + lr) * 32 + lk * 8);
#pragma unroll
    for (int n = 0; n < 4; ++n)
      bv[n] = *(const bfx8*)(Bs + (wn * 64 + n * 16 + lr) * 32 + lk * 8);
#pragma unroll
    for (int m = 0; m < 4; ++m)
#pragma unroll
      for (int n = 0; n < 4; ++n)
        acc[m][n] = __builtin_amdgcn_mfma_f32_16x16x32_bf16(af[m], bv[n], acc[m][n], 0, 0, 0);
    __syncthreads();
  }

#pragma unroll
  for (int n = 0; n < 4; ++n) {
    const int col = n0 + wn * 64 + n * 16 + lr;
    const float bcol = bias[col];
#pragma unroll
    for (int m = 0; m < 4; ++m) {
      const int rbase = m0 + wm * 64 + m * 16 + lk * 4;
#pragma unroll
      for (int i = 0; i < 4; ++i) {
        const size_t o = (size_t)(rbase + i) * N + col;
        ((float*)Cout)[o] = acc[m][n][i] + bcol;
      }
    }
  }
}

// ---------------- softmax over 12 + pack sampling params --------------------
__global__ void softmax_pack(const float* __restrict__ aw_raw,
                             const float* __restrict__ off_raw,
                             const float* __restrict__ refp,
                             float4* __restrict__ params) {
  const int t = blockIdx.x * 256 + threadIdx.x;       // [0, MQ*NHD)
  const int h = t % NHD, nq = t / NHD;
  const float* p = aw_raw + (size_t)nq * AW_NPAD + h * 12;
  float v[12], m = -1e30f;
#pragma unroll
  for (int j = 0; j < 12; ++j) { v[j] = p[j]; m = fmaxf(m, v[j]); }
  float s = 0.f;
#pragma unroll
  for (int j = 0; j < 12; ++j) { v[j] = __expf(v[j] - m); s += v[j]; }
  const float inv = 1.f / s;
  const float* op = off_raw + (size_t)nq * SO_NPAD + h * 24;
  const float* rp = refp + (size_t)nq * (NLVL * 2);
  float4* out = params + (size_t)t * 12;
  const float Wf[3] = {128.f, 64.f, 32.f};
#pragma unroll
  for (int l = 0; l < NLVL; ++l) {
    const float rxw = rp[2 * l] * Wf[l] - 0.5f;
    const float ryw = rp[2 * l + 1] * Wf[l] - 0.5f;
#pragma unroll
    for (int pt = 0; pt < NPT; ++pt) {
      float4 o4;
      o4.x = rxw + op[(l * 4 + pt) * 2 + 0];
      o4.y = ryw + op[(l * 4 + pt) * 2 + 1];
      o4.z = v[l * 4 + pt] * inv;
      o4.w = 0.f;
      out[l * 4 + pt] = o4;
    }
  }
}

// ---------------- deformable bilinear sampling (4 heads / wave) -------------
__device__ __forceinline__ void bacc(uint2 g, float wgt,
                                     float& a0, float& a1, float& a2, float& a3) {
  union { uint32_t u; float f; } c;
  c.u = g.x << 16;          a0 += c.f * wgt;
  c.u = g.x & 0xffff0000u;  a1 += c.f * wgt;
  c.u = g.y << 16;          a2 += c.f * wgt;
  c.u = g.y & 0xffff0000u;  a3 += c.f * wgt;
}

__global__ __launch_bounds__(256) void deform_sample4(
    const char* __restrict__ vbytes, const float4* __restrict__ params,
    ushort* __restrict__ samp)
{
  const int w    = blockIdx.x * 4 + (threadIdx.x >> 6);
  const int lane = threadIdx.x & 63;
  const int nq   = w / 3;                     // wave-uniform
  const int hg   = w - nq * 3;
  const int h    = hg * 4 + (lane >> 4);
  const int n    = nq >> 12;                  // Lq = 4096
  const uint32_t laneoff = ((uint32_t)h << 7) + (uint32_t)((lane & 15) << 3);
  const float4* __restrict__ pp = params + ((size_t)nq * NHD + h) * 12;
  const uint32_t nbase = (uint32_t)n * (uint32_t)(LIN * CDIM * 2);

  float acc0 = 0.f, acc1 = 0.f, acc2 = 0.f, acc3 = 0.f;

  const int      Wl[3]  = {128, 64, 32};
  const uint32_t STb[3] = {0u, 16384u * 1536u, 20480u * 1536u};

#pragma unroll
  for (int l = 0; l < NLVL; ++l) {
    const int W_ = Wl[l];
    const uint32_t base = nbase + STb[l] + laneoff;
#pragma unroll
    for (int p = 0; p < NPT; ++p) {
      const float4 pt = pp[l * 4 + p];
      const float fx = floorf(pt.x), fy = floorf(pt.y);
      const float tx = pt.x - fx,   ty = pt.y - fy;
      const int x0 = (int)fx, y0 = (int)fy;
      const int x1 = x0 + 1,  y1 = y0 + 1;
      const float wx0 = ((uint32_t)x0 < (uint32_t)W_) ? (1.f - tx) : 0.f;
      const float wx1 = ((uint32_t)x1 < (uint32_t)W_) ? tx : 0.f;
      const float wy0 = ((uint32_t)y0 < (uint32_t)W_) ? pt.z * (1.f - ty) : 0.f;
      const float wy1 = ((uint32_t)y1 < (uint32_t)W_) ? pt.z * ty : 0.f;
      const int xc0 = min(max(x0, 0), W_ - 1);
      const int xc1 = min(max(x1, 0), W_ - 1);
      const int yr0 = min(max(y0, 0), W_ - 1) * W_;
      const int yr1 = min(max(y1, 0), W_ - 1) * W_;
      const float w00 = wy0 * wx0, w01 = wy0 * wx1;
      const float w10 = wy1 * wx0, w11 = wy1 * wx1;
      const uint2 g00 = *(const uint2*)(vbytes + (base + (uint32_t)(yr0 + xc0) * 1536u));
      const uint2 g01 = *(const uint2*)(vbytes + (base + (uint32_t)(yr0 + xc1) * 1536u));
      const uint2 g10 = *(const uint2*)(vbytes + (base + (uint32_t)(yr1 + xc0) * 1536u));
      const uint2 g11 = *(const uint2*)(vbytes + (base + (uint32_t)(yr1 + xc1) * 1536u));
      bacc(g00, w00, acc0, acc1, acc2, acc3);
      bacc(g01, w01, acc0, acc1, acc2, acc3);
      bacc(g10, w10, acc0, acc1, acc2, acc3);
      bacc(g11, w11, acc0, acc1, acc2, acc3);
    }
  }

  ushort4 o;
  o.x = f2bf(acc0); o.y = f2bf(acc1); o.z = f2bf(acc2); o.w = f2bf(acc3);
  *(ushort4*)(samp + (size_t)nq * CDIM + h * HDIM + (lane & 15) * 4) = o;
}

// ---------------- host ------------------------------------------------------
extern "C" void kernel_launch(void* const* d_in, const int* in_sizes, int n_in,
                              void* d_out, int out_size, void* d_ws, size_t ws_size,
                              hipStream_t stream) {
  const float* query = (const float*)d_in[0];
  const float* refp  = (const float*)d_in[1];
  const float* feat  = (const float*)d_in[2];
  const float* qn_w  = (const float*)d_in[3];
  const float* qn_b  = (const float*)d_in[4];
  const float* fn_w  = (const float*)d_in[5];
  const float* fn_b  = (const float*)d_in[6];
  const float* gamma = (const float*)d_in[7];
  const float* so_w  = (const float*)d_in[8];
  const float* so_b  = (const float*)d_in[9];
  const float* aw_w  = (const float*)d_in[10];
  const float* aw_b  = (const float*)d_in[11];
  const float* vp_w  = (const float*)d_in[12];
  const float* vp_b  = (const float*)d_in[13];
  const float* op_w  = (const float*)d_in[14];
  const float* op_b  = (const float*)d_in[15];

  char* ws = (char*)d_ws;
  size_t off = 0;
  auto alloc = [&](size_t bytes) {
    char* p = ws + off;
    off = (off + bytes + 255) & ~(size_t)255;
    return p;
  };
  ushort* q_bf   = (ushort*)alloc((size_t)MQ * CDIM * 2);
  ushort* val_bf = (ushort*)alloc((size_t)MF * CDIM * 2);
  ushort* vp_wT  = (ushort*)alloc((size_t)CDIM * CDIM * 2);
  ushort* op_wT  = (ushort*)alloc((size_t)CDIM * CDIM * 2);
  ushort* so_wT  = (ushort*)alloc((size_t)SO_NPAD * CDIM * 2);
  ushort* aw_wT  = (ushort*)alloc((size_t)AW_NPAD * CDIM * 2);
  float*  so_bp  = (float*)alloc(SO_NPAD * 4);
  float*  aw_bp  = (float*)alloc(AW_NPAD * 4);

  // region R: f_bf (phase A) aliases the phase-B buffers
  const size_t r = off;
  ushort* f_bf = (ushort*)(ws + r);
  const size_t f_end = r + (size_t)MF * CDIM * 2;
  size_t o2 = r;
  float*  off_raw = (float*)(ws + o2);  o2 += (size_t)MQ * SO_NPAD * 4;
  float*  aw_raw  = (float*)(ws + o2);  o2 += (size_t)MQ * AW_NPAD * 4;
  float4* params  = (float4*)(ws + o2); o2 += (size_t)MQ * NHD * 12 * 16;
  ushort* samp    = (ushort*)(ws + o2); o2 += (size_t)MQ * CDIM * 2;
  const size_t need = (f_end > o2) ? f_end : o2;
  if (ws_size < need) return;   // ~293 MB required

  // 1) weights -> bf16 transposed (+ padded biases)
  transpose_cast<<<(CDIM * CDIM + 255) / 256, 256, 0, stream>>>(vp_w, vp_wT, CDIM, CDIM, CDIM);
  transpose_cast<<<(CDIM * CDIM + 255) / 256, 256, 0, stream>>>(op_w, op_wT, CDIM, CDIM, CDIM);
  transpose_cast<<<(SO_NPAD * CDIM + 255) / 256, 256, 0, stream>>>(so_w, so_wT, CDIM, SO_N, SO_NPAD);
  transpose_cast<<<(AW_NPAD * CDIM + 255) / 256, 256, 0, stream>>>(aw_w, aw_wT, CDIM, AW_N, AW_NPAD);
  pad_bias<<<2, 256, 0, stream>>>(so_b, so_bp, SO_N, SO_NPAD);
  pad_bias<<<1, 256, 0, stream>>>(aw_b, aw_bp, AW_N, AW_NPAD);

  // 2) layernorms -> bf16
  ln_cast<<<MQ, 192, 0, stream>>>(query, qn_w, qn_b, q_bf);
  ln_cast<<<MF, 192, 0, stream>>>(feat, fn_w, fn_b, f_bf);

  // 3) value = LN(feat) @ vp_w + vp_b      (8-phase 256^2, bf16 out)
  gemm8_bt<0><<<(MF / 256) * (CDIM / 256), 512, 0, stream>>>(
      f_bf, vp_wT, vp_b, val_bf, MF, CDIM, CDIM, CDIM / 256, nullptr, nullptr);

  // 4) sampling offsets / attention weights  (2-phase 128^2, f32 out)
  gemm_bt<1><<<(MQ / 128) * (SO_NPAD / 128), 256, 0, stream>>>(
      q_bf, so_wT, so_bp, off_raw, MQ, SO_NPAD, CDIM, SO_NPAD / 128, nullptr, nullptr);
  gemm_bt<1><<<(MQ / 128) * (AW_NPAD / 128), 256, 0, stream>>>(
      q_bf, aw_wT, aw_bp, aw_raw, MQ, AW_NPAD, CDIM, AW_NPAD / 128, nullptr, nullptr);

  // 5) softmax + pack {px,py,a} per (q,h,l,p)
  softmax_pack<<<(MQ * NHD) / 256, 256, 0, stream>>>(aw_raw, off_raw, refp, params);

  // 6) deformable sampling -> samp bf16 [MQ][768]   (4 heads per wave)
  deform_sample4<<<(MQ * 3) / 4, 256, 0, stream>>>((const char*)val_bf, params, samp);

  // 7) out = query + gamma * (samp @ op_w + op_b)   (8-phase 256^2, fused epilogue)
  gemm8_bt<2><<<(MQ / 256) * (CDIM / 256), 512, 0, stream>>>(
      samp, op_wT, op_b, (float*)d_out, MQ, CDIM, CDIM, CDIM / 256, query, gamma);
}

// Round 5
// 474.185 us; speedup vs baseline: 1.0942x; 1.0942x over previous
//
#include <hip/hip_runtime.h>
#include <hip/hip_bf16.h>
#include <stdint.h>

// ---------------- problem constants (fixed by setup_inputs) ----------------
#define NHD   12        // heads
#define NPT   4         // points
#define CDIM  768
#define HDIM  64
#define NLVL  3
#define LQ    4096
#define NB    4
#define LIN   21504     // 128*128 + 64*64 + 32*32
#define MQ    (NB*LQ)   // 16384 query rows
#define MF    (NB*LIN)  // 86016 feat rows
#define CAT_N 512       // fused so(288) | aw(144) | pad(80)
#define AW_OFF 288

typedef __bf16 bfx8 __attribute__((ext_vector_type(8)));
typedef float  f32x4 __attribute__((ext_vector_type(4)));

__device__ __forceinline__ ushort f2bf(float x) {
  union { float f; uint32_t u; } v; v.f = x;
  uint32_t r = v.u + 0x7fffu + ((v.u >> 16) & 1u);   // RNE
  return (ushort)(r >> 16);
}

// ---------------- weight transpose + cast:  Wt[n][k] = bf16(W[k][n]) -------
__global__ void transpose_cast(const float* __restrict__ W, ushort* __restrict__ Wt,
                               int K, int Nsrc, int Npad) {
  int t = blockIdx.x * 256 + threadIdx.x;
  if (t >= Npad * K) return;
  int n = t / K, k = t - n * K;
  Wt[t] = (n < Nsrc) ? f2bf(W[(size_t)k * Nsrc + n]) : (ushort)0;
}

__global__ void pad_bias(const float* __restrict__ src, float* __restrict__ dst,
                         int nReal, int nPad) {
  int i = blockIdx.x * 256 + threadIdx.x;
  if (i < nPad) dst[i] = (i < nReal) ? src[i] : 0.f;
}

// ---------------- LayerNorm + cast to bf16 (one block per row) -------------
__global__ __launch_bounds__(192) void ln_cast(const float* __restrict__ x,
                                               const float* __restrict__ w,
                                               const float* __restrict__ b,
                                               ushort* __restrict__ y) {
  const int row = blockIdx.x;
  const int tid = threadIdx.x;                  // 192 threads * float4 = 768
  const float4 v = ((const float4*)(x + (size_t)row * CDIM))[tid];
  float s1 = v.x + v.y + v.z + v.w;
  float s2 = v.x*v.x + v.y*v.y + v.z*v.z + v.w*v.w;
#pragma unroll
  for (int o = 32; o > 0; o >>= 1) { s1 += __shfl_down(s1, o); s2 += __shfl_down(s2, o); }
  __shared__ float r1[3], r2[3];
  const int lane = tid & 63, wv = tid >> 6;
  if (lane == 0) { r1[wv] = s1; r2[wv] = s2; }
  __syncthreads();
  s1 = r1[0] + r1[1] + r1[2];
  s2 = r2[0] + r2[1] + r2[2];
  const float mu = s1 * (1.f / CDIM);
  const float rs = rsqrtf(s2 * (1.f / CDIM) - mu * mu + 1e-6f);
  const float4 w4 = ((const float4*)w)[tid];
  const float4 b4 = ((const float4*)b)[tid];
  ushort4 o4;
  o4.x = f2bf((v.x - mu) * rs * w4.x + b4.x);
  o4.y = f2bf((v.y - mu) * rs * w4.y + b4.y);
  o4.z = f2bf((v.z - mu) * rs * w4.z + b4.z);
  o4.w = f2bf((v.w - mu) * rs * w4.w + b4.w);
  ((ushort4*)(y + (size_t)row * CDIM))[tid] = o4;
}

// ====================== 256x256 counted-vmcnt bf16 GEMM =====================
// C[M][N] = A[M][K] * Wt[N][K]^T + bias. 512 threads = 8 waves (2M x 4N).
// BK=64 split into K-halves; LDS per buf: A-k0|A-k1|B-k0|B-k1, each [256][32]
// bf16 (16 KB), 2 bufs = 128 KiB. Phase p (kk=p>>1, mg=p&1):
//   { ds_read frags (kk) | stage half p of tile t+1 | 16 MFMA }  + 1 barrier.
// Counted waits: vmcnt(4) at end of p1 (covers h2,h3 of cur) and p3 (covers
// h0',h1' of next) -- never 0 in steady state (T3+T4). Swizzle: 16B slot
// s at row r holds global slot s^((r>>1)&3) (free 2-way on ds_read_b128).
// MODE 0: bf16 store via LDS-staged wide stores. MODE 2: f32 resid+gamma.
template<int MODE>
__global__ __launch_bounds__(512, 2) void gemm8_bt(
    const ushort* __restrict__ A, const ushort* __restrict__ Wt,
    const float* __restrict__ bias, void* __restrict__ Cout,
    int M, int N, int K, int nTN,
    const float* __restrict__ resid, const float* __restrict__ gammav)
{
  __shared__ __align__(16) char lds[131072];   // 128 KiB

  int bid = blockIdx.x;
  const int nwg = gridDim.x;
  if ((nwg & 7) == 0) {                 // XCD-chunked swizzle (bijective)
    const int chunk = nwg >> 3;
    bid = (bid & 7) * chunk + (bid >> 3);
  }
  const int mt = bid / nTN, ntl = bid - mt * nTN;
  const int m0 = mt * 256, n0 = ntl * 256;
  const int tid  = threadIdx.x;
  const int lane = tid & 63, wid = tid >> 6;
  const int wm = wid >> 2, wn = wid & 3;           // 2x4 wave grid
  const int lr = lane & 15, lk = lane >> 4;

  f32x4 acc[8][4] = {};

  // stage half h (0=A-k0, 1=B-k0, 2=A-k1, 3=B-k1) of K-tile kt into buf
  auto stage_half = [&](int kt, int h, int buf) {
    const ushort* srcM = (h & 1) ? Wt : A;
    const int base0 = (h & 1) ? n0 : m0;
    const int koff  = kt * 64 + (h >> 1) * 32;
    char* dst0 = lds + buf * 65536 + (h & 1) * 32768 + (h >> 1) * 16384;
#pragma unroll
    for (int it = 0; it < 2; ++it) {
      const int c   = it * 512 + tid;        // 16B chunk id, 1024 per half
      const int row = c >> 2, g = c & 3;
      const ushort* src = srcM + (size_t)(base0 + row) * K + koff
                          + ((g ^ ((row >> 1) & 3)) << 3);   // pre-swizzled src
      char* dst = dst0 + (it * 512 + wid * 64) * 16;         // wave-uniform base
      __builtin_amdgcn_global_load_lds(
          (const __attribute__((address_space(1))) uint32_t*)src,
          (__attribute__((address_space(3))) uint32_t*)dst, 16, 0, 0);
    }
  };
  // swizzled ds_read of one bf16x8 fragment. ab: 0=A,1=B. row in [0,256).
  auto rdfrag = [&](int buf, int ab, int row, int kk) -> bfx8 {
    const int slot = lk ^ ((row >> 1) & 3);
    return *(const bfx8*)(lds + buf * 65536 + ab * 32768 + kk * 16384
                          + row * 64 + slot * 16);
  };

  // prologue: tile 0 fully staged into buf 0
  stage_half(0, 0, 0); stage_half(0, 1, 0); stage_half(0, 2, 0); stage_half(0, 3, 0);
  asm volatile("s_waitcnt vmcnt(0)" ::: "memory");
  __builtin_amdgcn_s_barrier();
  asm volatile("" ::: "memory");

  const int nk = K >> 6;                           // K-tiles of 64
  bfx8 bfr[4];
  for (int t = 0; t < nk; ++t) {
    const int cur = t & 1;
    const bool pre = (t + 1 < nk);
#pragma unroll
    for (int p = 0; p < 4; ++p) {
      const int kk = p >> 1, mg = p & 1;
      if (mg == 0) {
#pragma unroll
        for (int n = 0; n < 4; ++n) bfr[n] = rdfrag(cur, 1, wn * 64 + n * 16 + lr, kk);
      }
      bfx8 af[4];
#pragma unroll
      for (int j = 0; j < 4; ++j)
        af[j] = rdfrag(cur, 0, wm * 128 + (mg * 4 + j) * 16 + lr, kk);
      if (pre) stage_half(t + 1, p, cur ^ 1);
      __builtin_amdgcn_s_setprio(1);
#pragma unroll
      for (int j = 0; j < 4; ++j)
#pragma unroll
        for (int n = 0; n < 4; ++n)
          acc[mg * 4 + j][n] = __builtin_amdgcn_mfma_f32_16x16x32_bf16(
              af[j], bfr[n], acc[mg * 4 + j][n], 0, 0, 0);
      __builtin_amdgcn_s_setprio(0);
      if (p == 1) {               // need h2,h3 of cur before p2 reads
        if (pre) asm volatile("s_waitcnt vmcnt(4)" ::: "memory");
        else     asm volatile("s_waitcnt vmcnt(0)" ::: "memory");
      } else if (p == 3 && pre) { // need h0',h1' of next before its p0
        asm volatile("s_waitcnt vmcnt(4)" ::: "memory");
      }
      __builtin_amdgcn_s_barrier();
      asm volatile("" ::: "memory");
    }
  }

  // ---- epilogue. D layout per MFMA: row = lk*4+i, col = lr (m89-verified).
  if constexpr (MODE == 0) {
    // per-wave LDS staging -> row-contiguous 32 B/lane bf16 stores.
    // scratch = the buffer NOT used by the last K-tile: buf (nk&1).
    ushort* my = (ushort*)(lds + (nk & 1) * 65536) + wid * (16 * 72);
    float bc[4];
#pragma unroll
    for (int n = 0; n < 4; ++n) bc[n] = bias[n0 + wn * 64 + n * 16 + lr];
    const int rrow = lane >> 2, cg = lane & 3;
#pragma unroll
    for (int m = 0; m < 8; ++m) {
#pragma unroll
      for (int n = 0; n < 4; ++n)
#pragma unroll
        for (int i = 0; i < 4; ++i)
          my[(lk * 4 + i) * 72 + n * 16 + lr] = f2bf(acc[m][n][i] + bc[n]);
      const uint4 w0 = *(const uint4*)(my + rrow * 72 + cg * 16);
      const uint4 w1 = *(const uint4*)(my + rrow * 72 + cg * 16 + 8);
      const size_t orow = (size_t)(m0 + wm * 128 + m * 16 + rrow) * N
                          + (n0 + wn * 64 + cg * 16);
      *(uint4*)((ushort*)Cout + orow)     = w0;
      *(uint4*)((ushort*)Cout + orow + 8) = w1;
    }
  } else {
#pragma unroll
    for (int n = 0; n < 4; ++n) {
      const int col = n0 + wn * 64 + n * 16 + lr;
      const float bcol = bias[col];
      const float gcol = gammav[col];
#pragma unroll
      for (int m = 0; m < 8; ++m) {
        const int rbase = m0 + wm * 128 + m * 16 + lk * 4;
#pragma unroll
        for (int i = 0; i < 4; ++i) {
          const size_t o = (size_t)(rbase + i) * N + col;
          ((float*)Cout)[o] = resid[o] + gcol * (acc[m][n][i] + bcol);
        }
      }
    }
  }
}

// ---------------- 2-phase 128x128 GEMM (fused so|aw, f32 out) --------------
__global__ __launch_bounds__(256) void gemm_bt(
    const ushort* __restrict__ A, const ushort* __restrict__ Wt,
    const float* __restrict__ bias, float* __restrict__ Cout,
    int M, int N, int K, int nTN)
{
  int bid = blockIdx.x;
  const int nwg = gridDim.x;
  if ((nwg & 7) == 0) {
    const int chunk = nwg >> 3;
    bid = (bid & 7) * chunk + (bid >> 3);
  }
  const int mt = bid / nTN;
  const int nt = bid - mt * nTN;
  const int m0 = mt * 128, n0 = nt * 128;
  const int tid  = threadIdx.x;
  const int lane = tid & 63, wid = tid >> 6;
  const int wm = wid >> 1, wn = wid & 1;
  const int lr = lane & 15, lk = lane >> 4;

  __shared__ __align__(16) ushort lds[2][8192];

  f32x4 acc[4][4] = {};

  auto stage = [&](int kt, int buf) {
    const int k0 = kt * 32;
#pragma unroll
    for (int it = 0; it < 2; ++it) {
      const int c   = it * 256 + wid * 64 + lane;
      const int row = c >> 2, g = c & 3;
      const ushort* srcA = A + (size_t)(m0 + row) * K + (k0 + g * 8);
      ushort* dstA = &lds[buf][(it * 256 + wid * 64) * 8];
      __builtin_amdgcn_global_load_lds(
          (const __attribute__((address_space(1))) uint32_t*)srcA,
          (__attribute__((address_space(3))) uint32_t*)dstA, 16, 0, 0);
      const ushort* srcB = Wt + (size_t)(n0 + row) * K + (k0 + g * 8);
      ushort* dstB = &lds[buf][4096 + (it * 256 + wid * 64) * 8];
      __builtin_amdgcn_global_load_lds(
          (const __attribute__((address_space(1))) uint32_t*)srcB,
          (__attribute__((address_space(3))) uint32_t*)dstB, 16, 0, 0);
    }
  };

  stage(0, 0);
  __syncthreads();
  const int nk = K >> 5;
  for (int kt = 0; kt < nk; ++kt) {
    const int cur = kt & 1;
    if (kt + 1 < nk) stage(kt + 1, cur ^ 1);
    const ushort* As = &lds[cur][0];
    const ushort* Bs = &lds[cur][4096];
    bfx8 af[4], bv[4];
#pragma unroll
    for (int m = 0; m < 4; ++m)
      af[m] = *(const bfx8*)(As + (wm * 64 + m * 16 + lr) * 32 + lk * 8);
#pragma unroll
    for (int n = 0; n < 4; ++n)
      bv[n] = *(const bfx8*)(Bs + (wn * 64 + n * 16 + lr) * 32 + lk * 8);
#pragma unroll
    for (int m = 0; m < 4; ++m)
#pragma unroll
      for (int n = 0; n < 4; ++n)
        acc[m][n] = __builtin_amdgcn_mfma_f32_16x16x32_bf16(af[m], bv[n], acc[m][n], 0, 0, 0);
    __syncthreads();
  }

#pragma unroll
  for (int n = 0; n < 4; ++n) {
    const int col = n0 + wn * 64 + n * 16 + lr;
    const float bcol = bias[col];
#pragma unroll
    for (int m = 0; m < 4; ++m) {
      const int rbase = m0 + wm * 64 + m * 16 + lk * 4;
#pragma unroll
      for (int i = 0; i < 4; ++i)
        Cout[(size_t)(rbase + i) * N + col] = acc[m][n][i] + bcol;
    }
  }
}

// ---------------- softmax over 12 + pack sampling params --------------------
// raw layout per (nq): [0,288) sampling offsets, [288,432) attn logits.
__global__ void softmax_pack(const float* __restrict__ raw,
                             const float* __restrict__ refp,
                             float4* __restrict__ params) {
  const int t = blockIdx.x * 256 + threadIdx.x;       // [0, MQ*NHD)
  const int h = t % NHD, nq = t / NHD;
  const float* p = raw + (size_t)nq * CAT_N + AW_OFF + h * 12;
  float v[12], m = -1e30f;
#pragma unroll
  for (int j = 0; j < 12; ++j) { v[j] = p[j]; m = fmaxf(m, v[j]); }
  float s = 0.f;
#pragma unroll
  for (int j = 0; j < 12; ++j) { v[j] = __expf(v[j] - m); s += v[j]; }
  const float inv = 1.f / s;
  const float* op = raw + (size_t)nq * CAT_N + h * 24;
  const float* rp = refp + (size_t)nq * (NLVL * 2);
  float4* out = params + (size_t)t * 12;
  const float Wf[3] = {128.f, 64.f, 32.f};
#pragma unroll
  for (int l = 0; l < NLVL; ++l) {
    const float rxw = rp[2 * l] * Wf[l] - 0.5f;
    const float ryw = rp[2 * l + 1] * Wf[l] - 0.5f;
#pragma unroll
    for (int pt = 0; pt < NPT; ++pt) {
      float4 o4;
      o4.x = rxw + op[(l * 4 + pt) * 2 + 0];
      o4.y = ryw + op[(l * 4 + pt) * 2 + 1];
      o4.z = v[l * 4 + pt] * inv;
      o4.w = 0.f;
      out[l * 4 + pt] = o4;
    }
  }
}

// ---------------- deformable bilinear sampling (4 heads / wave) -------------
__device__ __forceinline__ void bacc(uint2 g, float wgt,
                                     float& a0, float& a1, float& a2, float& a3) {
  union { uint32_t u; float f; } c;
  c.u = g.x << 16;          a0 += c.f * wgt;
  c.u = g.x & 0xffff0000u;  a1 += c.f * wgt;
  c.u = g.y << 16;          a2 += c.f * wgt;
  c.u = g.y & 0xffff0000u;  a3 += c.f * wgt;
}

__global__ __launch_bounds__(256) void deform_sample4(
    const char* __restrict__ vbytes, const float4* __restrict__ params,
    ushort* __restrict__ samp)
{
  const int w    = blockIdx.x * 4 + (threadIdx.x >> 6);
  const int lane = threadIdx.x & 63;
  const int nq   = w / 3;                     // wave-uniform
  const int hg   = w - nq * 3;
  const int h    = hg * 4 + (lane >> 4);
  const int n    = nq >> 12;                  // Lq = 4096
  const uint32_t laneoff = ((uint32_t)h << 7) + (uint32_t)((lane & 15) << 3);
  const float4* __restrict__ pp = params + ((size_t)nq * NHD + h) * 12;
  const uint32_t nbase = (uint32_t)n * (uint32_t)(LIN * CDIM * 2);

  float acc0 = 0.f, acc1 = 0.f, acc2 = 0.f, acc3 = 0.f;

  const int      Wl[3]  = {128, 64, 32};
  const uint32_t STb[3] = {0u, 16384u * 1536u, 20480u * 1536u};

#pragma unroll
  for (int l = 0; l < NLVL; ++l) {
    const int W_ = Wl[l];
    const uint32_t base = nbase + STb[l] + laneoff;
#pragma unroll
    for (int p = 0; p < NPT; ++p) {
      const float4 pt = pp[l * 4 + p];
      const float fx = floorf(pt.x), fy = floorf(pt.y);
      const float tx = pt.x - fx,   ty = pt.y - fy;
      const int x0 = (int)fx, y0 = (int)fy;
      const int x1 = x0 + 1,  y1 = y0 + 1;
      const float wx0 = ((uint32_t)x0 < (uint32_t)W_) ? (1.f - tx) : 0.f;
      const float wx1 = ((uint32_t)x1 < (uint32_t)W_) ? tx : 0.f;
      const float wy0 = ((uint32_t)y0 < (uint32_t)W_) ? pt.z * (1.f - ty) : 0.f;
      const float wy1 = ((uint32_t)y1 < (uint32_t)W_) ? pt.z * ty : 0.f;
      const int xc0 = min(max(x0, 0), W_ - 1);
      const int xc1 = min(max(x1, 0), W_ - 1);
      const int yr0 = min(max(y0, 0), W_ - 1) * W_;
      const int yr1 = min(max(y1, 0), W_ - 1) * W_;
      const float w00 = wy0 * wx0, w01 = wy0 * wx1;
      const float w10 = wy1 * wx0, w11 = wy1 * wx1;
      const uint2 g00 = *(const uint2*)(vbytes + (base + (uint32_t)(yr0 + xc0) * 1536u));
      const uint2 g01 = *(const uint2*)(vbytes + (base + (uint32_t)(yr0 + xc1) * 1536u));
      const uint2 g10 = *(const uint2*)(vbytes + (base + (uint32_t)(yr1 + xc0) * 1536u));
      const uint2 g11 = *(const uint2*)(vbytes + (base + (uint32_t)(yr1 + xc1) * 1536u));
      bacc(g00, w00, acc0, acc1, acc2, acc3);
      bacc(g01, w01, acc0, acc1, acc2, acc3);
      bacc(g10, w10, acc0, acc1, acc2, acc3);
      bacc(g11, w11, acc0, acc1, acc2, acc3);
    }
  }

  ushort4 o;
  o.x = f2bf(acc0); o.y = f2bf(acc1); o.z = f2bf(acc2); o.w = f2bf(acc3);
  *(ushort4*)(samp + (size_t)nq * CDIM + h * HDIM + (lane & 15) * 4) = o;
}

// ---------------- host ------------------------------------------------------
extern "C" void kernel_launch(void* const* d_in, const int* in_sizes, int n_in,
                              void* d_out, int out_size, void* d_ws, size_t ws_size,
                              hipStream_t stream) {
  const float* query = (const float*)d_in[0];
  const float* refp  = (const float*)d_in[1];
  const float* feat  = (const float*)d_in[2];
  const float* qn_w  = (const float*)d_in[3];
  const float* qn_b  = (const float*)d_in[4];
  const float* fn_w  = (const float*)d_in[5];
  const float* fn_b  = (const float*)d_in[6];
  const float* gamma = (const float*)d_in[7];
  const float* so_w  = (const float*)d_in[8];
  const float* so_b  = (const float*)d_in[9];
  const float* aw_w  = (const float*)d_in[10];
  const float* aw_b  = (const float*)d_in[11];
  const float* vp_w  = (const float*)d_in[12];
  const float* vp_b  = (const float*)d_in[13];
  const float* op_w  = (const float*)d_in[14];
  const float* op_b  = (const float*)d_in[15];

  char* ws = (char*)d_ws;
  size_t off = 0;
  auto alloc = [&](size_t bytes) {
    char* p = ws + off;
    off = (off + bytes + 255) & ~(size_t)255;
    return p;
  };
  ushort* q_bf   = (ushort*)alloc((size_t)MQ * CDIM * 2);
  ushort* val_bf = (ushort*)alloc((size_t)MF * CDIM * 2);
  ushort* vp_wT  = (ushort*)alloc((size_t)CDIM * CDIM * 2);
  ushort* op_wT  = (ushort*)alloc((size_t)CDIM * CDIM * 2);
  ushort* cat_wT = (ushort*)alloc((size_t)CAT_N * CDIM * 2);
  float*  cat_bp = (float*)alloc(CAT_N * 4);

  // region R: f_bf (phase A) aliases the phase-B buffers
  const size_t r = off;
  ushort* f_bf = (ushort*)(ws + r);
  const size_t f_end = r + (size_t)MF * CDIM * 2;
  size_t o2 = r;
  float*  raw     = (float*)(ws + o2);  o2 += (size_t)MQ * CAT_N * 4;
  float4* params  = (float4*)(ws + o2); o2 += (size_t)MQ * NHD * 12 * 16;
  ushort* samp    = (ushort*)(ws + o2); o2 += (size_t)MQ * CDIM * 2;
  const size_t need = (f_end > o2) ? f_end : o2;
  if (ws_size < need) return;   // ~292 MB required

  // 1) weights -> bf16 transposed (+ padded biases). cat = [so | aw | pad]
  transpose_cast<<<(CDIM * CDIM + 255) / 256, 256, 0, stream>>>(vp_w, vp_wT, CDIM, CDIM, CDIM);
  transpose_cast<<<(CDIM * CDIM + 255) / 256, 256, 0, stream>>>(op_w, op_wT, CDIM, CDIM, CDIM);
  transpose_cast<<<(AW_OFF * CDIM + 255) / 256, 256, 0, stream>>>(so_w, cat_wT, CDIM, 288, AW_OFF);
  transpose_cast<<<((CAT_N - AW_OFF) * CDIM + 255) / 256, 256, 0, stream>>>(
      aw_w, cat_wT + (size_t)AW_OFF * CDIM, CDIM, 144, CAT_N - AW_OFF);
  pad_bias<<<2, 256, 0, stream>>>(so_b, cat_bp, 288, AW_OFF);
  pad_bias<<<1, 256, 0, stream>>>(aw_b, cat_bp + AW_OFF, 144, CAT_N - AW_OFF);

  // 2) layernorms -> bf16
  ln_cast<<<MQ, 192, 0, stream>>>(query, qn_w, qn_b, q_bf);
  ln_cast<<<MF, 192, 0, stream>>>(feat, fn_w, fn_b, f_bf);

  // 3) value = LN(feat) @ vp_w + vp_b      (counted-vmcnt 256^2, bf16 out)
  gemm8_bt<0><<<(MF / 256) * (CDIM / 256), 512, 0, stream>>>(
      f_bf, vp_wT, vp_b, val_bf, MF, CDIM, CDIM, CDIM / 256, nullptr, nullptr);

  // 4) fused sampling-offset | attn-weight GEMM  (2-phase 128^2, f32 out)
  gemm_bt<<<(MQ / 128) * (CAT_N / 128), 256, 0, stream>>>(
      q_bf, cat_wT, cat_bp, raw, MQ, CAT_N, CDIM, CAT_N / 128);

  // 5) softmax + pack {px,py,a} per (q,h,l,p)
  softmax_pack<<<(MQ * NHD) / 256, 256, 0, stream>>>(raw, refp, params);

  // 6) deformable sampling -> samp bf16 [MQ][768]   (4 heads per wave)
  deform_sample4<<<(MQ * 3) / 4, 256, 0, stream>>>((const char*)val_bf, params, samp);

  // 7) out = query + gamma * (samp @ op_w + op_b)   (counted-vmcnt, fused epi)
  gemm8_bt<2><<<(MQ / 256) * (CDIM / 256), 512, 0, stream>>>(
      samp, op_wT, op_b, (float*)d_out, MQ, CDIM, CDIM, CDIM / 256, query, gamma);
}

// Round 6
// 473.615 us; speedup vs baseline: 1.0955x; 1.0012x over previous
//
#include <hip/hip_runtime.h>
#include <hip/hip_bf16.h>
#include <stdint.h>

// ---------------- problem constants (fixed by setup_inputs) ----------------
#define NHD   12        // heads
#define NPT   4         // points
#define CDIM  768
#define HDIM  64
#define NLVL  3
#define LQ    4096
#define NB    4
#define LIN   21504     // 128*128 + 64*64 + 32*32
#define MQ    (NB*LQ)   // 16384 query rows
#define MF    (NB*LIN)  // 86016 feat rows
#define CAT_N 512       // fused so(288) | aw(144) | pad(80)
#define AW_OFF 288

typedef __bf16 bfx8 __attribute__((ext_vector_type(8)));
typedef float  f32x4 __attribute__((ext_vector_type(4)));

__device__ __forceinline__ ushort f2bf(float x) {
  union { float f; uint32_t u; } v; v.f = x;
  uint32_t r = v.u + 0x7fffu + ((v.u >> 16) & 1u);   // RNE
  return (ushort)(r >> 16);
}

// ---------------- weight transpose + cast:  Wt[n][k] = bf16(W[k][n]) -------
__global__ void transpose_cast(const float* __restrict__ W, ushort* __restrict__ Wt,
                               int K, int Nsrc, int Npad) {
  int t = blockIdx.x * 256 + threadIdx.x;
  if (t >= Npad * K) return;
  int n = t / K, k = t - n * K;
  Wt[t] = (n < Nsrc) ? f2bf(W[(size_t)k * Nsrc + n]) : (ushort)0;
}

__global__ void pad_bias(const float* __restrict__ src, float* __restrict__ dst,
                         int nReal, int nPad) {
  int i = blockIdx.x * 256 + threadIdx.x;
  if (i < nPad) dst[i] = (i < nReal) ? src[i] : 0.f;
}

// ---------------- LayerNorm + cast to bf16 (one block per row) -------------
__global__ __launch_bounds__(192) void ln_cast(const float* __restrict__ x,
                                               const float* __restrict__ w,
                                               const float* __restrict__ b,
                                               ushort* __restrict__ y) {
  const int row = blockIdx.x;
  const int tid = threadIdx.x;                  // 192 threads * float4 = 768
  const float4 v = ((const float4*)(x + (size_t)row * CDIM))[tid];
  float s1 = v.x + v.y + v.z + v.w;
  float s2 = v.x*v.x + v.y*v.y + v.z*v.z + v.w*v.w;
#pragma unroll
  for (int o = 32; o > 0; o >>= 1) { s1 += __shfl_down(s1, o); s2 += __shfl_down(s2, o); }
  __shared__ float r1[3], r2[3];
  const int lane = tid & 63, wv = tid >> 6;
  if (lane == 0) { r1[wv] = s1; r2[wv] = s2; }
  __syncthreads();
  s1 = r1[0] + r1[1] + r1[2];
  s2 = r2[0] + r2[1] + r2[2];
  const float mu = s1 * (1.f / CDIM);
  const float rs = rsqrtf(s2 * (1.f / CDIM) - mu * mu + 1e-6f);
  const float4 w4 = ((const float4*)w)[tid];
  const float4 b4 = ((const float4*)b)[tid];
  ushort4 o4;
  o4.x = f2bf((v.x - mu) * rs * w4.x + b4.x);
  o4.y = f2bf((v.y - mu) * rs * w4.y + b4.y);
  o4.z = f2bf((v.z - mu) * rs * w4.z + b4.z);
  o4.w = f2bf((v.w - mu) * rs * w4.w + b4.w);
  ((ushort4*)(y + (size_t)row * CDIM))[tid] = o4;
}

// ====================== 256x256 counted-vmcnt bf16 GEMM =====================
// C = A[M][K] * Wt[N][K]^T + bias. 512 threads = 8 waves (2M x 4N).
// BK=64 split into K-halves; LDS per buf: A-k0|B-k0|A-k1|B-k1, each [256][32]
// bf16 (16 KB), 2 bufs = 128 KiB. Phase p (kk=p>>1, mg=p&1):
//   { ds_read frags (kk) | stage half p of tile t+1 | 16 MFMA }  + 1 barrier.
// Counted waits: vmcnt(4) at end of p1 and p3 only -- never 0 in steady
// state (T3+T4). Swizzle: 16B slot s at row r holds slot s^((r>>1)&3).
// MODE 0: bf16 store, HEAD-MAJOR value layout [n][NHD][LIN][64].
// MODE 2: f32, out = resid + gamma*(acc+bias), row-major [M][N].
template<int MODE>
__global__ __launch_bounds__(512, 2) void gemm8_bt(
    const ushort* __restrict__ A, const ushort* __restrict__ Wt,
    const float* __restrict__ bias, void* __restrict__ Cout,
    int M, int N, int K, int nTN,
    const float* __restrict__ resid, const float* __restrict__ gammav)
{
  __shared__ __align__(16) char lds[131072];   // 128 KiB

  int bid = blockIdx.x;
  const int nwg = gridDim.x;
  if ((nwg & 7) == 0) {                 // XCD-chunked swizzle (bijective)
    const int chunk = nwg >> 3;
    bid = (bid & 7) * chunk + (bid >> 3);
  }
  const int mt = bid / nTN, ntl = bid - mt * nTN;
  const int m0 = mt * 256, n0 = ntl * 256;
  const int tid  = threadIdx.x;
  const int lane = tid & 63, wid = tid >> 6;
  const int wm = wid >> 2, wn = wid & 3;           // 2x4 wave grid
  const int lr = lane & 15, lk = lane >> 4;

  f32x4 acc[8][4] = {};

  // stage half h (0=A-k0, 1=B-k0, 2=A-k1, 3=B-k1) of K-tile kt into buf
  auto stage_half = [&](int kt, int h, int buf) {
    const ushort* srcM = (h & 1) ? Wt : A;
    const int base0 = (h & 1) ? n0 : m0;
    const int koff  = kt * 64 + (h >> 1) * 32;
    char* dst0 = lds + buf * 65536 + (h & 1) * 32768 + (h >> 1) * 16384;
#pragma unroll
    for (int it = 0; it < 2; ++it) {
      const int c   = it * 512 + tid;        // 16B chunk id, 1024 per half
      const int row = c >> 2, g = c & 3;
      const ushort* src = srcM + (size_t)(base0 + row) * K + koff
                          + ((g ^ ((row >> 1) & 3)) << 3);   // pre-swizzled src
      char* dst = dst0 + (it * 512 + wid * 64) * 16;         // wave-uniform base
      __builtin_amdgcn_global_load_lds(
          (const __attribute__((address_space(1))) uint32_t*)src,
          (__attribute__((address_space(3))) uint32_t*)dst, 16, 0, 0);
    }
  };
  // swizzled ds_read of one bf16x8 fragment. ab: 0=A,1=B. row in [0,256).
  auto rdfrag = [&](int buf, int ab, int row, int kk) -> bfx8 {
    const int slot = lk ^ ((row >> 1) & 3);
    return *(const bfx8*)(lds + buf * 65536 + ab * 32768 + kk * 16384
                          + row * 64 + slot * 16);
  };

  // prologue: tile 0 fully staged into buf 0
  stage_half(0, 0, 0); stage_half(0, 1, 0); stage_half(0, 2, 0); stage_half(0, 3, 0);
  asm volatile("s_waitcnt vmcnt(0)" ::: "memory");
  __builtin_amdgcn_s_barrier();
  asm volatile("" ::: "memory");

  const int nk = K >> 6;                           // K-tiles of 64
  bfx8 bfr[4];
  for (int t = 0; t < nk; ++t) {
    const int cur = t & 1;
    const bool pre = (t + 1 < nk);
#pragma unroll
    for (int p = 0; p < 4; ++p) {
      const int kk = p >> 1, mg = p & 1;
      if (mg == 0) {
#pragma unroll
        for (int n = 0; n < 4; ++n) bfr[n] = rdfrag(cur, 1, wn * 64 + n * 16 + lr, kk);
      }
      bfx8 af[4];
#pragma unroll
      for (int j = 0; j < 4; ++j)
        af[j] = rdfrag(cur, 0, wm * 128 + (mg * 4 + j) * 16 + lr, kk);
      if (pre) stage_half(t + 1, p, cur ^ 1);
      __builtin_amdgcn_s_setprio(1);
#pragma unroll
      for (int j = 0; j < 4; ++j)
#pragma unroll
        for (int n = 0; n < 4; ++n)
          acc[mg * 4 + j][n] = __builtin_amdgcn_mfma_f32_16x16x32_bf16(
              af[j], bfr[n], acc[mg * 4 + j][n], 0, 0, 0);
      __builtin_amdgcn_s_setprio(0);
      if (p == 1) {               // need h2,h3 of cur before p2 reads
        if (pre) asm volatile("s_waitcnt vmcnt(4)" ::: "memory");
        else     asm volatile("s_waitcnt vmcnt(0)" ::: "memory");
      } else if (p == 3 && pre) { // need h0',h1' of next before its p0
        asm volatile("s_waitcnt vmcnt(4)" ::: "memory");
      }
      __builtin_amdgcn_s_barrier();
      asm volatile("" ::: "memory");
    }
  }

  // ---- epilogue. D layout per MFMA: row = lk*4+i, col = lr (m89-verified).
  if constexpr (MODE == 0) {
    // head-major value store: Cout layout [n][NHD][LIN][64] bf16.
    // Each wave's 64-col segment == one head (n0 + wn*64 is 64-aligned).
    // LDS-staged -> 32 B/lane contiguous stores (2 KB runs per wave).
    ushort* my = (ushort*)(lds + (nk & 1) * 65536) + wid * (16 * 72);
    float bc[4];
#pragma unroll
    for (int n = 0; n < 4; ++n) bc[n] = bias[n0 + wn * 64 + n * 16 + lr];
    const int rrow = lane >> 2, cg = lane & 3;
    const int n_img = (unsigned)m0 / LIN;          // LIN%256==0: no crossing
    const int head  = (n0 + wn * 64) >> 6;
    ushort* plane = (ushort*)Cout
        + ((size_t)(n_img * NHD + head) * LIN + (m0 - n_img * LIN)) * 64;
#pragma unroll
    for (int m = 0; m < 8; ++m) {
#pragma unroll
      for (int n = 0; n < 4; ++n)
#pragma unroll
        for (int i = 0; i < 4; ++i)
          my[(lk * 4 + i) * 72 + n * 16 + lr] = f2bf(acc[m][n][i] + bc[n]);
      const uint4 w0 = *(const uint4*)(my + rrow * 72 + cg * 16);
      const uint4 w1 = *(const uint4*)(my + rrow * 72 + cg * 16 + 8);
      ushort* orow = plane + (wm * 128 + m * 16 + rrow) * 64 + cg * 16;
      *(uint4*)orow       = w0;
      *(uint4*)(orow + 8) = w1;
    }
  } else {
#pragma unroll
    for (int n = 0; n < 4; ++n) {
      const int col = n0 + wn * 64 + n * 16 + lr;
      const float bcol = bias[col];
      const float gcol = gammav[col];
#pragma unroll
      for (int m = 0; m < 8; ++m) {
        const int rbase = m0 + wm * 128 + m * 16 + lk * 4;
#pragma unroll
        for (int i = 0; i < 4; ++i) {
          const size_t o = (size_t)(rbase + i) * N + col;
          ((float*)Cout)[o] = resid[o] + gcol * (acc[m][n][i] + bcol);
        }
      }
    }
  }
}

// ---------------- 2-phase 128x128 GEMM (fused so|aw, f32 out) --------------
__global__ __launch_bounds__(256) void gemm_bt(
    const ushort* __restrict__ A, const ushort* __restrict__ Wt,
    const float* __restrict__ bias, float* __restrict__ Cout,
    int M, int N, int K, int nTN)
{
  int bid = blockIdx.x;
  const int nwg = gridDim.x;
  if ((nwg & 7) == 0) {
    const int chunk = nwg >> 3;
    bid = (bid & 7) * chunk + (bid >> 3);
  }
  const int mt = bid / nTN;
  const int nt = bid - mt * nTN;
  const int m0 = mt * 128, n0 = nt * 128;
  const int tid  = threadIdx.x;
  const int lane = tid & 63, wid = tid >> 6;
  const int wm = wid >> 1, wn = wid & 1;
  const int lr = lane & 15, lk = lane >> 4;

  __shared__ __align__(16) ushort lds[2][8192];

  f32x4 acc[4][4] = {};

  auto stage = [&](int kt, int buf) {
    const int k0 = kt * 32;
#pragma unroll
    for (int it = 0; it < 2; ++it) {
      const int c   = it * 256 + wid * 64 + lane;
      const int row = c >> 2, g = c & 3;
      const ushort* srcA = A + (size_t)(m0 + row) * K + (k0 + g * 8);
      ushort* dstA = &lds[buf][(it * 256 + wid * 64) * 8];
      __builtin_amdgcn_global_load_lds(
          (const __attribute__((address_space(1))) uint32_t*)srcA,
          (__attribute__((address_space(3))) uint32_t*)dstA, 16, 0, 0);
      const ushort* srcB = Wt + (size_t)(n0 + row) * K + (k0 + g * 8);
      ushort* dstB = &lds[buf][4096 + (it * 256 + wid * 64) * 8];
      __builtin_amdgcn_global_load_lds(
          (const __attribute__((address_space(1))) uint32_t*)srcB,
          (__attribute__((address_space(3))) uint32_t*)dstB, 16, 0, 0);
    }
  };

  stage(0, 0);
  __syncthreads();
  const int nk = K >> 5;
  for (int kt = 0; kt < nk; ++kt) {
    const int cur = kt & 1;
    if (kt + 1 < nk) stage(kt + 1, cur ^ 1);
    const ushort* As = &lds[cur][0];
    const ushort* Bs = &lds[cur][4096];
    bfx8 af[4], bv[4];
#pragma unroll
    for (int m = 0; m < 4; ++m)
      af[m] = *(const bfx8*)(As + (wm * 64 + m * 16 + lr) * 32 + lk * 8);
#pragma unroll
    for (int n = 0; n < 4; ++n)
      bv[n] = *(const bfx8*)(Bs + (wn * 64 + n * 16 + lr) * 32 + lk * 8);
#pragma unroll
    for (int m = 0; m < 4; ++m)
#pragma unroll
      for (int n = 0; n < 4; ++n)
        acc[m][n] = __builtin_amdgcn_mfma_f32_16x16x32_bf16(af[m], bv[n], acc[m][n], 0, 0, 0);
    __syncthreads();
  }

#pragma unroll
  for (int n = 0; n < 4; ++n) {
    const int col = n0 + wn * 64 + n * 16 + lr;
    const float bcol = bias[col];
#pragma unroll
    for (int m = 0; m < 4; ++m) {
      const int rbase = m0 + wm * 64 + m * 16 + lk * 4;
#pragma unroll
      for (int i = 0; i < 4; ++i)
        Cout[(size_t)(rbase + i) * N + col] = acc[m][n][i] + bcol;
    }
  }
}

// ---------------- softmax over 12 + pack sampling params --------------------
// raw layout per (nq): [0,288) sampling offsets, [288,432) attn logits.
__global__ void softmax_pack(const float* __restrict__ raw,
                             const float* __restrict__ refp,
                             float4* __restrict__ params) {
  const int t = blockIdx.x * 256 + threadIdx.x;       // [0, MQ*NHD)
  const int h = t % NHD, nq = t / NHD;
  const float* p = raw + (size_t)nq * CAT_N + AW_OFF + h * 12;
  float v[12], m = -1e30f;
#pragma unroll
  for (int j = 0; j < 12; ++j) { v[j] = p[j]; m = fmaxf(m, v[j]); }
  float s = 0.f;
#pragma unroll
  for (int j = 0; j < 12; ++j) { v[j] = __expf(v[j] - m); s += v[j]; }
  const float inv = 1.f / s;
  const float* op = raw + (size_t)nq * CAT_N + h * 24;
  const float* rp = refp + (size_t)nq * (NLVL * 2);
  float4* out = params + (size_t)t * 12;
  const float Wf[3] = {128.f, 64.f, 32.f};
#pragma unroll
  for (int l = 0; l < NLVL; ++l) {
    const float rxw = rp[2 * l] * Wf[l] - 0.5f;
    const float ryw = rp[2 * l + 1] * Wf[l] - 0.5f;
#pragma unroll
    for (int pt = 0; pt < NPT; ++pt) {
      float4 o4;
      o4.x = rxw + op[(l * 4 + pt) * 2 + 0];
      o4.y = ryw + op[(l * 4 + pt) * 2 + 1];
      o4.z = v[l * 4 + pt] * inv;
      o4.w = 0.f;
      out[l * 4 + pt] = o4;
    }
  }
}

// ---------------- deformable bilinear sampling, XCD-pinned groups ----------
// value layout: [n][NHD][LIN][64] bf16 -> one (n,h) plane = 2.75 MB < L2/XCD.
// Group g = plane index in [0,48); blocks of group g are exactly the blocks
// with blockIdx%8 == g%8 in one contiguous stretch -> all land on XCD g%8 and
// one group exactly fills an XCD's residency (256 blocks), so gathers hit L2.
// Wave: 4 queries x 16 lanes; lane&15 = channel quad (uint2 = 4 bf16).
__device__ __forceinline__ void bacc(uint2 g, float wgt,
                                     float& a0, float& a1, float& a2, float& a3) {
  union { uint32_t u; float f; } c;
  c.u = g.x << 16;          a0 += c.f * wgt;
  c.u = g.x & 0xffff0000u;  a1 += c.f * wgt;
  c.u = g.y << 16;          a2 += c.f * wgt;
  c.u = g.y & 0xffff0000u;  a3 += c.f * wgt;
}

__global__ __launch_bounds__(256) void deform_grp(
    const char* __restrict__ vbytes, const float4* __restrict__ params,
    ushort* __restrict__ samp)
{
  const int j = blockIdx.x;
  const int x = j & 7, k = j >> 3;
  const int g = x + ((k >> 8) << 3);          // plane = n*NHD+h, pinned to XCD x
  const int i = k & 255;                      // block within group
  const int n = g / NHD, h = g - n * NHD;
  const int wid  = threadIdx.x >> 6;
  const int lane = threadIdx.x & 63;
  const int q  = i * 16 + wid * 4 + (lane >> 4);        // [0, 4096)
  const int nq = n * LQ + q;
  const float4* __restrict__ pp = params + ((size_t)nq * NHD + h) * 12;
  const uint32_t base0 = (uint32_t)g * (uint32_t)(LIN * 128)
                       + ((uint32_t)(lane & 15) << 3);

  float acc0 = 0.f, acc1 = 0.f, acc2 = 0.f, acc3 = 0.f;

  const int      Wl[3]  = {128, 64, 32};
  const uint32_t STb[3] = {0u, 16384u * 128u, 20480u * 128u};

#pragma unroll
  for (int l = 0; l < NLVL; ++l) {
    const int W_ = Wl[l];
    const uint32_t base = base0 + STb[l];
#pragma unroll
    for (int p = 0; p < NPT; ++p) {
      const float4 pt = pp[l * 4 + p];
      const float fx = floorf(pt.x), fy = floorf(pt.y);
      const float tx = pt.x - fx,   ty = pt.y - fy;
      const int x0 = (int)fx, y0 = (int)fy;
      const int x1 = x0 + 1,  y1 = y0 + 1;
      const float wx0 = ((uint32_t)x0 < (uint32_t)W_) ? (1.f - tx) : 0.f;
      const float wx1 = ((uint32_t)x1 < (uint32_t)W_) ? tx : 0.f;
      const float wy0 = ((uint32_t)y0 < (uint32_t)W_) ? pt.z * (1.f - ty) : 0.f;
      const float wy1 = ((uint32_t)y1 < (uint32_t)W_) ? pt.z * ty : 0.f;
      const int xc0 = min(max(x0, 0), W_ - 1);
      const int xc1 = min(max(x1, 0), W_ - 1);
      const int yr0 = min(max(y0, 0), W_ - 1) * W_;
      const int yr1 = min(max(y1, 0), W_ - 1) * W_;
      const float w00 = wy0 * wx0, w01 = wy0 * wx1;
      const float w10 = wy1 * wx0, w11 = wy1 * wx1;
      const uint2 g00 = *(const uint2*)(vbytes + (base + (uint32_t)(yr0 + xc0) * 128u));
      const uint2 g01 = *(const uint2*)(vbytes + (base + (uint32_t)(yr0 + xc1) * 128u));
      const uint2 g10 = *(const uint2*)(vbytes + (base + (uint32_t)(yr1 + xc0) * 128u));
      const uint2 g11 = *(const uint2*)(vbytes + (base + (uint32_t)(yr1 + xc1) * 128u));
      bacc(g00, w00, acc0, acc1, acc2, acc3);
      bacc(g01, w01, acc0, acc1, acc2, acc3);
      bacc(g10, w10, acc0, acc1, acc2, acc3);
      bacc(g11, w11, acc0, acc1, acc2, acc3);
    }
  }

  ushort4 o;
  o.x = f2bf(acc0); o.y = f2bf(acc1); o.z = f2bf(acc2); o.w = f2bf(acc3);
  *(ushort4*)(samp + (size_t)nq * CDIM + h * HDIM + (lane & 15) * 4) = o;
}

// ---------------- host ------------------------------------------------------
extern "C" void kernel_launch(void* const* d_in, const int* in_sizes, int n_in,
                              void* d_out, int out_size, void* d_ws, size_t ws_size,
                              hipStream_t stream) {
  const float* query = (const float*)d_in[0];
  const float* refp  = (const float*)d_in[1];
  const float* feat  = (const float*)d_in[2];
  const float* qn_w  = (const float*)d_in[3];
  const float* qn_b  = (const float*)d_in[4];
  const float* fn_w  = (const float*)d_in[5];
  const float* fn_b  = (const float*)d_in[6];
  const float* gamma = (const float*)d_in[7];
  const float* so_w  = (const float*)d_in[8];
  const float* so_b  = (const float*)d_in[9];
  const float* aw_w  = (const float*)d_in[10];
  const float* aw_b  = (const float*)d_in[11];
  const float* vp_w  = (const float*)d_in[12];
  const float* vp_b  = (const float*)d_in[13];
  const float* op_w  = (const float*)d_in[14];
  const float* op_b  = (const float*)d_in[15];

  char* ws = (char*)d_ws;
  size_t off = 0;
  auto alloc = [&](size_t bytes) {
    char* p = ws + off;
    off = (off + bytes + 255) & ~(size_t)255;
    return p;
  };
  ushort* q_bf   = (ushort*)alloc((size_t)MQ * CDIM * 2);
  ushort* val_bf = (ushort*)alloc((size_t)MF * CDIM * 2);  // [n][NHD][LIN][64]
  ushort* vp_wT  = (ushort*)alloc((size_t)CDIM * CDIM * 2);
  ushort* op_wT  = (ushort*)alloc((size_t)CDIM * CDIM * 2);
  ushort* cat_wT = (ushort*)alloc((size_t)CAT_N * CDIM * 2);
  float*  cat_bp = (float*)alloc(CAT_N * 4);

  // region R: f_bf (phase A) aliases the phase-B buffers
  const size_t r = off;
  ushort* f_bf = (ushort*)(ws + r);
  const size_t f_end = r + (size_t)MF * CDIM * 2;
  size_t o2 = r;
  float*  raw     = (float*)(ws + o2);  o2 += (size_t)MQ * CAT_N * 4;
  float4* params  = (float4*)(ws + o2); o2 += (size_t)MQ * NHD * 12 * 16;
  ushort* samp    = (ushort*)(ws + o2); o2 += (size_t)MQ * CDIM * 2;
  const size_t need = (f_end > o2) ? f_end : o2;
  if (ws_size < need) return;   // ~292 MB required

  // 1) weights -> bf16 transposed (+ padded biases). cat = [so | aw | pad]
  transpose_cast<<<(CDIM * CDIM + 255) / 256, 256, 0, stream>>>(vp_w, vp_wT, CDIM, CDIM, CDIM);
  transpose_cast<<<(CDIM * CDIM + 255) / 256, 256, 0, stream>>>(op_w, op_wT, CDIM, CDIM, CDIM);
  transpose_cast<<<(AW_OFF * CDIM + 255) / 256, 256, 0, stream>>>(so_w, cat_wT, CDIM, 288, AW_OFF);
  transpose_cast<<<((CAT_N - AW_OFF) * CDIM + 255) / 256, 256, 0, stream>>>(
      aw_w, cat_wT + (size_t)AW_OFF * CDIM, CDIM, 144, CAT_N - AW_OFF);
  pad_bias<<<2, 256, 0, stream>>>(so_b, cat_bp, 288, AW_OFF);
  pad_bias<<<1, 256, 0, stream>>>(aw_b, cat_bp + AW_OFF, 144, CAT_N - AW_OFF);

  // 2) layernorms -> bf16
  ln_cast<<<MQ, 192, 0, stream>>>(query, qn_w, qn_b, q_bf);
  ln_cast<<<MF, 192, 0, stream>>>(feat, fn_w, fn_b, f_bf);

  // 3) value = LN(feat) @ vp_w + vp_b   (counted-vmcnt 256^2, head-major out)
  gemm8_bt<0><<<(MF / 256) * (CDIM / 256), 512, 0, stream>>>(
      f_bf, vp_wT, vp_b, val_bf, MF, CDIM, CDIM, CDIM / 256, nullptr, nullptr);

  // 4) fused sampling-offset | attn-weight GEMM  (2-phase 128^2, f32 out)
  gemm_bt<<<(MQ / 128) * (CAT_N / 128), 256, 0, stream>>>(
      q_bf, cat_wT, cat_bp, raw, MQ, CAT_N, CDIM, CAT_N / 128);

  // 5) softmax + pack {px,py,a} per (q,h,l,p)
  softmax_pack<<<(MQ * NHD) / 256, 256, 0, stream>>>(raw, refp, params);

  // 6) deformable sampling -> samp bf16 [MQ][768]  (XCD-pinned (n,h) groups)
  deform_grp<<<48 * 256, 256, 0, stream>>>((const char*)val_bf, params, samp);

  // 7) out = query + gamma * (samp @ op_w + op_b)   (counted-vmcnt, fused epi)
  gemm8_bt<2><<<(MQ / 256) * (CDIM / 256), 512, 0, stream>>>(
      samp, op_wT, op_b, (float*)d_out, MQ, CDIM, CDIM, CDIM / 256, query, gamma);
}

// Round 7
// 412.435 us; speedup vs baseline: 1.2580x; 1.1483x over previous
//
#include <hip/hip_runtime.h>
#include <hip/hip_bf16.h>
#include <stdint.h>

// ---------------- problem constants (fixed by setup_inputs) ----------------
#define NHD   12        // heads
#define NPT   4         // points
#define CDIM  768
#define HDIM  64
#define NLVL  3
#define LQ    4096
#define NB    4
#define LIN   21504     // 128*128 + 64*64 + 32*32
#define MQ    (NB*LQ)   // 16384 query rows
#define MF    (NB*LIN)  // 86016 feat rows
#define CAT_N 512       // fused so(288) | aw(144) | pad(80)
#define AW_OFF 288

typedef __bf16 bfx8 __attribute__((ext_vector_type(8)));
typedef float  f32x4 __attribute__((ext_vector_type(4)));
typedef float  f32x2 __attribute__((ext_vector_type(2)));

__device__ __forceinline__ ushort f2bf(float x) {
  union { float f; uint32_t u; } v; v.f = x;
  uint32_t r = v.u + 0x7fffu + ((v.u >> 16) & 1u);   // RNE
  return (ushort)(r >> 16);
}

// ---------------- weight transpose + cast:  Wt[n][k] = bf16(W[k][n]) -------
__global__ void transpose_cast(const float* __restrict__ W, ushort* __restrict__ Wt,
                               int K, int Nsrc, int Npad) {
  int t = blockIdx.x * 256 + threadIdx.x;
  if (t >= Npad * K) return;
  int n = t / K, k = t - n * K;
  Wt[t] = (n < Nsrc) ? f2bf(W[(size_t)k * Nsrc + n]) : (ushort)0;
}

__global__ void pad_bias(const float* __restrict__ src, float* __restrict__ dst,
                         int nReal, int nPad) {
  int i = blockIdx.x * 256 + threadIdx.x;
  if (i < nPad) dst[i] = (i < nReal) ? src[i] : 0.f;
}

// ---------------- LayerNorm + cast to bf16 (one block per row) -------------
__global__ __launch_bounds__(192) void ln_cast(const float* __restrict__ x,
                                               const float* __restrict__ w,
                                               const float* __restrict__ b,
                                               ushort* __restrict__ y) {
  const int row = blockIdx.x;
  const int tid = threadIdx.x;                  // 192 threads * float4 = 768
  const float4 v = ((const float4*)(x + (size_t)row * CDIM))[tid];
  float s1 = v.x + v.y + v.z + v.w;
  float s2 = v.x*v.x + v.y*v.y + v.z*v.z + v.w*v.w;
#pragma unroll
  for (int o = 32; o > 0; o >>= 1) { s1 += __shfl_down(s1, o); s2 += __shfl_down(s2, o); }
  __shared__ float r1[3], r2[3];
  const int lane = tid & 63, wv = tid >> 6;
  if (lane == 0) { r1[wv] = s1; r2[wv] = s2; }
  __syncthreads();
  s1 = r1[0] + r1[1] + r1[2];
  s2 = r2[0] + r2[1] + r2[2];
  const float mu = s1 * (1.f / CDIM);
  const float rs = rsqrtf(s2 * (1.f / CDIM) - mu * mu + 1e-6f);
  const float4 w4 = ((const float4*)w)[tid];
  const float4 b4 = ((const float4*)b)[tid];
  ushort4 o4;
  o4.x = f2bf((v.x - mu) * rs * w4.x + b4.x);
  o4.y = f2bf((v.y - mu) * rs * w4.y + b4.y);
  o4.z = f2bf((v.z - mu) * rs * w4.z + b4.z);
  o4.w = f2bf((v.w - mu) * rs * w4.w + b4.w);
  ((ushort4*)(y + (size_t)row * CDIM))[tid] = o4;
}

// ====================== 256x256 counted-vmcnt bf16 GEMM =====================
// C = A[M][K] * Wt[N][K]^T + bias. 512 threads = 8 waves (2M x 4N).
// BK=64 split into K-halves; LDS per buf: A-k0|B-k0|A-k1|B-k1, each [256][32]
// bf16 (16 KB), 2 bufs = 128 KiB. Phase p (kk=p>>1, mg=p&1):
//   { ds_read frags (kk) | stage half p of tile t+1 | 16 MFMA }  + 1 barrier.
// Counted waits: vmcnt(4) at end of p1 and p3 only -- never 0 in steady
// state (T3+T4). Swizzle: 16B slot s at row r holds slot s^((r>>1)&3).
// MODE 0: FP8 e4m3 store, HEAD-MAJOR value layout [n*NHD+h][LIN][64] (1B/el).
// MODE 2: f32, out = resid + gamma*(acc+bias), row-major [M][N].
template<int MODE>
__global__ __launch_bounds__(512, 2) void gemm8_bt(
    const ushort* __restrict__ A, const ushort* __restrict__ Wt,
    const float* __restrict__ bias, void* __restrict__ Cout,
    int M, int N, int K, int nTN,
    const float* __restrict__ resid, const float* __restrict__ gammav)
{
  __shared__ __align__(16) char lds[131072];   // 128 KiB

  int bid = blockIdx.x;
  const int nwg = gridDim.x;
  if ((nwg & 7) == 0) {                 // XCD-chunked swizzle (bijective)
    const int chunk = nwg >> 3;
    bid = (bid & 7) * chunk + (bid >> 3);
  }
  const int mt = bid / nTN, ntl = bid - mt * nTN;
  const int m0 = mt * 256, n0 = ntl * 256;
  const int tid  = threadIdx.x;
  const int lane = tid & 63, wid = tid >> 6;
  const int wm = wid >> 2, wn = wid & 3;           // 2x4 wave grid
  const int lr = lane & 15, lk = lane >> 4;

  f32x4 acc[8][4] = {};

  // stage half h (0=A-k0, 1=B-k0, 2=A-k1, 3=B-k1) of K-tile kt into buf
  auto stage_half = [&](int kt, int h, int buf) {
    const ushort* srcM = (h & 1) ? Wt : A;
    const int base0 = (h & 1) ? n0 : m0;
    const int koff  = kt * 64 + (h >> 1) * 32;
    char* dst0 = lds + buf * 65536 + (h & 1) * 32768 + (h >> 1) * 16384;
#pragma unroll
    for (int it = 0; it < 2; ++it) {
      const int c   = it * 512 + tid;        // 16B chunk id, 1024 per half
      const int row = c >> 2, g = c & 3;
      const ushort* src = srcM + (size_t)(base0 + row) * K + koff
                          + ((g ^ ((row >> 1) & 3)) << 3);   // pre-swizzled src
      char* dst = dst0 + (it * 512 + wid * 64) * 16;         // wave-uniform base
      __builtin_amdgcn_global_load_lds(
          (const __attribute__((address_space(1))) uint32_t*)src,
          (__attribute__((address_space(3))) uint32_t*)dst, 16, 0, 0);
    }
  };
  // swizzled ds_read of one bf16x8 fragment. ab: 0=A,1=B. row in [0,256).
  auto rdfrag = [&](int buf, int ab, int row, int kk) -> bfx8 {
    const int slot = lk ^ ((row >> 1) & 3);
    return *(const bfx8*)(lds + buf * 65536 + ab * 32768 + kk * 16384
                          + row * 64 + slot * 16);
  };

  // prologue: tile 0 fully staged into buf 0
  stage_half(0, 0, 0); stage_half(0, 1, 0); stage_half(0, 2, 0); stage_half(0, 3, 0);
  asm volatile("s_waitcnt vmcnt(0)" ::: "memory");
  __builtin_amdgcn_s_barrier();
  asm volatile("" ::: "memory");

  const int nk = K >> 6;                           // K-tiles of 64
  bfx8 bfr[4];
  for (int t = 0; t < nk; ++t) {
    const int cur = t & 1;
    const bool pre = (t + 1 < nk);
#pragma unroll
    for (int p = 0; p < 4; ++p) {
      const int kk = p >> 1, mg = p & 1;
      if (mg == 0) {
#pragma unroll
        for (int n = 0; n < 4; ++n) bfr[n] = rdfrag(cur, 1, wn * 64 + n * 16 + lr, kk);
      }
      bfx8 af[4];
#pragma unroll
      for (int j = 0; j < 4; ++j)
        af[j] = rdfrag(cur, 0, wm * 128 + (mg * 4 + j) * 16 + lr, kk);
      if (pre) stage_half(t + 1, p, cur ^ 1);
      __builtin_amdgcn_s_setprio(1);
#pragma unroll
      for (int j = 0; j < 4; ++j)
#pragma unroll
        for (int n = 0; n < 4; ++n)
          acc[mg * 4 + j][n] = __builtin_amdgcn_mfma_f32_16x16x32_bf16(
              af[j], bfr[n], acc[mg * 4 + j][n], 0, 0, 0);
      __builtin_amdgcn_s_setprio(0);
      if (p == 1) {               // need h2,h3 of cur before p2 reads
        if (pre) asm volatile("s_waitcnt vmcnt(4)" ::: "memory");
        else     asm volatile("s_waitcnt vmcnt(0)" ::: "memory");
      } else if (p == 3 && pre) { // need h0',h1' of next before its p0
        asm volatile("s_waitcnt vmcnt(4)" ::: "memory");
      }
      __builtin_amdgcn_s_barrier();
      asm volatile("" ::: "memory");
    }
  }

  // ---- epilogue. D layout per MFMA: row = lk*4+i, col = lr (m89-verified).
  if constexpr (MODE == 0) {
    // FP8 head-major value store: Cout layout [n*NHD+h][LIN][64] e4m3.
    // Stage f32 through LDS (row stride 68 f32), read back 16 consecutive
    // f32 per lane, pack to 16 fp8 via v_cvt_pk_fp8_f32, store uint4.
    float* my = (float*)(lds + (nk & 1) * 65536) + wid * (16 * 68);
    float bc[4];
#pragma unroll
    for (int n = 0; n < 4; ++n) bc[n] = bias[n0 + wn * 64 + n * 16 + lr];
    const int rrow = lane >> 2, sgt = lane & 3;     // row 0..15, 16B seg 0..3
    const int n_img = (unsigned)m0 / LIN;           // LIN%256==0: no crossing
    const int head  = (n0 + wn * 64) >> 6;
    char* plane = (char*)Cout
        + ((size_t)(n_img * NHD + head) * LIN + (m0 - n_img * LIN)) * 64;
#pragma unroll
    for (int m = 0; m < 8; ++m) {
#pragma unroll
      for (int n = 0; n < 4; ++n)
#pragma unroll
        for (int i = 0; i < 4; ++i)
          my[(lk * 4 + i) * 68 + n * 16 + lr] = acc[m][n][i] + bc[n];
      const float* src = my + rrow * 68 + sgt * 16;
      uint32_t w[4];
#pragma unroll
      for (int q = 0; q < 4; ++q) {
        uint32_t pk = 0;
        pk = __builtin_amdgcn_cvt_pk_fp8_f32(src[q*4+0], src[q*4+1], pk, false);
        pk = __builtin_amdgcn_cvt_pk_fp8_f32(src[q*4+2], src[q*4+3], pk, true);
        w[q] = pk;
      }
      char* orow = plane + (size_t)(wm * 128 + m * 16 + rrow) * 64 + sgt * 16;
      *(uint4*)orow = *(uint4*)w;
    }
  } else {
#pragma unroll
    for (int n = 0; n < 4; ++n) {
      const int col = n0 + wn * 64 + n * 16 + lr;
      const float bcol = bias[col];
      const float gcol = gammav[col];
#pragma unroll
      for (int m = 0; m < 8; ++m) {
        const int rbase = m0 + wm * 128 + m * 16 + lk * 4;
#pragma unroll
        for (int i = 0; i < 4; ++i) {
          const size_t o = (size_t)(rbase + i) * N + col;
          ((float*)Cout)[o] = resid[o] + gcol * (acc[m][n][i] + bcol);
        }
      }
    }
  }
}

// ---------------- 2-phase 128x128 GEMM (fused so|aw, f32 out) --------------
__global__ __launch_bounds__(256) void gemm_bt(
    const ushort* __restrict__ A, const ushort* __restrict__ Wt,
    const float* __restrict__ bias, float* __restrict__ Cout,
    int M, int N, int K, int nTN)
{
  int bid = blockIdx.x;
  const int nwg = gridDim.x;
  if ((nwg & 7) == 0) {
    const int chunk = nwg >> 3;
    bid = (bid & 7) * chunk + (bid >> 3);
  }
  const int mt = bid / nTN;
  const int nt = bid - mt * nTN;
  const int m0 = mt * 128, n0 = nt * 128;
  const int tid  = threadIdx.x;
  const int lane = tid & 63, wid = tid >> 6;
  const int wm = wid >> 1, wn = wid & 1;
  const int lr = lane & 15, lk = lane >> 4;

  __shared__ __align__(16) ushort lds[2][8192];

  f32x4 acc[4][4] = {};

  auto stage = [&](int kt, int buf) {
    const int k0 = kt * 32;
#pragma unroll
    for (int it = 0; it < 2; ++it) {
      const int c   = it * 256 + wid * 64 + lane;
      const int row = c >> 2, g = c & 3;
      const ushort* srcA = A + (size_t)(m0 + row) * K + (k0 + g * 8);
      ushort* dstA = &lds[buf][(it * 256 + wid * 64) * 8];
      __builtin_amdgcn_global_load_lds(
          (const __attribute__((address_space(1))) uint32_t*)srcA,
          (__attribute__((address_space(3))) uint32_t*)dstA, 16, 0, 0);
      const ushort* srcB = Wt + (size_t)(n0 + row) * K + (k0 + g * 8);
      ushort* dstB = &lds[buf][4096 + (it * 256 + wid * 64) * 8];
      __builtin_amdgcn_global_load_lds(
          (const __attribute__((address_space(1))) uint32_t*)srcB,
          (__attribute__((address_space(3))) uint32_t*)dstB, 16, 0, 0);
    }
  };

  stage(0, 0);
  __syncthreads();
  const int nk = K >> 5;
  for (int kt = 0; kt < nk; ++kt) {
    const int cur = kt & 1;
    if (kt + 1 < nk) stage(kt + 1, cur ^ 1);
    const ushort* As = &lds[cur][0];
    const ushort* Bs = &lds[cur][4096];
    bfx8 af[4], bv[4];
#pragma unroll
    for (int m = 0; m < 4; ++m)
      af[m] = *(const bfx8*)(As + (wm * 64 + m * 16 + lr) * 32 + lk * 8);
#pragma unroll
    for (int n = 0; n < 4; ++n)
      bv[n] = *(const bfx8*)(Bs + (wn * 64 + n * 16 + lr) * 32 + lk * 8);
#pragma unroll
    for (int m = 0; m < 4; ++m)
#pragma unroll
      for (int n = 0; n < 4; ++n)
        acc[m][n] = __builtin_amdgcn_mfma_f32_16x16x32_bf16(af[m], bv[n], acc[m][n], 0, 0, 0);
    __syncthreads();
  }

#pragma unroll
  for (int n = 0; n < 4; ++n) {
    const int col = n0 + wn * 64 + n * 16 + lr;
    const float bcol = bias[col];
#pragma unroll
    for (int m = 0; m < 4; ++m) {
      const int rbase = m0 + wm * 64 + m * 16 + lk * 4;
#pragma unroll
      for (int i = 0; i < 4; ++i)
        Cout[(size_t)(rbase + i) * N + col] = acc[m][n][i] + bcol;
    }
  }
}

// ---------------- softmax over 12 + pack sampling params --------------------
// raw layout per (nq): [0,288) sampling offsets, [288,432) attn logits.
__global__ void softmax_pack(const float* __restrict__ raw,
                             const float* __restrict__ refp,
                             float4* __restrict__ params) {
  const int t = blockIdx.x * 256 + threadIdx.x;       // [0, MQ*NHD)
  const int h = t % NHD, nq = t / NHD;
  const float* p = raw + (size_t)nq * CAT_N + AW_OFF + h * 12;
  float v[12], m = -1e30f;
#pragma unroll
  for (int j = 0; j < 12; ++j) { v[j] = p[j]; m = fmaxf(m, v[j]); }
  float s = 0.f;
#pragma unroll
  for (int j = 0; j < 12; ++j) { v[j] = __expf(v[j] - m); s += v[j]; }
  const float inv = 1.f / s;
  const float* op = raw + (size_t)nq * CAT_N + h * 24;
  const float* rp = refp + (size_t)nq * (NLVL * 2);
  float4* out = params + (size_t)t * 12;
  const float Wf[3] = {128.f, 64.f, 32.f};
#pragma unroll
  for (int l = 0; l < NLVL; ++l) {
    const float rxw = rp[2 * l] * Wf[l] - 0.5f;
    const float ryw = rp[2 * l + 1] * Wf[l] - 0.5f;
#pragma unroll
    for (int pt = 0; pt < NPT; ++pt) {
      float4 o4;
      o4.x = rxw + op[(l * 4 + pt) * 2 + 0];
      o4.y = ryw + op[(l * 4 + pt) * 2 + 1];
      o4.z = v[l * 4 + pt] * inv;
      o4.w = 0.f;
      out[l * 4 + pt] = o4;
    }
  }
}

// ---------------- deformable bilinear sampling, fp8 value ------------------
// value layout: [g=n*NHD+h][LIN][64] e4m3 -> one plane = 1.37 MB (2 fit/L2).
// Group g pinned to XCD g%8 via blockIdx%8; 256 blocks/group = one full
// residency batch per XCD. Wave: 4 queries x 16 lanes; lane&15 = channel
// quad; gather = uint32 (4 fp8), decode via v_cvt_pk_f32_fp8.
__global__ __launch_bounds__(256) void deform_grp(
    const char* __restrict__ vbytes, const float4* __restrict__ params,
    ushort* __restrict__ samp)
{
  const int j = blockIdx.x;
  const int x = j & 7, k = j >> 3;
  const int g = x + ((k >> 8) << 3);          // plane = n*NHD+h, pinned to XCD x
  const int i = k & 255;                      // block within group
  const int n = g / NHD, h = g - n * NHD;
  const int wid  = threadIdx.x >> 6;
  const int lane = threadIdx.x & 63;
  const int q  = i * 16 + wid * 4 + (lane >> 4);        // [0, 4096)
  const int nq = n * LQ + q;
  const float4* __restrict__ pp = params + ((size_t)nq * NHD + h) * 12;
  const uint32_t base0 = (uint32_t)g * (uint32_t)(LIN * 64)
                       + ((uint32_t)(lane & 15) << 2);

  float acc0 = 0.f, acc1 = 0.f, acc2 = 0.f, acc3 = 0.f;

  const int      Wl[3]  = {128, 64, 32};
  const uint32_t STb[3] = {0u, 16384u * 64u, 20480u * 64u};

#pragma unroll
  for (int l = 0; l < NLVL; ++l) {
    const int W_ = Wl[l];
    const uint32_t base = base0 + STb[l];
#pragma unroll
    for (int p = 0; p < NPT; ++p) {
      const float4 pt = pp[l * 4 + p];
      const float fx = floorf(pt.x), fy = floorf(pt.y);
      const float tx = pt.x - fx,   ty = pt.y - fy;
      const int x0 = (int)fx, y0 = (int)fy;
      const int x1 = x0 + 1,  y1 = y0 + 1;
      const float wx0 = ((uint32_t)x0 < (uint32_t)W_) ? (1.f - tx) : 0.f;
      const float wx1 = ((uint32_t)x1 < (uint32_t)W_) ? tx : 0.f;
      const float wy0 = ((uint32_t)y0 < (uint32_t)W_) ? pt.z * (1.f - ty) : 0.f;
      const float wy1 = ((uint32_t)y1 < (uint32_t)W_) ? pt.z * ty : 0.f;
      const int xc0 = min(max(x0, 0), W_ - 1);
      const int xc1 = min(max(x1, 0), W_ - 1);
      const int yr0 = min(max(y0, 0), W_ - 1) * W_;
      const int yr1 = min(max(y1, 0), W_ - 1) * W_;
      const float w00 = wy0 * wx0, w01 = wy0 * wx1;
      const float w10 = wy1 * wx0, w11 = wy1 * wx1;
      const uint32_t g00 = *(const uint32_t*)(vbytes + base + (uint32_t)(yr0 + xc0) * 64u);
      const uint32_t g01 = *(const uint32_t*)(vbytes + base + (uint32_t)(yr0 + xc1) * 64u);
      const uint32_t g10 = *(const uint32_t*)(vbytes + base + (uint32_t)(yr1 + xc0) * 64u);
      const uint32_t g11 = *(const uint32_t*)(vbytes + base + (uint32_t)(yr1 + xc1) * 64u);
      {
        f32x2 lo = __builtin_amdgcn_cvt_pk_f32_fp8(g00, false);
        f32x2 hi = __builtin_amdgcn_cvt_pk_f32_fp8(g00, true);
        acc0 += lo[0] * w00; acc1 += lo[1] * w00; acc2 += hi[0] * w00; acc3 += hi[1] * w00;
      }
      {
        f32x2 lo = __builtin_amdgcn_cvt_pk_f32_fp8(g01, false);
        f32x2 hi = __builtin_amdgcn_cvt_pk_f32_fp8(g01, true);
        acc0 += lo[0] * w01; acc1 += lo[1] * w01; acc2 += hi[0] * w01; acc3 += hi[1] * w01;
      }
      {
        f32x2 lo = __builtin_amdgcn_cvt_pk_f32_fp8(g10, false);
        f32x2 hi = __builtin_amdgcn_cvt_pk_f32_fp8(g10, true);
        acc0 += lo[0] * w10; acc1 += lo[1] * w10; acc2 += hi[0] * w10; acc3 += hi[1] * w10;
      }
      {
        f32x2 lo = __builtin_amdgcn_cvt_pk_f32_fp8(g11, false);
        f32x2 hi = __builtin_amdgcn_cvt_pk_f32_fp8(g11, true);
        acc0 += lo[0] * w11; acc1 += lo[1] * w11; acc2 += hi[0] * w11; acc3 += hi[1] * w11;
      }
    }
  }

  ushort4 o;
  o.x = f2bf(acc0); o.y = f2bf(acc1); o.z = f2bf(acc2); o.w = f2bf(acc3);
  *(ushort4*)(samp + (size_t)nq * CDIM + h * HDIM + (lane & 15) * 4) = o;
}

// ---------------- host ------------------------------------------------------
extern "C" void kernel_launch(void* const* d_in, const int* in_sizes, int n_in,
                              void* d_out, int out_size, void* d_ws, size_t ws_size,
                              hipStream_t stream) {
  const float* query = (const float*)d_in[0];
  const float* refp  = (const float*)d_in[1];
  const float* feat  = (const float*)d_in[2];
  const float* qn_w  = (const float*)d_in[3];
  const float* qn_b  = (const float*)d_in[4];
  const float* fn_w  = (const float*)d_in[5];
  const float* fn_b  = (const float*)d_in[6];
  const float* gamma = (const float*)d_in[7];
  const float* so_w  = (const float*)d_in[8];
  const float* so_b  = (const float*)d_in[9];
  const float* aw_w  = (const float*)d_in[10];
  const float* aw_b  = (const float*)d_in[11];
  const float* vp_w  = (const float*)d_in[12];
  const float* vp_b  = (const float*)d_in[13];
  const float* op_w  = (const float*)d_in[14];
  const float* op_b  = (const float*)d_in[15];

  char* ws = (char*)d_ws;
  size_t off = 0;
  auto alloc = [&](size_t bytes) {
    char* p = ws + off;
    off = (off + bytes + 255) & ~(size_t)255;
    return p;
  };
  ushort* q_bf   = (ushort*)alloc((size_t)MQ * CDIM * 2);
  char*   val_f8 = (char*)alloc((size_t)MF * CDIM);        // [48][LIN][64] e4m3
  ushort* vp_wT  = (ushort*)alloc((size_t)CDIM * CDIM * 2);
  ushort* op_wT  = (ushort*)alloc((size_t)CDIM * CDIM * 2);
  ushort* cat_wT = (ushort*)alloc((size_t)CAT_N * CDIM * 2);
  float*  cat_bp = (float*)alloc(CAT_N * 4);

  // region R: f_bf (phase A) aliases the phase-B buffers
  const size_t r = off;
  ushort* f_bf = (ushort*)(ws + r);
  const size_t f_end = r + (size_t)MF * CDIM * 2;
  size_t o2 = r;
  float*  raw     = (float*)(ws + o2);  o2 += (size_t)MQ * CAT_N * 4;
  float4* params  = (float4*)(ws + o2); o2 += (size_t)MQ * NHD * 12 * 16;
  ushort* samp    = (ushort*)(ws + o2); o2 += (size_t)MQ * CDIM * 2;
  const size_t need = (f_end > o2) ? f_end : o2;
  if (ws_size < need) return;   // ~226 MB required

  // 1) weights -> bf16 transposed (+ padded biases). cat = [so | aw | pad]
  transpose_cast<<<(CDIM * CDIM + 255) / 256, 256, 0, stream>>>(vp_w, vp_wT, CDIM, CDIM, CDIM);
  transpose_cast<<<(CDIM * CDIM + 255) / 256, 256, 0, stream>>>(op_w, op_wT, CDIM, CDIM, CDIM);
  transpose_cast<<<(AW_OFF * CDIM + 255) / 256, 256, 0, stream>>>(so_w, cat_wT, CDIM, 288, AW_OFF);
  transpose_cast<<<((CAT_N - AW_OFF) * CDIM + 255) / 256, 256, 0, stream>>>(
      aw_w, cat_wT + (size_t)AW_OFF * CDIM, CDIM, 144, CAT_N - AW_OFF);
  pad_bias<<<2, 256, 0, stream>>>(so_b, cat_bp, 288, AW_OFF);
  pad_bias<<<1, 256, 0, stream>>>(aw_b, cat_bp + AW_OFF, 144, CAT_N - AW_OFF);

  // 2) layernorms -> bf16
  ln_cast<<<MQ, 192, 0, stream>>>(query, qn_w, qn_b, q_bf);
  ln_cast<<<MF, 192, 0, stream>>>(feat, fn_w, fn_b, f_bf);

  // 3) value = LN(feat) @ vp_w + vp_b   (counted-vmcnt 256^2, fp8 head-major)
  gemm8_bt<0><<<(MF / 256) * (CDIM / 256), 512, 0, stream>>>(
      f_bf, vp_wT, vp_b, val_f8, MF, CDIM, CDIM, CDIM / 256, nullptr, nullptr);

  // 4) fused sampling-offset | attn-weight GEMM  (2-phase 128^2, f32 out)
  gemm_bt<<<(MQ / 128) * (CAT_N / 128), 256, 0, stream>>>(
      q_bf, cat_wT, cat_bp, raw, MQ, CAT_N, CDIM, CAT_N / 128);

  // 5) softmax + pack {px,py,a} per (q,h,l,p)
  softmax_pack<<<(MQ * NHD) / 256, 256, 0, stream>>>(raw, refp, params);

  // 6) deformable sampling -> samp bf16 [MQ][768]  (fp8 gathers, XCD-pinned)
  deform_grp<<<48 * 256, 256, 0, stream>>>(val_f8, params, samp);

  // 7) out = query + gamma * (samp @ op_w + op_b)   (counted-vmcnt, fused epi)
  gemm8_bt<2><<<(MQ / 256) * (CDIM / 256), 512, 0, stream>>>(
      samp, op_wT, op_b, (float*)d_out, MQ, CDIM, CDIM, CDIM / 256, query, gamma);
}

// Round 8
// 407.748 us; speedup vs baseline: 1.2725x; 1.0115x over previous
//
#include <hip/hip_runtime.h>
#include <hip/hip_bf16.h>
#include <stdint.h>

// ---------------- problem constants (fixed by setup_inputs) ----------------
#define NHD   12        // heads
#define NPT   4         // points
#define CDIM  768
#define HDIM  64
#define NLVL  3
#define LQ    4096
#define NB    4
#define LIN   21504     // 128*128 + 64*64 + 32*32
#define MQ    (NB*LQ)   // 16384 query rows
#define MF    (NB*LIN)  // 86016 feat rows
#define CAT_N 512       // fused so(288) | aw(144) | pad(80)
#define AW_OFF 288

typedef __bf16 bfx8 __attribute__((ext_vector_type(8)));
typedef float  f32x4 __attribute__((ext_vector_type(4)));
typedef float  f32x2 __attribute__((ext_vector_type(2)));

__device__ __forceinline__ ushort f2bf(float x) {
  union { float f; uint32_t u; } v; v.f = x;
  uint32_t r = v.u + 0x7fffu + ((v.u >> 16) & 1u);   // RNE
  return (ushort)(r >> 16);
}
__device__ __forceinline__ long u2l(uint2 v) {
  union { uint2 u; long l; } x; x.u = v; return x.l;
}

// ---------------- weight transpose + cast ----------------------------------
__global__ void transpose_cast(const float* __restrict__ W, ushort* __restrict__ Wt,
                               int K, int Nsrc, int Npad) {
  int t = blockIdx.x * 256 + threadIdx.x;
  if (t >= Npad * K) return;
  int n = t / K, k = t - n * K;
  Wt[t] = (n < Nsrc) ? f2bf(W[(size_t)k * Nsrc + n]) : (ushort)0;
}

__global__ void transpose_cast_f8(const float* __restrict__ W, char* __restrict__ Wt,
                                  int K, int N) {
  int t = blockIdx.x * 256 + threadIdx.x;
  if (t >= N * K) return;
  int n = t / K, k = t - n * K;
  uint32_t pk = __builtin_amdgcn_cvt_pk_fp8_f32(W[(size_t)k * N + n], 0.f, 0, false);
  Wt[t] = (char)(pk & 0xff);
}

__global__ void pad_bias(const float* __restrict__ src, float* __restrict__ dst,
                         int nReal, int nPad) {
  int i = blockIdx.x * 256 + threadIdx.x;
  if (i < nPad) dst[i] = (i < nReal) ? src[i] : 0.f;
}

// ---------------- LayerNorm + cast (OUT8: 0 = bf16, 1 = fp8 e4m3) ----------
template<int OUT8>
__global__ __launch_bounds__(192) void ln_cast(const float* __restrict__ x,
                                               const float* __restrict__ w,
                                               const float* __restrict__ b,
                                               void* __restrict__ y) {
  const int row = blockIdx.x;
  const int tid = threadIdx.x;                  // 192 threads * float4 = 768
  const float4 v = ((const float4*)(x + (size_t)row * CDIM))[tid];
  float s1 = v.x + v.y + v.z + v.w;
  float s2 = v.x*v.x + v.y*v.y + v.z*v.z + v.w*v.w;
#pragma unroll
  for (int o = 32; o > 0; o >>= 1) { s1 += __shfl_down(s1, o); s2 += __shfl_down(s2, o); }
  __shared__ float r1[3], r2[3];
  const int lane = tid & 63, wv = tid >> 6;
  if (lane == 0) { r1[wv] = s1; r2[wv] = s2; }
  __syncthreads();
  s1 = r1[0] + r1[1] + r1[2];
  s2 = r2[0] + r2[1] + r2[2];
  const float mu = s1 * (1.f / CDIM);
  const float rs = rsqrtf(s2 * (1.f / CDIM) - mu * mu + 1e-6f);
  const float4 w4 = ((const float4*)w)[tid];
  const float4 b4 = ((const float4*)b)[tid];
  const float o0 = (v.x - mu) * rs * w4.x + b4.x;
  const float o1 = (v.y - mu) * rs * w4.y + b4.y;
  const float o2 = (v.z - mu) * rs * w4.z + b4.z;
  const float o3 = (v.w - mu) * rs * w4.w + b4.w;
  if constexpr (OUT8) {
    uint32_t pk = 0;
    pk = __builtin_amdgcn_cvt_pk_fp8_f32(o0, o1, pk, false);
    pk = __builtin_amdgcn_cvt_pk_fp8_f32(o2, o3, pk, true);
    ((uint32_t*)((char*)y + (size_t)row * CDIM))[tid] = pk;
  } else {
    ushort4 o4;
    o4.x = f2bf(o0); o4.y = f2bf(o1); o4.z = f2bf(o2); o4.w = f2bf(o3);
    ((ushort4*)((ushort*)y + (size_t)row * CDIM))[tid] = o4;
  }
}

// ================= 256x256 fp8 GEMM, triple-buffered K-pipeline =============
// C = A[M][K](e4m3) * Wt[N][K](e4m3)^T + bias. 512 thr = 8 waves (2M x 4N).
// BK=64; half h = (kk=h>>1, ab=h&1), each [256 rows][32 B] packed as
// [128 lines][64 B] (line j = rows 2j,2j+1; 16B chunk g holds source chunk
// g^((j>>1)&3) -- bank-distinct per 16-lane quarter-wave on ds_read_b64).
// 3 LDS bufs x 32 KB: stage tile t+2 during tile t (1 load/thr/half);
// ONE wait/tile: vmcnt(4) at p3 => tile t+1 ready, ~7 phases of cover.
// MODE 0: fp8 head-major value store [n*NHD+h][LIN][64].
// MODE 2: f32, out = resid + gamma*(acc+bias), row-major [M][N].
template<int MODE>
__global__ __launch_bounds__(512, 2) void gemm8_f8(
    const char* __restrict__ A, const char* __restrict__ Wt,
    const float* __restrict__ bias, void* __restrict__ Cout,
    int M, int N, int K, int nTN,
    const float* __restrict__ resid, const float* __restrict__ gammav)
{
  __shared__ __align__(16) char lds[98304];   // 3 x 32 KiB

  int bid = blockIdx.x;
  const int nwg = gridDim.x;
  if ((nwg & 7) == 0) {                 // XCD-chunked swizzle (bijective)
    const int chunk = nwg >> 3;
    bid = (bid & 7) * chunk + (bid >> 3);
  }
  const int mt = bid / nTN, ntl = bid - mt * nTN;
  const int m0 = mt * 256, n0 = ntl * 256;
  const int tid  = threadIdx.x;
  const int lane = tid & 63, wid = tid >> 6;
  const int wm = wid >> 2, wn = wid & 3;           // 2x4 wave grid
  const int lr = lane & 15, lk = lane >> 4;

  f32x4 acc[8][4] = {};

  // stage half h of K-tile kt into buf (one 16B gload_lds per thread)
  auto stage_half = [&](int kt, int h, int buf) {
    const char* srcM = (h & 1) ? Wt : A;
    const int base0 = (h & 1) ? n0 : m0;
    const int koff  = kt * 64 + (h >> 1) * 32;
    const int j = tid >> 2, g = tid & 3;
    const int c = g ^ ((j >> 1) & 3);              // source chunk (involution)
    const char* src = srcM + (size_t)(base0 + 2 * j + (c >> 1)) * K
                           + koff + (c & 1) * 16;
    char* dst = lds + buf * 32768 + h * 8192 + wid * 1024;  // + lane*16 by HW
    __builtin_amdgcn_global_load_lds(
        (const __attribute__((address_space(1))) uint32_t*)src,
        (__attribute__((address_space(3))) uint32_t*)dst, 16, 0, 0);
  };
  // swizzled ds_read_b64 of one 8-fp8 fragment. ab: 0=A,1=B. row in [0,256).
  auto rdfrag = [&](int buf, int ab, int row, int kk) -> uint2 {
    const int j = row >> 1;
    const int g = (((row & 1) << 1) + (lk >> 1)) ^ ((j >> 1) & 3);
    return *(const uint2*)(lds + buf * 32768 + (kk * 2 + ab) * 8192
                           + j * 64 + g * 16 + (lk & 1) * 8);
  };

  const int nk = K >> 6;                           // K-tiles of 64
  // prologue: tiles 0 and 1 staged into bufs 0,1
#pragma unroll
  for (int h = 0; h < 4; ++h) stage_half(0, h, 0);
#pragma unroll
  for (int h = 0; h < 4; ++h) stage_half(1, h, 1);
  asm volatile("s_waitcnt vmcnt(4)" ::: "memory"); // tile 0 ready
  __builtin_amdgcn_s_barrier();
  asm volatile("" ::: "memory");

  uint2 bfr[4];
  for (int t = 0; t < nk; ++t) {
    const int cur = t % 3;
    const int tgt = (t + 2) % 3;
    const bool pre2 = (t + 2 < nk);
#pragma unroll
    for (int p = 0; p < 4; ++p) {
      const int kk = p >> 1, mg = p & 1;
      if (mg == 0) {
#pragma unroll
        for (int n = 0; n < 4; ++n) bfr[n] = rdfrag(cur, 1, wn * 64 + n * 16 + lr, kk);
      }
      uint2 af[4];
#pragma unroll
      for (int j = 0; j < 4; ++j)
        af[j] = rdfrag(cur, 0, wm * 128 + (mg * 4 + j) * 16 + lr, kk);
      if (pre2) stage_half(t + 2, p, tgt);
      __builtin_amdgcn_s_setprio(1);
#pragma unroll
      for (int j = 0; j < 4; ++j)
#pragma unroll
        for (int n = 0; n < 4; ++n)
          acc[mg * 4 + j][n] = __builtin_amdgcn_mfma_f32_16x16x32_fp8_fp8(
              u2l(af[j]), u2l(bfr[n]), acc[mg * 4 + j][n], 0, 0, 0);
      __builtin_amdgcn_s_setprio(0);
      if (p == 3 && t + 1 < nk) {      // tile t+1 fully staged before its p0
        if (pre2) asm volatile("s_waitcnt vmcnt(4)" ::: "memory");
        else      asm volatile("s_waitcnt vmcnt(0)" ::: "memory");
      }
      __builtin_amdgcn_s_barrier();
      asm volatile("" ::: "memory");
    }
  }

  // ---- epilogue. D layout per MFMA: row = lk*4+i, col = lr (m89-verified).
  if constexpr (MODE == 0) {
    // fp8 head-major value store: [n*NHD+head][LIN][64] e4m3, via LDS stage.
    float* my = (float*)lds + wid * 1088;          // 16 rows x 68 f32 per wave
    float bc[4];
#pragma unroll
    for (int n = 0; n < 4; ++n) bc[n] = bias[n0 + wn * 64 + n * 16 + lr];
    const int rrow = lane >> 2, sgt = lane & 3;    // row 0..15, 16B seg 0..3
    const int n_img = (unsigned)m0 / LIN;          // LIN%256==0: no crossing
    const int head  = (n0 + wn * 64) >> 6;
    char* plane = (char*)Cout
        + ((size_t)(n_img * NHD + head) * LIN + (m0 - n_img * LIN)) * 64;
#pragma unroll
    for (int m = 0; m < 8; ++m) {
#pragma unroll
      for (int n = 0; n < 4; ++n)
#pragma unroll
        for (int i = 0; i < 4; ++i)
          my[(lk * 4 + i) * 68 + n * 16 + lr] = acc[m][n][i] + bc[n];
      const float* src = my + rrow * 68 + sgt * 16;
      uint32_t w[4];
#pragma unroll
      for (int q = 0; q < 4; ++q) {
        uint32_t pk = 0;
        pk = __builtin_amdgcn_cvt_pk_fp8_f32(src[q*4+0], src[q*4+1], pk, false);
        pk = __builtin_amdgcn_cvt_pk_fp8_f32(src[q*4+2], src[q*4+3], pk, true);
        w[q] = pk;
      }
      char* orow = plane + (size_t)(wm * 128 + m * 16 + rrow) * 64 + sgt * 16;
      *(uint4*)orow = *(uint4*)w;
    }
  } else {
#pragma unroll
    for (int n = 0; n < 4; ++n) {
      const int col = n0 + wn * 64 + n * 16 + lr;
      const float bcol = bias[col];
      const float gcol = gammav[col];
#pragma unroll
      for (int m = 0; m < 8; ++m) {
        const int rbase = m0 + wm * 128 + m * 16 + lk * 4;
#pragma unroll
        for (int i = 0; i < 4; ++i) {
          const size_t o = (size_t)(rbase + i) * N + col;
          ((float*)Cout)[o] = resid[o] + gcol * (acc[m][n][i] + bcol);
        }
      }
    }
  }
}

// ---------------- 2-phase 128x128 bf16 GEMM (fused so|aw, f32 out) ---------
__global__ __launch_bounds__(256) void gemm_bt(
    const ushort* __restrict__ A, const ushort* __restrict__ Wt,
    const float* __restrict__ bias, float* __restrict__ Cout,
    int M, int N, int K, int nTN)
{
  int bid = blockIdx.x;
  const int nwg = gridDim.x;
  if ((nwg & 7) == 0) {
    const int chunk = nwg >> 3;
    bid = (bid & 7) * chunk + (bid >> 3);
  }
  const int mt = bid / nTN;
  const int nt = bid - mt * nTN;
  const int m0 = mt * 128, n0 = nt * 128;
  const int tid  = threadIdx.x;
  const int lane = tid & 63, wid = tid >> 6;
  const int wm = wid >> 1, wn = wid & 1;
  const int lr = lane & 15, lk = lane >> 4;

  __shared__ __align__(16) ushort lds[2][8192];

  f32x4 acc[4][4] = {};

  auto stage = [&](int kt, int buf) {
    const int k0 = kt * 32;
#pragma unroll
    for (int it = 0; it < 2; ++it) {
      const int c   = it * 256 + wid * 64 + lane;
      const int row = c >> 2, g = c & 3;
      const ushort* srcA = A + (size_t)(m0 + row) * K + (k0 + g * 8);
      ushort* dstA = &lds[buf][(it * 256 + wid * 64) * 8];
      __builtin_amdgcn_global_load_lds(
          (const __attribute__((address_space(1))) uint32_t*)srcA,
          (__attribute__((address_space(3))) uint32_t*)dstA, 16, 0, 0);
      const ushort* srcB = Wt + (size_t)(n0 + row) * K + (k0 + g * 8);
      ushort* dstB = &lds[buf][4096 + (it * 256 + wid * 64) * 8];
      __builtin_amdgcn_global_load_lds(
          (const __attribute__((address_space(1))) uint32_t*)srcB,
          (__attribute__((address_space(3))) uint32_t*)dstB, 16, 0, 0);
    }
  };

  stage(0, 0);
  __syncthreads();
  const int nk = K >> 5;
  for (int kt = 0; kt < nk; ++kt) {
    const int cur = kt & 1;
    if (kt + 1 < nk) stage(kt + 1, cur ^ 1);
    const ushort* As = &lds[cur][0];
    const ushort* Bs = &lds[cur][4096];
    bfx8 af[4], bv[4];
#pragma unroll
    for (int m = 0; m < 4; ++m)
      af[m] = *(const bfx8*)(As + (wm * 64 + m * 16 + lr) * 32 + lk * 8);
#pragma unroll
    for (int n = 0; n < 4; ++n)
      bv[n] = *(const bfx8*)(Bs + (wn * 64 + n * 16 + lr) * 32 + lk * 8);
#pragma unroll
    for (int m = 0; m < 4; ++m)
#pragma unroll
      for (int n = 0; n < 4; ++n)
        acc[m][n] = __builtin_amdgcn_mfma_f32_16x16x32_bf16(af[m], bv[n], acc[m][n], 0, 0, 0);
    __syncthreads();
  }

#pragma unroll
  for (int n = 0; n < 4; ++n) {
    const int col = n0 + wn * 64 + n * 16 + lr;
    const float bcol = bias[col];
#pragma unroll
    for (int m = 0; m < 4; ++m) {
      const int rbase = m0 + wm * 64 + m * 16 + lk * 4;
#pragma unroll
      for (int i = 0; i < 4; ++i)
        Cout[(size_t)(rbase + i) * N + col] = acc[m][n][i] + bcol;
    }
  }
}

// ---------------- softmax over 12 + pack sampling params --------------------
__global__ void softmax_pack(const float* __restrict__ raw,
                             const float* __restrict__ refp,
                             float4* __restrict__ params) {
  const int t = blockIdx.x * 256 + threadIdx.x;       // [0, MQ*NHD)
  const int h = t % NHD, nq = t / NHD;
  const float* p = raw + (size_t)nq * CAT_N + AW_OFF + h * 12;
  float v[12], m = -1e30f;
#pragma unroll
  for (int j = 0; j < 12; ++j) { v[j] = p[j]; m = fmaxf(m, v[j]); }
  float s = 0.f;
#pragma unroll
  for (int j = 0; j < 12; ++j) { v[j] = __expf(v[j] - m); s += v[j]; }
  const float inv = 1.f / s;
  const float* op = raw + (size_t)nq * CAT_N + h * 24;
  const float* rp = refp + (size_t)nq * (NLVL * 2);
  float4* out = params + (size_t)t * 12;
  const float Wf[3] = {128.f, 64.f, 32.f};
#pragma unroll
  for (int l = 0; l < NLVL; ++l) {
    const float rxw = rp[2 * l] * Wf[l] - 0.5f;
    const float ryw = rp[2 * l + 1] * Wf[l] - 0.5f;
#pragma unroll
    for (int pt = 0; pt < NPT; ++pt) {
      float4 o4;
      o4.x = rxw + op[(l * 4 + pt) * 2 + 0];
      o4.y = ryw + op[(l * 4 + pt) * 2 + 1];
      o4.z = v[l * 4 + pt] * inv;
      o4.w = 0.f;
      out[l * 4 + pt] = o4;
    }
  }
}

// ---------------- deformable bilinear sampling, fp8 value/samp -------------
__global__ __launch_bounds__(256) void deform_grp(
    const char* __restrict__ vbytes, const float4* __restrict__ params,
    char* __restrict__ samp)
{
  const int j = blockIdx.x;
  const int x = j & 7, k = j >> 3;
  const int g = x + ((k >> 8) << 3);          // plane = n*NHD+h, pinned to XCD x
  const int i = k & 255;                      // block within group
  const int n = g / NHD, h = g - n * NHD;
  const int wid  = threadIdx.x >> 6;
  const int lane = threadIdx.x & 63;
  const int q  = i * 16 + wid * 4 + (lane >> 4);        // [0, 4096)
  const int nq = n * LQ + q;
  const float4* __restrict__ pp = params + ((size_t)nq * NHD + h) * 12;
  const uint32_t base0 = (uint32_t)g * (uint32_t)(LIN * 64)
                       + ((uint32_t)(lane & 15) << 2);

  float acc0 = 0.f, acc1 = 0.f, acc2 = 0.f, acc3 = 0.f;

  const int      Wl[3]  = {128, 64, 32};
  const uint32_t STb[3] = {0u, 16384u * 64u, 20480u * 64u};

#pragma unroll
  for (int l = 0; l < NLVL; ++l) {
    const int W_ = Wl[l];
    const uint32_t base = base0 + STb[l];
#pragma unroll
    for (int p = 0; p < NPT; ++p) {
      const float4 pt = pp[l * 4 + p];
      const float fx = floorf(pt.x), fy = floorf(pt.y);
      const float tx = pt.x - fx,   ty = pt.y - fy;
      const int x0 = (int)fx, y0 = (int)fy;
      const int x1 = x0 + 1,  y1 = y0 + 1;
      const float wx0 = ((uint32_t)x0 < (uint32_t)W_) ? (1.f - tx) : 0.f;
      const float wx1 = ((uint32_t)x1 < (uint32_t)W_) ? tx : 0.f;
      const float wy0 = ((uint32_t)y0 < (uint32_t)W_) ? pt.z * (1.f - ty) : 0.f;
      const float wy1 = ((uint32_t)y1 < (uint32_t)W_) ? pt.z * ty : 0.f;
      const int xc0 = min(max(x0, 0), W_ - 1);
      const int xc1 = min(max(x1, 0), W_ - 1);
      const int yr0 = min(max(y0, 0), W_ - 1) * W_;
      const int yr1 = min(max(y1, 0), W_ - 1) * W_;
      const float w00 = wy0 * wx0, w01 = wy0 * wx1;
      const float w10 = wy1 * wx0, w11 = wy1 * wx1;
      const uint32_t g00 = *(const uint32_t*)(vbytes + base + (uint32_t)(yr0 + xc0) * 64u);
      const uint32_t g01 = *(const uint32_t*)(vbytes + base + (uint32_t)(yr0 + xc1) * 64u);
      const uint32_t g10 = *(const uint32_t*)(vbytes + base + (uint32_t)(yr1 + xc0) * 64u);
      const uint32_t g11 = *(const uint32_t*)(vbytes + base + (uint32_t)(yr1 + xc1) * 64u);
      {
        f32x2 lo = __builtin_amdgcn_cvt_pk_f32_fp8(g00, false);
        f32x2 hi = __builtin_amdgcn_cvt_pk_f32_fp8(g00, true);
        acc0 += lo[0] * w00; acc1 += lo[1] * w00; acc2 += hi[0] * w00; acc3 += hi[1] * w00;
      }
      {
        f32x2 lo = __builtin_amdgcn_cvt_pk_f32_fp8(g01, false);
        f32x2 hi = __builtin_amdgcn_cvt_pk_f32_fp8(g01, true);
        acc0 += lo[0] * w01; acc1 += lo[1] * w01; acc2 += hi[0] * w01; acc3 += hi[1] * w01;
      }
      {
        f32x2 lo = __builtin_amdgcn_cvt_pk_f32_fp8(g10, false);
        f32x2 hi = __builtin_amdgcn_cvt_pk_f32_fp8(g10, true);
        acc0 += lo[0] * w10; acc1 += lo[1] * w10; acc2 += hi[0] * w10; acc3 += hi[1] * w10;
      }
      {
        f32x2 lo = __builtin_amdgcn_cvt_pk_f32_fp8(g11, false);
        f32x2 hi = __builtin_amdgcn_cvt_pk_f32_fp8(g11, true);
        acc0 += lo[0] * w11; acc1 += lo[1] * w11; acc2 += hi[0] * w11; acc3 += hi[1] * w11;
      }
    }
  }

  uint32_t pk = 0;
  pk = __builtin_amdgcn_cvt_pk_fp8_f32(acc0, acc1, pk, false);
  pk = __builtin_amdgcn_cvt_pk_fp8_f32(acc2, acc3, pk, true);
  *(uint32_t*)(samp + (size_t)nq * CDIM + h * HDIM + (lane & 15) * 4) = pk;
}

// ---------------- host ------------------------------------------------------
extern "C" void kernel_launch(void* const* d_in, const int* in_sizes, int n_in,
                              void* d_out, int out_size, void* d_ws, size_t ws_size,
                              hipStream_t stream) {
  const float* query = (const float*)d_in[0];
  const float* refp  = (const float*)d_in[1];
  const float* feat  = (const float*)d_in[2];
  const float* qn_w  = (const float*)d_in[3];
  const float* qn_b  = (const float*)d_in[4];
  const float* fn_w  = (const float*)d_in[5];
  const float* fn_b  = (const float*)d_in[6];
  const float* gamma = (const float*)d_in[7];
  const float* so_w  = (const float*)d_in[8];
  const float* so_b  = (const float*)d_in[9];
  const float* aw_w  = (const float*)d_in[10];
  const float* aw_b  = (const float*)d_in[11];
  const float* vp_w  = (const float*)d_in[12];
  const float* vp_b  = (const float*)d_in[13];
  const float* op_w  = (const float*)d_in[14];
  const float* op_b  = (const float*)d_in[15];

  char* ws = (char*)d_ws;
  size_t off = 0;
  auto alloc = [&](size_t bytes) {
    char* p = ws + off;
    off = (off + bytes + 255) & ~(size_t)255;
    return p;
  };
  ushort* q_bf   = (ushort*)alloc((size_t)MQ * CDIM * 2);
  char*   val_f8 = (char*)alloc((size_t)MF * CDIM);        // [48][LIN][64] e4m3
  char*   vp_w8  = (char*)alloc((size_t)CDIM * CDIM);
  char*   op_w8  = (char*)alloc((size_t)CDIM * CDIM);
  ushort* cat_wT = (ushort*)alloc((size_t)CAT_N * CDIM * 2);
  float*  cat_bp = (float*)alloc(CAT_N * 4);

  // region R: f_f8 (phase A) aliases the phase-B buffers
  const size_t r = off;
  char* f_f8 = ws + r;
  const size_t f_end = r + (size_t)MF * CDIM;
  size_t o2 = r;
  float*  raw     = (float*)(ws + o2);  o2 += (size_t)MQ * CAT_N * 4;
  float4* params  = (float4*)(ws + o2); o2 += (size_t)MQ * NHD * 12 * 16;
  char*   samp8   = (char*)(ws + o2);   o2 += (size_t)MQ * CDIM;
  const size_t need = (f_end > o2) ? f_end : o2;
  if (ws_size < need) return;   // ~180 MB required

  // 1) weights: vp/op -> fp8 transposed; cat (so|aw) -> bf16 transposed
  transpose_cast_f8<<<(CDIM * CDIM + 255) / 256, 256, 0, stream>>>(vp_w, vp_w8, CDIM, CDIM);
  transpose_cast_f8<<<(CDIM * CDIM + 255) / 256, 256, 0, stream>>>(op_w, op_w8, CDIM, CDIM);
  transpose_cast<<<(AW_OFF * CDIM + 255) / 256, 256, 0, stream>>>(so_w, cat_wT, CDIM, 288, AW_OFF);
  transpose_cast<<<((CAT_N - AW_OFF) * CDIM + 255) / 256, 256, 0, stream>>>(
      aw_w, cat_wT + (size_t)AW_OFF * CDIM, CDIM, 144, CAT_N - AW_OFF);
  pad_bias<<<2, 256, 0, stream>>>(so_b, cat_bp, 288, AW_OFF);
  pad_bias<<<1, 256, 0, stream>>>(aw_b, cat_bp + AW_OFF, 144, CAT_N - AW_OFF);

  // 2) layernorms: query -> bf16, feat -> fp8
  ln_cast<0><<<MQ, 192, 0, stream>>>(query, qn_w, qn_b, q_bf);
  ln_cast<1><<<MF, 192, 0, stream>>>(feat, fn_w, fn_b, f_f8);

  // 3) value = LN(feat) @ vp_w + vp_b   (fp8 GEMM, fp8 head-major out)
  gemm8_f8<0><<<(MF / 256) * (CDIM / 256), 512, 0, stream>>>(
      f_f8, vp_w8, vp_b, val_f8, MF, CDIM, CDIM, CDIM / 256, nullptr, nullptr);

  // 4) fused sampling-offset | attn-weight GEMM  (bf16 2-phase, f32 out)
  gemm_bt<<<(MQ / 128) * (CAT_N / 128), 256, 0, stream>>>(
      q_bf, cat_wT, cat_bp, raw, MQ, CAT_N, CDIM, CAT_N / 128);

  // 5) softmax + pack {px,py,a} per (q,h,l,p)
  softmax_pack<<<(MQ * NHD) / 256, 256, 0, stream>>>(raw, refp, params);

  // 6) deformable sampling -> samp fp8 [MQ][768]
  deform_grp<<<48 * 256, 256, 0, stream>>>(val_f8, params, samp8);

  // 7) out = query + gamma * (samp @ op_w + op_b)   (fp8 GEMM, fused epi)
  gemm8_f8<2><<<(MQ / 256) * (CDIM / 256), 512, 0, stream>>>(
      samp8, op_w8, op_b, (float*)d_out, MQ, CDIM, CDIM, CDIM / 256, query, gamma);
}

// Round 9
// 397.160 us; speedup vs baseline: 1.3064x; 1.0267x over previous
//
#include <hip/hip_runtime.h>
#include <hip/hip_bf16.h>
#include <stdint.h>

// ---------------- problem constants (fixed by setup_inputs) ----------------
#define NHD   12        // heads
#define NPT   4         // points
#define CDIM  768
#define HDIM  64
#define NLVL  3
#define LQ    4096
#define NB    4
#define LIN   21504     // 128*128 + 64*64 + 32*32
#define MQ    (NB*LQ)   // 16384 query rows
#define MF    (NB*LIN)  // 86016 feat rows
#define CAT_N 512       // fused so(288) | aw(224: 144 real + pad)
#define AW_OFF 288

typedef __bf16 bfx8 __attribute__((ext_vector_type(8)));
typedef float  f32x4 __attribute__((ext_vector_type(4)));
typedef float  f32x2 __attribute__((ext_vector_type(2)));

__device__ __forceinline__ ushort f2bf(float x) {
  union { float f; uint32_t u; } v; v.f = x;
  uint32_t r = v.u + 0x7fffu + ((v.u >> 16) & 1u);   // RNE
  return (ushort)(r >> 16);
}
__device__ __forceinline__ long u2l(uint2 v) {
  union { uint2 u; long l; } x; x.u = v; return x.l;
}

// ---------------- LDS-tiled coalesced transpose + cast ---------------------
// Wt[n][k] = cast(W[k][n]). 32x32 tile, 256 thr (32x8). F8: e4m3 out.
template<int F8>
__global__ __launch_bounds__(256) void transpose_tile(
    const float* __restrict__ W, void* __restrict__ Wt,
    int K, int Nsrc, int Npad)
{
  __shared__ float t[32][33];
  const int nkt = K >> 5;
  const int k0 = (blockIdx.x % nkt) * 32;
  const int n0 = (blockIdx.x / nkt) * 32;
  const int tx = threadIdx.x & 31, ty = threadIdx.x >> 5;
#pragma unroll
  for (int i = ty; i < 32; i += 8) {
    const int n = n0 + tx;
    t[i][tx] = (n < Nsrc) ? W[(size_t)(k0 + i) * Nsrc + n] : 0.f;
  }
  __syncthreads();
#pragma unroll
  for (int i = ty; i < 32; i += 8) {
    const int n = n0 + i;
    const float v = t[tx][i];
    if constexpr (F8) {
      uint32_t pk = __builtin_amdgcn_cvt_pk_fp8_f32(v, 0.f, 0, false);
      ((char*)Wt)[(size_t)n * K + k0 + tx] = (char)(pk & 0xff);
    } else {
      ((ushort*)Wt)[(size_t)n * K + k0 + tx] = f2bf(v);
    }
  }
}

__global__ void pad_bias(const float* __restrict__ src, float* __restrict__ dst,
                         int nReal, int nPad) {
  int i = blockIdx.x * 256 + threadIdx.x;
  if (i < nPad) dst[i] = (i < nReal) ? src[i] : 0.f;
}

// ---------------- LayerNorm + cast (OUT8: 0 = bf16, 1 = fp8 e4m3) ----------
template<int OUT8>
__global__ __launch_bounds__(192) void ln_cast(const float* __restrict__ x,
                                               const float* __restrict__ w,
                                               const float* __restrict__ b,
                                               void* __restrict__ y) {
  const int row = blockIdx.x;
  const int tid = threadIdx.x;                  // 192 threads * float4 = 768
  const float4 v = ((const float4*)(x + (size_t)row * CDIM))[tid];
  float s1 = v.x + v.y + v.z + v.w;
  float s2 = v.x*v.x + v.y*v.y + v.z*v.z + v.w*v.w;
#pragma unroll
  for (int o = 32; o > 0; o >>= 1) { s1 += __shfl_down(s1, o); s2 += __shfl_down(s2, o); }
  __shared__ float r1[3], r2[3];
  const int lane = tid & 63, wv = tid >> 6;
  if (lane == 0) { r1[wv] = s1; r2[wv] = s2; }
  __syncthreads();
  s1 = r1[0] + r1[1] + r1[2];
  s2 = r2[0] + r2[1] + r2[2];
  const float mu = s1 * (1.f / CDIM);
  const float rs = rsqrtf(s2 * (1.f / CDIM) - mu * mu + 1e-6f);
  const float4 w4 = ((const float4*)w)[tid];
  const float4 b4 = ((const float4*)b)[tid];
  const float o0 = (v.x - mu) * rs * w4.x + b4.x;
  const float o1 = (v.y - mu) * rs * w4.y + b4.y;
  const float o2 = (v.z - mu) * rs * w4.z + b4.z;
  const float o3 = (v.w - mu) * rs * w4.w + b4.w;
  if constexpr (OUT8) {
    uint32_t pk = 0;
    pk = __builtin_amdgcn_cvt_pk_fp8_f32(o0, o1, pk, false);
    pk = __builtin_amdgcn_cvt_pk_fp8_f32(o2, o3, pk, true);
    ((uint32_t*)((char*)y + (size_t)row * CDIM))[tid] = pk;
  } else {
    ushort4 o4;
    o4.x = f2bf(o0); o4.y = f2bf(o1); o4.z = f2bf(o2); o4.w = f2bf(o3);
    ((ushort4*)((ushort*)y + (size_t)row * CDIM))[tid] = o4;
  }
}

// ============ 256x256 fp8 GEMM, 2-buf counted-vmcnt, 2 blocks/CU ============
// C = A[M][K](e4m3) * Wt[N][K](e4m3)^T + bias. 512 thr = 8 waves (2M x 4N).
// BK=64; half h (0=A-k0,1=B-k0,2=A-k1,3=B-k1), each [256 rows][32 B] packed
// as [128 lines][64 B] (line j = rows 2j,2j+1; 16B chunk g <- src chunk
// g^((j>>1)&3), bank-distinct per quarter-wave on ds_read_b64).
// 2 LDS bufs x 32 KB = 64 KB -> 2 workgroups/CU (the R8 96 KB version was
// LDS-capped at 1 wg/CU = 2 waves/SIMD; barrier waits were fully exposed).
// Stage half p of tile t+1 at phase p; waits: vmcnt(2)@p1 (h2,h3 of cur),
// vmcnt(2)@p3 (h0',h1') -- never drained to 0 in steady state.
// MODE 0: fp8 head-major value store [n*NHD+h][LIN][64].
// MODE 2: f32, out = resid + gamma*(acc+bias), row-major [M][N].
template<int MODE>
__global__ __launch_bounds__(512, 2) void gemm8_f8(
    const char* __restrict__ A, const char* __restrict__ Wt,
    const float* __restrict__ bias, void* __restrict__ Cout,
    int M, int N, int K, int nTN,
    const float* __restrict__ resid, const float* __restrict__ gammav)
{
  __shared__ __align__(16) char lds[65536];   // 2 x 32 KiB

  int bid = blockIdx.x;
  const int nwg = gridDim.x;
  if ((nwg & 7) == 0) {                 // XCD-chunked swizzle (bijective)
    const int chunk = nwg >> 3;
    bid = (bid & 7) * chunk + (bid >> 3);
  }
  const int mt = bid / nTN, ntl = bid - mt * nTN;
  const int m0 = mt * 256, n0 = ntl * 256;
  const int tid  = threadIdx.x;
  const int lane = tid & 63, wid = tid >> 6;
  const int wm = wid >> 2, wn = wid & 3;           // 2x4 wave grid
  const int lr = lane & 15, lk = lane >> 4;

  f32x4 acc[8][4] = {};

  // stage half h of K-tile kt into buf (one 16B gload_lds per thread)
  auto stage_half = [&](int kt, int h, int buf) {
    const char* srcM = (h & 1) ? Wt : A;
    const int base0 = (h & 1) ? n0 : m0;
    const int koff  = kt * 64 + (h >> 1) * 32;
    const int j = tid >> 2, g = tid & 3;
    const int c = g ^ ((j >> 1) & 3);              // source chunk (involution)
    const char* src = srcM + (size_t)(base0 + 2 * j + (c >> 1)) * K
                           + koff + (c & 1) * 16;
    char* dst = lds + buf * 32768 + h * 8192 + wid * 1024;  // + lane*16 by HW
    __builtin_amdgcn_global_load_lds(
        (const __attribute__((address_space(1))) uint32_t*)src,
        (__attribute__((address_space(3))) uint32_t*)dst, 16, 0, 0);
  };
  // swizzled ds_read_b64 of one 8-fp8 fragment. ab: 0=A,1=B. row in [0,256).
  auto rdfrag = [&](int buf, int ab, int row, int kk) -> uint2 {
    const int j = row >> 1;
    const int g = (((row & 1) << 1) + (lk >> 1)) ^ ((j >> 1) & 3);
    return *(const uint2*)(lds + buf * 32768 + (kk * 2 + ab) * 8192
                           + j * 64 + g * 16 + (lk & 1) * 8);
  };

  const int nk = K >> 6;                           // K-tiles of 64
  // prologue: tile 0 -> buf 0
#pragma unroll
  for (int h = 0; h < 4; ++h) stage_half(0, h, 0);
  asm volatile("s_waitcnt vmcnt(0)" ::: "memory");
  __builtin_amdgcn_s_barrier();
  asm volatile("" ::: "memory");

  uint2 bfr[4];
  for (int t = 0; t < nk; ++t) {
    const int cur = t & 1;
    const bool pre = (t + 1 < nk);
#pragma unroll
    for (int p = 0; p < 4; ++p) {
      const int kk = p >> 1, mg = p & 1;
      if (mg == 0) {
#pragma unroll
        for (int n = 0; n < 4; ++n) bfr[n] = rdfrag(cur, 1, wn * 64 + n * 16 + lr, kk);
      }
      uint2 af[4];
#pragma unroll
      for (int j = 0; j < 4; ++j)
        af[j] = rdfrag(cur, 0, wm * 128 + (mg * 4 + j) * 16 + lr, kk);
      if (pre) stage_half(t + 1, p, cur ^ 1);
      __builtin_amdgcn_s_setprio(1);
#pragma unroll
      for (int j = 0; j < 4; ++j)
#pragma unroll
        for (int n = 0; n < 4; ++n)
          acc[mg * 4 + j][n] = __builtin_amdgcn_mfma_f32_16x16x32_fp8_fp8(
              u2l(af[j]), u2l(bfr[n]), acc[mg * 4 + j][n], 0, 0, 0);
      __builtin_amdgcn_s_setprio(0);
      if (p == 1) {               // need h2,h3 of cur before p2 reads
        if (pre) asm volatile("s_waitcnt vmcnt(2)" ::: "memory");
        else     asm volatile("s_waitcnt vmcnt(0)" ::: "memory");
      } else if (p == 3 && pre) { // need h0',h1' of next before its p0
        asm volatile("s_waitcnt vmcnt(2)" ::: "memory");
      }
      __builtin_amdgcn_s_barrier();
      asm volatile("" ::: "memory");
    }
  }

  // ---- epilogue. D layout per MFMA: row = lk*4+i, col = lr (m89-verified).
  if constexpr (MODE == 0) {
    // fp8 head-major value store: [n*NHD+head][LIN][64] e4m3, via LDS stage.
    // After the final barrier both buffers are free; per-wave private region.
    float* my = (float*)lds + wid * 1088;          // 16 rows x 68 f32 per wave
    float bc[4];
#pragma unroll
    for (int n = 0; n < 4; ++n) bc[n] = bias[n0 + wn * 64 + n * 16 + lr];
    const int rrow = lane >> 2, sgt = lane & 3;    // row 0..15, 16B seg 0..3
    const int n_img = (unsigned)m0 / LIN;          // LIN%256==0: no crossing
    const int head  = (n0 + wn * 64) >> 6;
    char* plane = (char*)Cout
        + ((size_t)(n_img * NHD + head) * LIN + (m0 - n_img * LIN)) * 64;
#pragma unroll
    for (int m = 0; m < 8; ++m) {
#pragma unroll
      for (int n = 0; n < 4; ++n)
#pragma unroll
        for (int i = 0; i < 4; ++i)
          my[(lk * 4 + i) * 68 + n * 16 + lr] = acc[m][n][i] + bc[n];
      const float* src = my + rrow * 68 + sgt * 16;
      uint32_t w[4];
#pragma unroll
      for (int q = 0; q < 4; ++q) {
        uint32_t pk = 0;
        pk = __builtin_amdgcn_cvt_pk_fp8_f32(src[q*4+0], src[q*4+1], pk, false);
        pk = __builtin_amdgcn_cvt_pk_fp8_f32(src[q*4+2], src[q*4+3], pk, true);
        w[q] = pk;
      }
      char* orow = plane + (size_t)(wm * 128 + m * 16 + rrow) * 64 + sgt * 16;
      *(uint4*)orow = *(uint4*)w;
    }
  } else {
#pragma unroll
    for (int n = 0; n < 4; ++n) {
      const int col = n0 + wn * 64 + n * 16 + lr;
      const float bcol = bias[col];
      const float gcol = gammav[col];
#pragma unroll
      for (int m = 0; m < 8; ++m) {
        const int rbase = m0 + wm * 128 + m * 16 + lk * 4;
#pragma unroll
        for (int i = 0; i < 4; ++i) {
          const size_t o = (size_t)(rbase + i) * N + col;
          ((float*)Cout)[o] = resid[o] + gcol * (acc[m][n][i] + bcol);
        }
      }
    }
  }
}

// ---------------- 2-phase 128x128 bf16 GEMM (fused so|aw, f32 out) ---------
__global__ __launch_bounds__(256) void gemm_bt(
    const ushort* __restrict__ A, const ushort* __restrict__ Wt,
    const float* __restrict__ bias, float* __restrict__ Cout,
    int M, int N, int K, int nTN)
{
  int bid = blockIdx.x;
  const int nwg = gridDim.x;
  if ((nwg & 7) == 0) {
    const int chunk = nwg >> 3;
    bid = (bid & 7) * chunk + (bid >> 3);
  }
  const int mt = bid / nTN;
  const int nt = bid - mt * nTN;
  const int m0 = mt * 128, n0 = nt * 128;
  const int tid  = threadIdx.x;
  const int lane = tid & 63, wid = tid >> 6;
  const int wm = wid >> 1, wn = wid & 1;
  const int lr = lane & 15, lk = lane >> 4;

  __shared__ __align__(16) ushort lds[2][8192];

  f32x4 acc[4][4] = {};

  auto stage = [&](int kt, int buf) {
    const int k0 = kt * 32;
#pragma unroll
    for (int it = 0; it < 2; ++it) {
      const int c   = it * 256 + wid * 64 + lane;
      const int row = c >> 2, g = c & 3;
      const ushort* srcA = A + (size_t)(m0 + row) * K + (k0 + g * 8);
      ushort* dstA = &lds[buf][(it * 256 + wid * 64) * 8];
      __builtin_amdgcn_global_load_lds(
          (const __attribute__((address_space(1))) uint32_t*)srcA,
          (__attribute__((address_space(3))) uint32_t*)dstA, 16, 0, 0);
      const ushort* srcB = Wt + (size_t)(n0 + row) * K + (k0 + g * 8);
      ushort* dstB = &lds[buf][4096 + (it * 256 + wid * 64) * 8];
      __builtin_amdgcn_global_load_lds(
          (const __attribute__((address_space(1))) uint32_t*)srcB,
          (__attribute__((address_space(3))) uint32_t*)dstB, 16, 0, 0);
    }
  };

  stage(0, 0);
  __syncthreads();
  const int nk = K >> 5;
  for (int kt = 0; kt < nk; ++kt) {
    const int cur = kt & 1;
    if (kt + 1 < nk) stage(kt + 1, cur ^ 1);
    const ushort* As = &lds[cur][0];
    const ushort* Bs = &lds[cur][4096];
    bfx8 af[4], bv[4];
#pragma unroll
    for (int m = 0; m < 4; ++m)
      af[m] = *(const bfx8*)(As + (wm * 64 + m * 16 + lr) * 32 + lk * 8);
#pragma unroll
    for (int n = 0; n < 4; ++n)
      bv[n] = *(const bfx8*)(Bs + (wn * 64 + n * 16 + lr) * 32 + lk * 8);
#pragma unroll
    for (int m = 0; m < 4; ++m)
#pragma unroll
      for (int n = 0; n < 4; ++n)
        acc[m][n] = __builtin_amdgcn_mfma_f32_16x16x32_bf16(af[m], bv[n], acc[m][n], 0, 0, 0);
    __syncthreads();
  }

#pragma unroll
  for (int n = 0; n < 4; ++n) {
    const int col = n0 + wn * 64 + n * 16 + lr;
    const float bcol = bias[col];
#pragma unroll
    for (int m = 0; m < 4; ++m) {
      const int rbase = m0 + wm * 64 + m * 16 + lk * 4;
#pragma unroll
      for (int i = 0; i < 4; ++i)
        Cout[(size_t)(rbase + i) * N + col] = acc[m][n][i] + bcol;
    }
  }
}

// ---------------- softmax over 12 + pack sampling params --------------------
__global__ void softmax_pack(const float* __restrict__ raw,
                             const float* __restrict__ refp,
                             float4* __restrict__ params) {
  const int t = blockIdx.x * 256 + threadIdx.x;       // [0, MQ*NHD)
  const int h = t % NHD, nq = t / NHD;
  const float* p = raw + (size_t)nq * CAT_N + AW_OFF + h * 12;
  float v[12], m = -1e30f;
#pragma unroll
  for (int j = 0; j < 12; ++j) { v[j] = p[j]; m = fmaxf(m, v[j]); }
  float s = 0.f;
#pragma unroll
  for (int j = 0; j < 12; ++j) { v[j] = __expf(v[j] - m); s += v[j]; }
  const float inv = 1.f / s;
  const float* op = raw + (size_t)nq * CAT_N + h * 24;
  const float* rp = refp + (size_t)nq * (NLVL * 2);
  float4* out = params + (size_t)t * 12;
  const float Wf[3] = {128.f, 64.f, 32.f};
#pragma unroll
  for (int l = 0; l < NLVL; ++l) {
    const float rxw = rp[2 * l] * Wf[l] - 0.5f;
    const float ryw = rp[2 * l + 1] * Wf[l] - 0.5f;
#pragma unroll
    for (int pt = 0; pt < NPT; ++pt) {
      float4 o4;
      o4.x = rxw + op[(l * 4 + pt) * 2 + 0];
      o4.y = ryw + op[(l * 4 + pt) * 2 + 1];
      o4.z = v[l * 4 + pt] * inv;
      o4.w = 0.f;
      out[l * 4 + pt] = o4;
    }
  }
}

// ---------------- deformable bilinear sampling, fp8 value/samp -------------
__global__ __launch_bounds__(256) void deform_grp(
    const char* __restrict__ vbytes, const float4* __restrict__ params,
    char* __restrict__ samp)
{
  const int j = blockIdx.x;
  const int x = j & 7, k = j >> 3;
  const int g = x + ((k >> 8) << 3);          // plane = n*NHD+h, pinned to XCD x
  const int i = k & 255;                      // block within group
  const int n = g / NHD, h = g - n * NHD;
  const int wid  = threadIdx.x >> 6;
  const int lane = threadIdx.x & 63;
  const int q  = i * 16 + wid * 4 + (lane >> 4);        // [0, 4096)
  const int nq = n * LQ + q;
  const float4* __restrict__ pp = params + ((size_t)nq * NHD + h) * 12;
  const uint32_t base0 = (uint32_t)g * (uint32_t)(LIN * 64)
                       + ((uint32_t)(lane & 15) << 2);

  float acc0 = 0.f, acc1 = 0.f, acc2 = 0.f, acc3 = 0.f;

  const int      Wl[3]  = {128, 64, 32};
  const uint32_t STb[3] = {0u, 16384u * 64u, 20480u * 64u};

#pragma unroll
  for (int l = 0; l < NLVL; ++l) {
    const int W_ = Wl[l];
    const uint32_t base = base0 + STb[l];
#pragma unroll
    for (int p = 0; p < NPT; ++p) {
      const float4 pt = pp[l * 4 + p];
      const float fx = floorf(pt.x), fy = floorf(pt.y);
      const float tx = pt.x - fx,   ty = pt.y - fy;
      const int x0 = (int)fx, y0 = (int)fy;
      const int x1 = x0 + 1,  y1 = y0 + 1;
      const float wx0 = ((uint32_t)x0 < (uint32_t)W_) ? (1.f - tx) : 0.f;
      const float wx1 = ((uint32_t)x1 < (uint32_t)W_) ? tx : 0.f;
      const float wy0 = ((uint32_t)y0 < (uint32_t)W_) ? pt.z * (1.f - ty) : 0.f;
      const float wy1 = ((uint32_t)y1 < (uint32_t)W_) ? pt.z * ty : 0.f;
      const int xc0 = min(max(x0, 0), W_ - 1);
      const int xc1 = min(max(x1, 0), W_ - 1);
      const int yr0 = min(max(y0, 0), W_ - 1) * W_;
      const int yr1 = min(max(y1, 0), W_ - 1) * W_;
      const float w00 = wy0 * wx0, w01 = wy0 * wx1;
      const float w10 = wy1 * wx0, w11 = wy1 * wx1;
      const uint32_t g00 = *(const uint32_t*)(vbytes + base + (uint32_t)(yr0 + xc0) * 64u);
      const uint32_t g01 = *(const uint32_t*)(vbytes + base + (uint32_t)(yr0 + xc1) * 64u);
      const uint32_t g10 = *(const uint32_t*)(vbytes + base + (uint32_t)(yr1 + xc0) * 64u);
      const uint32_t g11 = *(const uint32_t*)(vbytes + base + (uint32_t)(yr1 + xc1) * 64u);
      {
        f32x2 lo = __builtin_amdgcn_cvt_pk_f32_fp8(g00, false);
        f32x2 hi = __builtin_amdgcn_cvt_pk_f32_fp8(g00, true);
        acc0 += lo[0] * w00; acc1 += lo[1] * w00; acc2 += hi[0] * w00; acc3 += hi[1] * w00;
      }
      {
        f32x2 lo = __builtin_amdgcn_cvt_pk_f32_fp8(g01, false);
        f32x2 hi = __builtin_amdgcn_cvt_pk_f32_fp8(g01, true);
        acc0 += lo[0] * w01; acc1 += lo[1] * w01; acc2 += hi[0] * w01; acc3 += hi[1] * w01;
      }
      {
        f32x2 lo = __builtin_amdgcn_cvt_pk_f32_fp8(g10, false);
        f32x2 hi = __builtin_amdgcn_cvt_pk_f32_fp8(g10, true);
        acc0 += lo[0] * w10; acc1 += lo[1] * w10; acc2 += hi[0] * w10; acc3 += hi[1] * w10;
      }
      {
        f32x2 lo = __builtin_amdgcn_cvt_pk_f32_fp8(g11, false);
        f32x2 hi = __builtin_amdgcn_cvt_pk_f32_fp8(g11, true);
        acc0 += lo[0] * w11; acc1 += lo[1] * w11; acc2 += hi[0] * w11; acc3 += hi[1] * w11;
      }
    }
  }

  uint32_t pk = 0;
  pk = __builtin_amdgcn_cvt_pk_fp8_f32(acc0, acc1, pk, false);
  pk = __builtin_amdgcn_cvt_pk_fp8_f32(acc2, acc3, pk, true);
  *(uint32_t*)(samp + (size_t)nq * CDIM + h * HDIM + (lane & 15) * 4) = pk;
}

// ---------------- host ------------------------------------------------------
extern "C" void kernel_launch(void* const* d_in, const int* in_sizes, int n_in,
                              void* d_out, int out_size, void* d_ws, size_t ws_size,
                              hipStream_t stream) {
  const float* query = (const float*)d_in[0];
  const float* refp  = (const float*)d_in[1];
  const float* feat  = (const float*)d_in[2];
  const float* qn_w  = (const float*)d_in[3];
  const float* qn_b  = (const float*)d_in[4];
  const float* fn_w  = (const float*)d_in[5];
  const float* fn_b  = (const float*)d_in[6];
  const float* gamma = (const float*)d_in[7];
  const float* so_w  = (const float*)d_in[8];
  const float* so_b  = (const float*)d_in[9];
  const float* aw_w  = (const float*)d_in[10];
  const float* aw_b  = (const float*)d_in[11];
  const float* vp_w  = (const float*)d_in[12];
  const float* vp_b  = (const float*)d_in[13];
  const float* op_w  = (const float*)d_in[14];
  const float* op_b  = (const float*)d_in[15];

  char* ws = (char*)d_ws;
  size_t off = 0;
  auto alloc = [&](size_t bytes) {
    char* p = ws + off;
    off = (off + bytes + 255) & ~(size_t)255;
    return p;
  };
  ushort* q_bf   = (ushort*)alloc((size_t)MQ * CDIM * 2);
  char*   val_f8 = (char*)alloc((size_t)MF * CDIM);        // [48][LIN][64] e4m3
  char*   vp_w8  = (char*)alloc((size_t)CDIM * CDIM);
  char*   op_w8  = (char*)alloc((size_t)CDIM * CDIM);
  ushort* cat_wT = (ushort*)alloc((size_t)CAT_N * CDIM * 2);
  float*  cat_bp = (float*)alloc(CAT_N * 4);

  // region R: f_f8 (phase A) aliases the phase-B buffers
  const size_t r = off;
  char* f_f8 = ws + r;
  const size_t f_end = r + (size_t)MF * CDIM;
  size_t o2 = r;
  float*  raw     = (float*)(ws + o2);  o2 += (size_t)MQ * CAT_N * 4;
  float4* params  = (float4*)(ws + o2); o2 += (size_t)MQ * NHD * 12 * 16;
  char*   samp8   = (char*)(ws + o2);   o2 += (size_t)MQ * CDIM;
  const size_t need = (f_end > o2) ? f_end : o2;
  if (ws_size < need) return;   // ~180 MB required

  // 1) weights: vp/op -> fp8 transposed; cat (so|aw) -> bf16 transposed.
  //    All via LDS-tiled coalesced transpose (old strided version was
  //    64-lines-per-wave uncoalesced).
  transpose_tile<1><<<24 * 24, 256, 0, stream>>>(vp_w, vp_w8, CDIM, CDIM, CDIM);
  transpose_tile<1><<<24 * 24, 256, 0, stream>>>(op_w, op_w8, CDIM, CDIM, CDIM);
  transpose_tile<0><<<24 * 9,  256, 0, stream>>>(so_w, cat_wT, CDIM, 288, AW_OFF);
  transpose_tile<0><<<24 * 7,  256, 0, stream>>>(
      aw_w, cat_wT + (size_t)AW_OFF * CDIM, CDIM, 144, CAT_N - AW_OFF);
  pad_bias<<<2, 256, 0, stream>>>(so_b, cat_bp, 288, AW_OFF);
  pad_bias<<<1, 256, 0, stream>>>(aw_b, cat_bp + AW_OFF, 144, CAT_N - AW_OFF);

  // 2) layernorms: query -> bf16, feat -> fp8
  ln_cast<0><<<MQ, 192, 0, stream>>>(query, qn_w, qn_b, q_bf);
  ln_cast<1><<<MF, 192, 0, stream>>>(feat, fn_w, fn_b, f_f8);

  // 3) value = LN(feat) @ vp_w + vp_b   (fp8 GEMM, fp8 head-major out)
  gemm8_f8<0><<<(MF / 256) * (CDIM / 256), 512, 0, stream>>>(
      f_f8, vp_w8, vp_b, val_f8, MF, CDIM, CDIM, CDIM / 256, nullptr, nullptr);

  // 4) fused sampling-offset | attn-weight GEMM  (bf16 2-phase, f32 out)
  gemm_bt<<<(MQ / 128) * (CAT_N / 128), 256, 0, stream>>>(
      q_bf, cat_wT, cat_bp, raw, MQ, CAT_N, CDIM, CAT_N / 128);

  // 5) softmax + pack {px,py,a} per (q,h,l,p)
  softmax_pack<<<(MQ * NHD) / 256, 256, 0, stream>>>(raw, refp, params);

  // 6) deformable sampling -> samp fp8 [MQ][768]
  deform_grp<<<48 * 256, 256, 0, stream>>>(val_f8, params, samp8);

  // 7) out = query + gamma * (samp @ op_w + op_b)   (fp8 GEMM, fused epi)
  gemm8_f8<2><<<(MQ / 256) * (CDIM / 256), 512, 0, stream>>>(
      samp8, op_w8, op_b, (float*)d_out, MQ, CDIM, CDIM, CDIM / 256, query, gamma);
}

// Round 10
// 377.205 us; speedup vs baseline: 1.3755x; 1.0529x over previous
//
#include <hip/hip_runtime.h>
#include <hip/hip_bf16.h>
#include <stdint.h>

// ---------------- problem constants (fixed by setup_inputs) ----------------
#define NHD   12        // heads
#define NPT   4         // points
#define CDIM  768
#define HDIM  64
#define NLVL  3
#define LQ    4096
#define NB    4
#define LIN   21504     // 128*128 + 64*64 + 32*32
#define MQ    (NB*LQ)   // 16384 query rows
#define MF    (NB*LIN)  // 86016 feat rows
#define CAT_N 512       // fused so(288) | aw(144 real + pad)
#define AW_OFF 288

typedef __bf16 bfx8 __attribute__((ext_vector_type(8)));
typedef float  f32x4 __attribute__((ext_vector_type(4)));
typedef float  f32x2 __attribute__((ext_vector_type(2)));

__device__ __forceinline__ ushort f2bf(float x) {
  union { float f; uint32_t u; } v; v.f = x;
  uint32_t r = v.u + 0x7fffu + ((v.u >> 16) & 1u);   // RNE
  return (ushort)(r >> 16);
}
__device__ __forceinline__ long u2l(uint2 v) {
  union { uint2 u; long l; } x; x.u = v; return x.l;
}

// ---------------- LDS-tiled coalesced transpose + cast ---------------------
// Wt[n][k] = cast(W[k][n]). 32x32 tile, 256 thr (32x8). F8: e4m3 out.
template<int F8>
__global__ __launch_bounds__(256) void transpose_tile(
    const float* __restrict__ W, void* __restrict__ Wt,
    int K, int Nsrc, int Npad)
{
  __shared__ float t[32][33];
  const int nkt = K >> 5;
  const int k0 = (blockIdx.x % nkt) * 32;
  const int n0 = (blockIdx.x / nkt) * 32;
  const int tx = threadIdx.x & 31, ty = threadIdx.x >> 5;
#pragma unroll
  for (int i = ty; i < 32; i += 8) {
    const int n = n0 + tx;
    t[i][tx] = (n < Nsrc) ? W[(size_t)(k0 + i) * Nsrc + n] : 0.f;
  }
  __syncthreads();
#pragma unroll
  for (int i = ty; i < 32; i += 8) {
    const int n = n0 + i;
    const float v = t[tx][i];
    if constexpr (F8) {
      uint32_t pk = __builtin_amdgcn_cvt_pk_fp8_f32(v, 0.f, 0, false);
      ((char*)Wt)[(size_t)n * K + k0 + tx] = (char)(pk & 0xff);
    } else {
      ((ushort*)Wt)[(size_t)n * K + k0 + tx] = f2bf(v);
    }
  }
}

__global__ void pad_bias(const float* __restrict__ src, float* __restrict__ dst,
                         int nReal, int nPad) {
  int i = blockIdx.x * 256 + threadIdx.x;
  if (i < nPad) dst[i] = (i < nReal) ? src[i] : 0.f;
}

// ---------------- LayerNorm, 1 wave/row (no barriers) ----------------------
// 4 rows per 256-thr block; lane handles 3 float4 segments (3*64*4 = 768).
// OUT8: 0 = bf16 out, 1 = fp8 e4m3 out.
template<int OUT8>
__global__ __launch_bounds__(256) void ln_wave(const float* __restrict__ x,
                                               const float* __restrict__ w,
                                               const float* __restrict__ b,
                                               void* __restrict__ y) {
  const int row  = blockIdx.x * 4 + (threadIdx.x >> 6);
  const int lane = threadIdx.x & 63;
  const float4* xr = (const float4*)(x + (size_t)row * CDIM);
  float4 v[3];
  v[0] = xr[lane]; v[1] = xr[lane + 64]; v[2] = xr[lane + 128];
  float s1 = 0.f, s2 = 0.f;
#pragma unroll
  for (int i = 0; i < 3; ++i) {
    s1 += v[i].x + v[i].y + v[i].z + v[i].w;
    s2 += v[i].x*v[i].x + v[i].y*v[i].y + v[i].z*v[i].z + v[i].w*v[i].w;
  }
#pragma unroll
  for (int o = 32; o > 0; o >>= 1) { s1 += __shfl_xor(s1, o); s2 += __shfl_xor(s2, o); }
  const float mu = s1 * (1.f / CDIM);
  const float rs = rsqrtf(s2 * (1.f / CDIM) - mu * mu + 1e-6f);
#pragma unroll
  for (int i = 0; i < 3; ++i) {
    const float4 w4 = ((const float4*)w)[lane + i * 64];
    const float4 b4 = ((const float4*)b)[lane + i * 64];
    const float o0 = (v[i].x - mu) * rs * w4.x + b4.x;
    const float o1 = (v[i].y - mu) * rs * w4.y + b4.y;
    const float o2 = (v[i].z - mu) * rs * w4.z + b4.z;
    const float o3 = (v[i].w - mu) * rs * w4.w + b4.w;
    if constexpr (OUT8) {
      uint32_t pk = 0;
      pk = __builtin_amdgcn_cvt_pk_fp8_f32(o0, o1, pk, false);
      pk = __builtin_amdgcn_cvt_pk_fp8_f32(o2, o3, pk, true);
      ((uint32_t*)((char*)y + (size_t)row * CDIM))[lane + i * 64] = pk;
    } else {
      ushort4 o4;
      o4.x = f2bf(o0); o4.y = f2bf(o1); o4.z = f2bf(o2); o4.w = f2bf(o3);
      ((ushort4*)((ushort*)y + (size_t)row * CDIM))[lane + i * 64] = o4;
    }
  }
}

// ============ 256x256 fp8 GEMM, 2-buf counted-vmcnt (unchanged R9) ==========
template<int MODE>
__global__ __launch_bounds__(512, 2) void gemm8_f8(
    const char* __restrict__ A, const char* __restrict__ Wt,
    const float* __restrict__ bias, void* __restrict__ Cout,
    int M, int N, int K, int nTN,
    const float* __restrict__ resid, const float* __restrict__ gammav)
{
  __shared__ __align__(16) char lds[65536];   // 2 x 32 KiB

  int bid = blockIdx.x;
  const int nwg = gridDim.x;
  if ((nwg & 7) == 0) {                 // XCD-chunked swizzle (bijective)
    const int chunk = nwg >> 3;
    bid = (bid & 7) * chunk + (bid >> 3);
  }
  const int mt = bid / nTN, ntl = bid - mt * nTN;
  const int m0 = mt * 256, n0 = ntl * 256;
  const int tid  = threadIdx.x;
  const int lane = tid & 63, wid = tid >> 6;
  const int wm = wid >> 2, wn = wid & 3;           // 2x4 wave grid
  const int lr = lane & 15, lk = lane >> 4;

  f32x4 acc[8][4] = {};

  auto stage_half = [&](int kt, int h, int buf) {
    const char* srcM = (h & 1) ? Wt : A;
    const int base0 = (h & 1) ? n0 : m0;
    const int koff  = kt * 64 + (h >> 1) * 32;
    const int j = tid >> 2, g = tid & 3;
    const int c = g ^ ((j >> 1) & 3);              // source chunk (involution)
    const char* src = srcM + (size_t)(base0 + 2 * j + (c >> 1)) * K
                           + koff + (c & 1) * 16;
    char* dst = lds + buf * 32768 + h * 8192 + wid * 1024;  // + lane*16 by HW
    __builtin_amdgcn_global_load_lds(
        (const __attribute__((address_space(1))) uint32_t*)src,
        (__attribute__((address_space(3))) uint32_t*)dst, 16, 0, 0);
  };
  auto rdfrag = [&](int buf, int ab, int row, int kk) -> uint2 {
    const int j = row >> 1;
    const int g = (((row & 1) << 1) + (lk >> 1)) ^ ((j >> 1) & 3);
    return *(const uint2*)(lds + buf * 32768 + (kk * 2 + ab) * 8192
                           + j * 64 + g * 16 + (lk & 1) * 8);
  };

  const int nk = K >> 6;                           // K-tiles of 64
#pragma unroll
  for (int h = 0; h < 4; ++h) stage_half(0, h, 0);
  asm volatile("s_waitcnt vmcnt(0)" ::: "memory");
  __builtin_amdgcn_s_barrier();
  asm volatile("" ::: "memory");

  uint2 bfr[4];
  for (int t = 0; t < nk; ++t) {
    const int cur = t & 1;
    const bool pre = (t + 1 < nk);
#pragma unroll
    for (int p = 0; p < 4; ++p) {
      const int kk = p >> 1, mg = p & 1;
      if (mg == 0) {
#pragma unroll
        for (int n = 0; n < 4; ++n) bfr[n] = rdfrag(cur, 1, wn * 64 + n * 16 + lr, kk);
      }
      uint2 af[4];
#pragma unroll
      for (int j = 0; j < 4; ++j)
        af[j] = rdfrag(cur, 0, wm * 128 + (mg * 4 + j) * 16 + lr, kk);
      if (pre) stage_half(t + 1, p, cur ^ 1);
      __builtin_amdgcn_s_setprio(1);
#pragma unroll
      for (int j = 0; j < 4; ++j)
#pragma unroll
        for (int n = 0; n < 4; ++n)
          acc[mg * 4 + j][n] = __builtin_amdgcn_mfma_f32_16x16x32_fp8_fp8(
              u2l(af[j]), u2l(bfr[n]), acc[mg * 4 + j][n], 0, 0, 0);
      __builtin_amdgcn_s_setprio(0);
      if (p == 1) {               // need h2,h3 of cur before p2 reads
        if (pre) asm volatile("s_waitcnt vmcnt(2)" ::: "memory");
        else     asm volatile("s_waitcnt vmcnt(0)" ::: "memory");
      } else if (p == 3 && pre) { // need h0',h1' of next before its p0
        asm volatile("s_waitcnt vmcnt(2)" ::: "memory");
      }
      __builtin_amdgcn_s_barrier();
      asm volatile("" ::: "memory");
    }
  }

  // ---- epilogue. D layout per MFMA: row = lk*4+i, col = lr (m89-verified).
  if constexpr (MODE == 0) {
    float* my = (float*)lds + wid * 1088;          // 16 rows x 68 f32 per wave
    float bc[4];
#pragma unroll
    for (int n = 0; n < 4; ++n) bc[n] = bias[n0 + wn * 64 + n * 16 + lr];
    const int rrow = lane >> 2, sgt = lane & 3;    // row 0..15, 16B seg 0..3
    const int n_img = (unsigned)m0 / LIN;          // LIN%256==0: no crossing
    const int head  = (n0 + wn * 64) >> 6;
    char* plane = (char*)Cout
        + ((size_t)(n_img * NHD + head) * LIN + (m0 - n_img * LIN)) * 64;
#pragma unroll
    for (int m = 0; m < 8; ++m) {
#pragma unroll
      for (int n = 0; n < 4; ++n)
#pragma unroll
        for (int i = 0; i < 4; ++i)
          my[(lk * 4 + i) * 68 + n * 16 + lr] = acc[m][n][i] + bc[n];
      const float* src = my + rrow * 68 + sgt * 16;
      uint32_t w[4];
#pragma unroll
      for (int q = 0; q < 4; ++q) {
        uint32_t pk = 0;
        pk = __builtin_amdgcn_cvt_pk_fp8_f32(src[q*4+0], src[q*4+1], pk, false);
        pk = __builtin_amdgcn_cvt_pk_fp8_f32(src[q*4+2], src[q*4+3], pk, true);
        w[q] = pk;
      }
      char* orow = plane + (size_t)(wm * 128 + m * 16 + rrow) * 64 + sgt * 16;
      *(uint4*)orow = *(uint4*)w;
    }
  } else {
#pragma unroll
    for (int n = 0; n < 4; ++n) {
      const int col = n0 + wn * 64 + n * 16 + lr;
      const float bcol = bias[col];
      const float gcol = gammav[col];
#pragma unroll
      for (int m = 0; m < 8; ++m) {
        const int rbase = m0 + wm * 128 + m * 16 + lk * 4;
#pragma unroll
        for (int i = 0; i < 4; ++i) {
          const size_t o = (size_t)(rbase + i) * N + col;
          ((float*)Cout)[o] = resid[o] + gcol * (acc[m][n][i] + bcol);
        }
      }
    }
  }
}

// ---------------- 2-phase 128x128 bf16 GEMM (fused so|aw, f32 out) ---------
__global__ __launch_bounds__(256) void gemm_bt(
    const ushort* __restrict__ A, const ushort* __restrict__ Wt,
    const float* __restrict__ bias, float* __restrict__ Cout,
    int M, int N, int K, int nTN)
{
  int bid = blockIdx.x;
  const int nwg = gridDim.x;
  if ((nwg & 7) == 0) {
    const int chunk = nwg >> 3;
    bid = (bid & 7) * chunk + (bid >> 3);
  }
  const int mt = bid / nTN;
  const int nt = bid - mt * nTN;
  const int m0 = mt * 128, n0 = nt * 128;
  const int tid  = threadIdx.x;
  const int lane = tid & 63, wid = tid >> 6;
  const int wm = wid >> 1, wn = wid & 1;
  const int lr = lane & 15, lk = lane >> 4;

  __shared__ __align__(16) ushort lds[2][8192];

  f32x4 acc[4][4] = {};

  auto stage = [&](int kt, int buf) {
    const int k0 = kt * 32;
#pragma unroll
    for (int it = 0; it < 2; ++it) {
      const int c   = it * 256 + wid * 64 + lane;
      const int row = c >> 2, g = c & 3;
      const ushort* srcA = A + (size_t)(m0 + row) * K + (k0 + g * 8);
      ushort* dstA = &lds[buf][(it * 256 + wid * 64) * 8];
      __builtin_amdgcn_global_load_lds(
          (const __attribute__((address_space(1))) uint32_t*)srcA,
          (__attribute__((address_space(3))) uint32_t*)dstA, 16, 0, 0);
      const ushort* srcB = Wt + (size_t)(n0 + row) * K + (k0 + g * 8);
      ushort* dstB = &lds[buf][4096 + (it * 256 + wid * 64) * 8];
      __builtin_amdgcn_global_load_lds(
          (const __attribute__((address_space(1))) uint32_t*)srcB,
          (__attribute__((address_space(3))) uint32_t*)dstB, 16, 0, 0);
    }
  };

  stage(0, 0);
  __syncthreads();
  const int nk = K >> 5;
  for (int kt = 0; kt < nk; ++kt) {
    const int cur = kt & 1;
    if (kt + 1 < nk) stage(kt + 1, cur ^ 1);
    const ushort* As = &lds[cur][0];
    const ushort* Bs = &lds[cur][4096];
    bfx8 af[4], bv[4];
#pragma unroll
    for (int m = 0; m < 4; ++m)
      af[m] = *(const bfx8*)(As + (wm * 64 + m * 16 + lr) * 32 + lk * 8);
#pragma unroll
    for (int n = 0; n < 4; ++n)
      bv[n] = *(const bfx8*)(Bs + (wn * 64 + n * 16 + lr) * 32 + lk * 8);
#pragma unroll
    for (int m = 0; m < 4; ++m)
#pragma unroll
      for (int n = 0; n < 4; ++n)
        acc[m][n] = __builtin_amdgcn_mfma_f32_16x16x32_bf16(af[m], bv[n], acc[m][n], 0, 0, 0);
    __syncthreads();
  }

#pragma unroll
  for (int n = 0; n < 4; ++n) {
    const int col = n0 + wn * 64 + n * 16 + lr;
    const float bcol = bias[col];
#pragma unroll
    for (int m = 0; m < 4; ++m) {
      const int rbase = m0 + wm * 64 + m * 16 + lk * 4;
#pragma unroll
      for (int i = 0; i < 4; ++i)
        Cout[(size_t)(rbase + i) * N + col] = acc[m][n][i] + bcol;
    }
  }
}

// ---------------- softmax over 12 + pack sampling params --------------------
__global__ void softmax_pack(const float* __restrict__ raw,
                             const float* __restrict__ refp,
                             float4* __restrict__ params) {
  const int t = blockIdx.x * 256 + threadIdx.x;       // [0, MQ*NHD)
  const int h = t % NHD, nq = t / NHD;
  const float* p = raw + (size_t)nq * CAT_N + AW_OFF + h * 12;
  float v[12], m = -1e30f;
#pragma unroll
  for (int j = 0; j < 12; ++j) { v[j] = p[j]; m = fmaxf(m, v[j]); }
  float s = 0.f;
#pragma unroll
  for (int j = 0; j < 12; ++j) { v[j] = __expf(v[j] - m); s += v[j]; }
  const float inv = 1.f / s;
  const float* op = raw + (size_t)nq * CAT_N + h * 24;
  const float* rp = refp + (size_t)nq * (NLVL * 2);
  float4* out = params + (size_t)t * 12;
  const float Wf[3] = {128.f, 64.f, 32.f};
#pragma unroll
  for (int l = 0; l < NLVL; ++l) {
    const float rxw = rp[2 * l] * Wf[l] - 0.5f;
    const float ryw = rp[2 * l + 1] * Wf[l] - 0.5f;
#pragma unroll
    for (int pt = 0; pt < NPT; ++pt) {
      float4 o4;
      o4.x = rxw + op[(l * 4 + pt) * 2 + 0];
      o4.y = ryw + op[(l * 4 + pt) * 2 + 1];
      o4.z = v[l * 4 + pt] * inv;
      o4.w = 0.f;
      out[l * 4 + pt] = o4;
    }
  }
}

// ------------- deformable sampling: 16 channels/lane, fp8 ------------------
// value layout [g=n*NHD+h][LIN][64] e4m3. Wave = 16 queries x 4 lanes;
// lane: qi = lane>>2 (query), ci = lane&3 (16-channel group, uint4 gather).
// vs 4-ch/lane version: 4x fewer load instructions, 4x less coord VALU.
// Block = 4 waves = 64 queries of one plane; 64 blocks/group; XCD-pinned.
__global__ __launch_bounds__(256) void deform_grp16(
    const char* __restrict__ vbytes, const float4* __restrict__ params,
    char* __restrict__ samp)
{
  const int j = blockIdx.x;                   // 3072 blocks
  const int x = j & 7, k = j >> 3;            // k in [0,384)
  const int g = x + ((k >> 6) << 3);          // plane, pinned to XCD x
  const int i = k & 63;                       // block within group
  const int n = g / NHD, h = g - n * NHD;
  const int wid = threadIdx.x >> 6, lane = threadIdx.x & 63;
  const int qi = lane >> 2, ci = lane & 3;
  const int q  = i * 64 + wid * 16 + qi;      // [0, 4096)
  const int nq = n * LQ + q;
  const float4* __restrict__ pp = params + ((size_t)nq * NHD + h) * 12;
  const uint32_t base0 = (uint32_t)g * (uint32_t)(LIN * 64)
                       + ((uint32_t)ci << 4);

  float acc[16];
#pragma unroll
  for (int c = 0; c < 16; ++c) acc[c] = 0.f;

  const int      Wl[3]  = {128, 64, 32};
  const uint32_t STb[3] = {0u, 16384u * 64u, 20480u * 64u};

#pragma unroll
  for (int l = 0; l < NLVL; ++l) {
    const int W_ = Wl[l];
    const uint32_t base = base0 + STb[l];
#pragma unroll
    for (int p = 0; p < NPT; ++p) {
      const float4 pt = pp[l * 4 + p];
      const float fx = floorf(pt.x), fy = floorf(pt.y);
      const float tx = pt.x - fx,   ty = pt.y - fy;
      const int x0 = (int)fx, y0 = (int)fy;
      const int x1 = x0 + 1,  y1 = y0 + 1;
      const float wx0 = ((uint32_t)x0 < (uint32_t)W_) ? (1.f - tx) : 0.f;
      const float wx1 = ((uint32_t)x1 < (uint32_t)W_) ? tx : 0.f;
      const float wy0 = ((uint32_t)y0 < (uint32_t)W_) ? pt.z * (1.f - ty) : 0.f;
      const float wy1 = ((uint32_t)y1 < (uint32_t)W_) ? pt.z * ty : 0.f;
      const int xc0 = min(max(x0, 0), W_ - 1);
      const int xc1 = min(max(x1, 0), W_ - 1);
      const int yr0 = min(max(y0, 0), W_ - 1) * W_;
      const int yr1 = min(max(y1, 0), W_ - 1) * W_;
      const float cw[4] = {wy0 * wx0, wy0 * wx1, wy1 * wx0, wy1 * wx1};
      const uint4 G0 = *(const uint4*)(vbytes + base + (uint32_t)(yr0 + xc0) * 64u);
      const uint4 G1 = *(const uint4*)(vbytes + base + (uint32_t)(yr0 + xc1) * 64u);
      const uint4 G2 = *(const uint4*)(vbytes + base + (uint32_t)(yr1 + xc0) * 64u);
      const uint4 G3 = *(const uint4*)(vbytes + base + (uint32_t)(yr1 + xc1) * 64u);
      const uint4 GG[4] = {G0, G1, G2, G3};
#pragma unroll
      for (int cnr = 0; cnr < 4; ++cnr) {
        const uint32_t wds[4] = {GG[cnr].x, GG[cnr].y, GG[cnr].z, GG[cnr].w};
        const float wgt = cw[cnr];
#pragma unroll
        for (int wd = 0; wd < 4; ++wd) {
          f32x2 lo = __builtin_amdgcn_cvt_pk_f32_fp8(wds[wd], false);
          f32x2 hi = __builtin_amdgcn_cvt_pk_f32_fp8(wds[wd], true);
          acc[wd * 4 + 0] += lo[0] * wgt;
          acc[wd * 4 + 1] += lo[1] * wgt;
          acc[wd * 4 + 2] += hi[0] * wgt;
          acc[wd * 4 + 3] += hi[1] * wgt;
        }
      }
    }
  }

  uint32_t out[4];
#pragma unroll
  for (int wd = 0; wd < 4; ++wd) {
    uint32_t pk = 0;
    pk = __builtin_amdgcn_cvt_pk_fp8_f32(acc[wd*4+0], acc[wd*4+1], pk, false);
    pk = __builtin_amdgcn_cvt_pk_fp8_f32(acc[wd*4+2], acc[wd*4+3], pk, true);
    out[wd] = pk;
  }
  *(uint4*)(samp + (size_t)nq * CDIM + h * HDIM + ci * 16) = *(uint4*)out;
}

// ---------------- host ------------------------------------------------------
extern "C" void kernel_launch(void* const* d_in, const int* in_sizes, int n_in,
                              void* d_out, int out_size, void* d_ws, size_t ws_size,
                              hipStream_t stream) {
  const float* query = (const float*)d_in[0];
  const float* refp  = (const float*)d_in[1];
  const float* feat  = (const float*)d_in[2];
  const float* qn_w  = (const float*)d_in[3];
  const float* qn_b  = (const float*)d_in[4];
  const float* fn_w  = (const float*)d_in[5];
  const float* fn_b  = (const float*)d_in[6];
  const float* gamma = (const float*)d_in[7];
  const float* so_w  = (const float*)d_in[8];
  const float* so_b  = (const float*)d_in[9];
  const float* aw_w  = (const float*)d_in[10];
  const float* aw_b  = (const float*)d_in[11];
  const float* vp_w  = (const float*)d_in[12];
  const float* vp_b  = (const float*)d_in[13];
  const float* op_w  = (const float*)d_in[14];
  const float* op_b  = (const float*)d_in[15];

  char* ws = (char*)d_ws;
  size_t off = 0;
  auto alloc = [&](size_t bytes) {
    char* p = ws + off;
    off = (off + bytes + 255) & ~(size_t)255;
    return p;
  };
  ushort* q_bf   = (ushort*)alloc((size_t)MQ * CDIM * 2);
  char*   val_f8 = (char*)alloc((size_t)MF * CDIM);        // [48][LIN][64] e4m3
  char*   vp_w8  = (char*)alloc((size_t)CDIM * CDIM);
  char*   op_w8  = (char*)alloc((size_t)CDIM * CDIM);
  ushort* cat_wT = (ushort*)alloc((size_t)CAT_N * CDIM * 2);
  float*  cat_bp = (float*)alloc(CAT_N * 4);

  // region R: f_f8 (phase A) aliases the phase-B buffers
  const size_t r = off;
  char* f_f8 = ws + r;
  const size_t f_end = r + (size_t)MF * CDIM;
  size_t o2 = r;
  float*  raw     = (float*)(ws + o2);  o2 += (size_t)MQ * CAT_N * 4;
  float4* params  = (float4*)(ws + o2); o2 += (size_t)MQ * NHD * 12 * 16;
  char*   samp8   = (char*)(ws + o2);   o2 += (size_t)MQ * CDIM;
  const size_t need = (f_end > o2) ? f_end : o2;
  if (ws_size < need) return;   // ~180 MB required

  // 1) weights: vp/op -> fp8 transposed; cat (so|aw) -> bf16 transposed
  transpose_tile<1><<<24 * 24, 256, 0, stream>>>(vp_w, vp_w8, CDIM, CDIM, CDIM);
  transpose_tile<1><<<24 * 24, 256, 0, stream>>>(op_w, op_w8, CDIM, CDIM, CDIM);
  transpose_tile<0><<<24 * 9,  256, 0, stream>>>(so_w, cat_wT, CDIM, 288, AW_OFF);
  transpose_tile<0><<<24 * 7,  256, 0, stream>>>(
      aw_w, cat_wT + (size_t)AW_OFF * CDIM, CDIM, 144, CAT_N - AW_OFF);
  pad_bias<<<2, 256, 0, stream>>>(so_b, cat_bp, 288, AW_OFF);
  pad_bias<<<1, 256, 0, stream>>>(aw_b, cat_bp + AW_OFF, 144, CAT_N - AW_OFF);

  // 2) layernorms (1 wave/row): query -> bf16, feat -> fp8
  ln_wave<0><<<MQ / 4, 256, 0, stream>>>(query, qn_w, qn_b, q_bf);
  ln_wave<1><<<MF / 4, 256, 0, stream>>>(feat, fn_w, fn_b, f_f8);

  // 3) value = LN(feat) @ vp_w + vp_b   (fp8 GEMM, fp8 head-major out)
  gemm8_f8<0><<<(MF / 256) * (CDIM / 256), 512, 0, stream>>>(
      f_f8, vp_w8, vp_b, val_f8, MF, CDIM, CDIM, CDIM / 256, nullptr, nullptr);

  // 4) fused sampling-offset | attn-weight GEMM  (bf16 2-phase, f32 out)
  gemm_bt<<<(MQ / 128) * (CAT_N / 128), 256, 0, stream>>>(
      q_bf, cat_wT, cat_bp, raw, MQ, CAT_N, CDIM, CAT_N / 128);

  // 5) softmax + pack {px,py,a} per (q,h,l,p)
  softmax_pack<<<(MQ * NHD) / 256, 256, 0, stream>>>(raw, refp, params);

  // 6) deformable sampling -> samp fp8 [MQ][768]  (16 ch/lane)
  deform_grp16<<<48 * 64, 256, 0, stream>>>(val_f8, params, samp8);

  // 7) out = query + gamma * (samp @ op_w + op_b)   (fp8 GEMM, fused epi)
  gemm8_f8<2><<<(MQ / 256) * (CDIM / 256), 512, 0, stream>>>(
      samp8, op_w8, op_b, (float*)d_out, MQ, CDIM, CDIM, CDIM / 256, query, gamma);
}

// Round 11
// 359.787 us; speedup vs baseline: 1.4421x; 1.0484x over previous
//
#include <hip/hip_runtime.h>
#include <hip/hip_bf16.h>
#include <stdint.h>

// ---------------- problem constants (fixed by setup_inputs) ----------------
#define NHD   12        // heads
#define NPT   4         // points
#define CDIM  768
#define HDIM  64
#define NLVL  3
#define LQ    4096
#define NB    4
#define LIN   21504     // 128*128 + 64*64 + 32*32
#define MQ    (NB*LQ)   // 16384 query rows
#define MF    (NB*LIN)  // 86016 feat rows
#define CAT_N 512       // fused so(288) | aw(144 real + pad)
#define AW_OFF 288

typedef __bf16 bfx8 __attribute__((ext_vector_type(8)));
typedef float  f32x4  __attribute__((ext_vector_type(4)));
typedef float  f32x2  __attribute__((ext_vector_type(2)));
typedef float  f32x16 __attribute__((ext_vector_type(16)));
typedef int    i32x8  __attribute__((ext_vector_type(8)));

__device__ __forceinline__ ushort f2bf(float x) {
  union { float f; uint32_t u; } v; v.f = x;
  uint32_t r = v.u + 0x7fffu + ((v.u >> 16) & 1u);   // RNE
  return (ushort)(r >> 16);
}
__device__ __forceinline__ long u2l(uint2 v) {
  union { uint2 u; long l; } x; x.u = v; return x.l;
}
__device__ __forceinline__ i32x8 mk8(uint4 lo, uint4 hi) {
  i32x8 v;
  v[0] = (int)lo.x; v[1] = (int)lo.y; v[2] = (int)lo.z; v[3] = (int)lo.w;
  v[4] = (int)hi.x; v[5] = (int)hi.y; v[6] = (int)hi.z; v[7] = (int)hi.w;
  return v;
}

// ---------------- LDS-tiled coalesced transpose + cast ---------------------
template<int F8>
__global__ __launch_bounds__(256) void transpose_tile(
    const float* __restrict__ W, void* __restrict__ Wt,
    int K, int Nsrc, int Npad)
{
  __shared__ float t[32][33];
  const int nkt = K >> 5;
  const int k0 = (blockIdx.x % nkt) * 32;
  const int n0 = (blockIdx.x / nkt) * 32;
  const int tx = threadIdx.x & 31, ty = threadIdx.x >> 5;
#pragma unroll
  for (int i = ty; i < 32; i += 8) {
    const int n = n0 + tx;
    t[i][tx] = (n < Nsrc) ? W[(size_t)(k0 + i) * Nsrc + n] : 0.f;
  }
  __syncthreads();
#pragma unroll
  for (int i = ty; i < 32; i += 8) {
    const int n = n0 + i;
    const float v = t[tx][i];
    if constexpr (F8) {
      uint32_t pk = __builtin_amdgcn_cvt_pk_fp8_f32(v, 0.f, 0, false);
      ((char*)Wt)[(size_t)n * K + k0 + tx] = (char)(pk & 0xff);
    } else {
      ((ushort*)Wt)[(size_t)n * K + k0 + tx] = f2bf(v);
    }
  }
}

__global__ void pad_bias(const float* __restrict__ src, float* __restrict__ dst,
                         int nReal, int nPad) {
  int i = blockIdx.x * 256 + threadIdx.x;
  if (i < nPad) dst[i] = (i < nReal) ? src[i] : 0.f;
}

// ---------------- LayerNorm, 1 wave/row (no barriers) ----------------------
template<int OUT8>
__global__ __launch_bounds__(256) void ln_wave(const float* __restrict__ x,
                                               const float* __restrict__ w,
                                               const float* __restrict__ b,
                                               void* __restrict__ y) {
  const int row  = blockIdx.x * 4 + (threadIdx.x >> 6);
  const int lane = threadIdx.x & 63;
  const float4* xr = (const float4*)(x + (size_t)row * CDIM);
  float4 v[3];
  v[0] = xr[lane]; v[1] = xr[lane + 64]; v[2] = xr[lane + 128];
  float s1 = 0.f, s2 = 0.f;
#pragma unroll
  for (int i = 0; i < 3; ++i) {
    s1 += v[i].x + v[i].y + v[i].z + v[i].w;
    s2 += v[i].x*v[i].x + v[i].y*v[i].y + v[i].z*v[i].z + v[i].w*v[i].w;
  }
#pragma unroll
  for (int o = 32; o > 0; o >>= 1) { s1 += __shfl_xor(s1, o); s2 += __shfl_xor(s2, o); }
  const float mu = s1 * (1.f / CDIM);
  const float rs = rsqrtf(s2 * (1.f / CDIM) - mu * mu + 1e-6f);
#pragma unroll
  for (int i = 0; i < 3; ++i) {
    const float4 w4 = ((const float4*)w)[lane + i * 64];
    const float4 b4 = ((const float4*)b)[lane + i * 64];
    const float o0 = (v[i].x - mu) * rs * w4.x + b4.x;
    const float o1 = (v[i].y - mu) * rs * w4.y + b4.y;
    const float o2 = (v[i].z - mu) * rs * w4.z + b4.z;
    const float o3 = (v[i].w - mu) * rs * w4.w + b4.w;
    if constexpr (OUT8) {
      uint32_t pk = 0;
      pk = __builtin_amdgcn_cvt_pk_fp8_f32(o0, o1, pk, false);
      pk = __builtin_amdgcn_cvt_pk_fp8_f32(o2, o3, pk, true);
      ((uint32_t*)((char*)y + (size_t)row * CDIM))[lane + i * 64] = pk;
    } else {
      ushort4 o4;
      o4.x = f2bf(o0); o4.y = f2bf(o1); o4.z = f2bf(o2); o4.w = f2bf(o3);
      ((ushort4*)((ushort*)y + (size_t)row * CDIM))[lane + i * 64] = o4;
    }
  }
}

// ======== 128x128 MX-scaled fp8 GEMM (value): 32x32x64, 4-buf pipeline ======
// C[M][N] = A * Wt^T + bias, fp8 e4m3 operands, unity e8m0 scales (0x7F =
// 2^0): numerically exact fp8 GEMM at 2x the K-per-instruction of 16x16x32.
// 256 thr = 4 waves (2M x 2N), per-wave 64x64 = 2x2 tiles of 32x32.
// BK=64. LDS: 4 bufs x (A[128][64] + B[128][64]) = 4 x 16 KB = 64 KB
// -> 2 blocks/CU. Stage 3 tiles ahead; ONE counted wait per tile:
// vmcnt(8) (12 outstanding, oldest 4 = next tile) -- drains only in 2-tile
// tail. Chunk swizzle: 16B chunk p of row r holds source chunk p^(r&3).
// Operand frag: lane l = row (l&31), k = (l>>5)*32 + e (e consecutive).
// C/D (m74/m101): col = lane&31, row = (reg&3)+8*(reg>>2)+4*(lane>>5).
// Output: fp8 head-major value [n*NHD+head][LIN][64].
__global__ __launch_bounds__(256, 2) void gemm_mx(
    const char* __restrict__ A, const char* __restrict__ Wt,
    const float* __restrict__ bias, char* __restrict__ Cout,
    int M, int N, int K, int nTN)
{
  __shared__ __align__(16) char lds[65536];   // 4 x 16 KiB

  int bid = blockIdx.x;
  const int nwg = gridDim.x;
  if ((nwg & 7) == 0) {                 // XCD-chunked swizzle (bijective)
    const int chunk = nwg >> 3;
    bid = (bid & 7) * chunk + (bid >> 3);
  }
  const int mt = bid / nTN, ntl = bid - mt * nTN;
  const int m0 = mt * 128, n0 = ntl * 128;
  const int tid  = threadIdx.x;
  const int lane = tid & 63, wid = tid >> 6;
  const int wm = wid >> 1, wn = wid & 1;          // 2x2 wave grid
  const int lr31 = lane & 31, lkb = lane >> 5;

  f32x16 acc[2][2] = {};

  // stage one operand (ab: 0=A, 1=B) of K-tile kt into buf
  auto stage = [&](int kt, int buf, int ab) {
    const char* srcM = ab ? Wt : A;
    const int base0 = ab ? n0 : m0;
    const int k0 = kt * 64;
    char* dst0 = lds + buf * 16384 + ab * 8192;
#pragma unroll
    for (int it = 0; it < 2; ++it) {
      const int i = it * 256 + tid;              // chunk 0..511
      const int r = i >> 2, p = i & 3;
      const int c = p ^ (r & 3);                 // source chunk (involution)
      const char* src = srcM + (size_t)(base0 + r) * K + k0 + c * 16;
      char* dst = dst0 + (it * 256 + wid * 64) * 16;   // + lane*16 by HW
      __builtin_amdgcn_global_load_lds(
          (const __attribute__((address_space(1))) uint32_t*)src,
          (__attribute__((address_space(3))) uint32_t*)dst, 16, 0, 0);
    }
  };
  // read one 32-byte operand fragment (row in [0,128), k = lkb*32..+31)
  auto rdop = [&](int buf, int ab, int row) -> i32x8 {
    const char* base = lds + buf * 16384 + ab * 8192 + row * 64;
    const int s = row & 3;
    const uint4 lo = *(const uint4*)(base + ((2 * lkb)     ^ s) * 16);
    const uint4 hi = *(const uint4*)(base + ((2 * lkb + 1) ^ s) * 16);
    return mk8(lo, hi);
  };

  const int nk = K >> 6;                          // 12 K-tiles
  // prologue: stage tiles 0,1,2 into bufs 0,1,2 (12 loads/thread)
#pragma unroll
  for (int t0 = 0; t0 < 3; ++t0) { stage(t0, t0, 0); stage(t0, t0, 1); }
  asm volatile("s_waitcnt vmcnt(8)" ::: "memory");  // tile 0 ready
  __builtin_amdgcn_s_barrier();
  asm volatile("" ::: "memory");

  for (int t = 0; t < nk; ++t) {
    const int cur = t & 3;
    const i32x8 a0 = rdop(cur, 0, wm * 64 + lr31);
    const i32x8 a1 = rdop(cur, 0, wm * 64 + 32 + lr31);
    const i32x8 b0 = rdop(cur, 1, wn * 64 + lr31);
    const i32x8 b1 = rdop(cur, 1, wn * 64 + 32 + lr31);
    if (t + 3 < nk) { stage(t + 3, (t + 3) & 3, 0); stage(t + 3, (t + 3) & 3, 1); }
    __builtin_amdgcn_s_setprio(1);
    acc[0][0] = __builtin_amdgcn_mfma_scale_f32_32x32x64_f8f6f4(
        a0, b0, acc[0][0], 0, 0, 0, 0x7F7F7F7F, 0, 0x7F7F7F7F);
    acc[0][1] = __builtin_amdgcn_mfma_scale_f32_32x32x64_f8f6f4(
        a0, b1, acc[0][1], 0, 0, 0, 0x7F7F7F7F, 0, 0x7F7F7F7F);
    acc[1][0] = __builtin_amdgcn_mfma_scale_f32_32x32x64_f8f6f4(
        a1, b0, acc[1][0], 0, 0, 0, 0x7F7F7F7F, 0, 0x7F7F7F7F);
    acc[1][1] = __builtin_amdgcn_mfma_scale_f32_32x32x64_f8f6f4(
        a1, b1, acc[1][1], 0, 0, 0, 0x7F7F7F7F, 0, 0x7F7F7F7F);
    __builtin_amdgcn_s_setprio(0);
    if (t + 3 < nk)      asm volatile("s_waitcnt vmcnt(8)" ::: "memory");
    else if (t + 2 < nk) asm volatile("s_waitcnt vmcnt(4)" ::: "memory");
    else if (t + 1 < nk) asm volatile("s_waitcnt vmcnt(0)" ::: "memory");
    __builtin_amdgcn_s_barrier();
    asm volatile("" ::: "memory");
  }

  // ---- epilogue: fp8 head-major store via per-wave LDS staging ----
  const int head  = (n0 + wn * 64) >> 6;
  const int n_img = (unsigned)m0 / LIN;           // LIN%128==0: no crossing
  char* plane = Cout + ((size_t)(n_img * NHD + head) * LIN
                        + (m0 - n_img * LIN)) * 64;
  float bcol[2];
#pragma unroll
  for (int nt2 = 0; nt2 < 2; ++nt2)
    bcol[nt2] = bias[n0 + wn * 64 + nt2 * 32 + lr31];
  float* my = (float*)(lds + wid * 16384);        // [32][68] f32 per wave

#pragma unroll
  for (int mt2 = 0; mt2 < 2; ++mt2) {
#pragma unroll
    for (int nt2 = 0; nt2 < 2; ++nt2)
#pragma unroll
      for (int reg = 0; reg < 16; ++reg) {
        const int row = (reg & 3) + 8 * (reg >> 2) + 4 * lkb;
        my[row * 68 + nt2 * 32 + lr31] = acc[mt2][nt2][reg] + bcol[nt2];
      }
#pragma unroll
    for (int it = 0; it < 2; ++it) {
      const int idx = it * 64 + lane;             // 0..127
      const int row = idx >> 2, seg = idx & 3;
      const float* s = my + row * 68 + seg * 16;
      uint32_t w[4];
#pragma unroll
      for (int q = 0; q < 4; ++q) {
        uint32_t pk = 0;
        pk = __builtin_amdgcn_cvt_pk_fp8_f32(s[q*4+0], s[q*4+1], pk, false);
        pk = __builtin_amdgcn_cvt_pk_fp8_f32(s[q*4+2], s[q*4+3], pk, true);
        w[q] = pk;
      }
      char* orow = plane + (size_t)(wm * 64 + mt2 * 32 + row) * 64 + seg * 16;
      *(uint4*)orow = *(uint4*)w;
    }
  }
}

// ============ 256x256 fp8 GEMM, 2-buf counted-vmcnt (out-proj) ==============
template<int MODE>
__global__ __launch_bounds__(512, 2) void gemm8_f8(
    const char* __restrict__ A, const char* __restrict__ Wt,
    const float* __restrict__ bias, void* __restrict__ Cout,
    int M, int N, int K, int nTN,
    const float* __restrict__ resid, const float* __restrict__ gammav)
{
  __shared__ __align__(16) char lds[65536];   // 2 x 32 KiB

  int bid = blockIdx.x;
  const int nwg = gridDim.x;
  if ((nwg & 7) == 0) {
    const int chunk = nwg >> 3;
    bid = (bid & 7) * chunk + (bid >> 3);
  }
  const int mt = bid / nTN, ntl = bid - mt * nTN;
  const int m0 = mt * 256, n0 = ntl * 256;
  const int tid  = threadIdx.x;
  const int lane = tid & 63, wid = tid >> 6;
  const int wm = wid >> 2, wn = wid & 3;           // 2x4 wave grid
  const int lr = lane & 15, lk = lane >> 4;

  f32x4 acc[8][4] = {};

  auto stage_half = [&](int kt, int h, int buf) {
    const char* srcM = (h & 1) ? Wt : A;
    const int base0 = (h & 1) ? n0 : m0;
    const int koff  = kt * 64 + (h >> 1) * 32;
    const int j = tid >> 2, g = tid & 3;
    const int c = g ^ ((j >> 1) & 3);
    const char* src = srcM + (size_t)(base0 + 2 * j + (c >> 1)) * K
                           + koff + (c & 1) * 16;
    char* dst = lds + buf * 32768 + h * 8192 + wid * 1024;
    __builtin_amdgcn_global_load_lds(
        (const __attribute__((address_space(1))) uint32_t*)src,
        (__attribute__((address_space(3))) uint32_t*)dst, 16, 0, 0);
  };
  auto rdfrag = [&](int buf, int ab, int row, int kk) -> uint2 {
    const int j = row >> 1;
    const int g = (((row & 1) << 1) + (lk >> 1)) ^ ((j >> 1) & 3);
    return *(const uint2*)(lds + buf * 32768 + (kk * 2 + ab) * 8192
                           + j * 64 + g * 16 + (lk & 1) * 8);
  };

  const int nk = K >> 6;
#pragma unroll
  for (int h = 0; h < 4; ++h) stage_half(0, h, 0);
  asm volatile("s_waitcnt vmcnt(0)" ::: "memory");
  __builtin_amdgcn_s_barrier();
  asm volatile("" ::: "memory");

  uint2 bfr[4];
  for (int t = 0; t < nk; ++t) {
    const int cur = t & 1;
    const bool pre = (t + 1 < nk);
#pragma unroll
    for (int p = 0; p < 4; ++p) {
      const int kk = p >> 1, mg = p & 1;
      if (mg == 0) {
#pragma unroll
        for (int n = 0; n < 4; ++n) bfr[n] = rdfrag(cur, 1, wn * 64 + n * 16 + lr, kk);
      }
      uint2 af[4];
#pragma unroll
      for (int j = 0; j < 4; ++j)
        af[j] = rdfrag(cur, 0, wm * 128 + (mg * 4 + j) * 16 + lr, kk);
      if (pre) stage_half(t + 1, p, cur ^ 1);
      __builtin_amdgcn_s_setprio(1);
#pragma unroll
      for (int j = 0; j < 4; ++j)
#pragma unroll
        for (int n = 0; n < 4; ++n)
          acc[mg * 4 + j][n] = __builtin_amdgcn_mfma_f32_16x16x32_fp8_fp8(
              u2l(af[j]), u2l(bfr[n]), acc[mg * 4 + j][n], 0, 0, 0);
      __builtin_amdgcn_s_setprio(0);
      if (p == 1) {
        if (pre) asm volatile("s_waitcnt vmcnt(2)" ::: "memory");
        else     asm volatile("s_waitcnt vmcnt(0)" ::: "memory");
      } else if (p == 3 && pre) {
        asm volatile("s_waitcnt vmcnt(2)" ::: "memory");
      }
      __builtin_amdgcn_s_barrier();
      asm volatile("" ::: "memory");
    }
  }

#pragma unroll
  for (int n = 0; n < 4; ++n) {
    const int col = n0 + wn * 64 + n * 16 + lr;
    const float bcol = bias[col];
    const float gcol = gammav[col];
#pragma unroll
    for (int m = 0; m < 8; ++m) {
      const int rbase = m0 + wm * 128 + m * 16 + lk * 4;
#pragma unroll
      for (int i = 0; i < 4; ++i) {
        const size_t o = (size_t)(rbase + i) * N + col;
        ((float*)Cout)[o] = resid[o] + gcol * (acc[m][n][i] + bcol);
      }
    }
  }
}

// ---------------- 2-phase 128x128 bf16 GEMM (fused so|aw, f32 out) ---------
__global__ __launch_bounds__(256) void gemm_bt(
    const ushort* __restrict__ A, const ushort* __restrict__ Wt,
    const float* __restrict__ bias, float* __restrict__ Cout,
    int M, int N, int K, int nTN)
{
  int bid = blockIdx.x;
  const int nwg = gridDim.x;
  if ((nwg & 7) == 0) {
    const int chunk = nwg >> 3;
    bid = (bid & 7) * chunk + (bid >> 3);
  }
  const int mt = bid / nTN;
  const int nt = bid - mt * nTN;
  const int m0 = mt * 128, n0 = nt * 128;
  const int tid  = threadIdx.x;
  const int lane = tid & 63, wid = tid >> 6;
  const int wm = wid >> 1, wn = wid & 1;
  const int lr = lane & 15, lk = lane >> 4;

  __shared__ __align__(16) ushort lds[2][8192];

  f32x4 acc[4][4] = {};

  auto stage = [&](int kt, int buf) {
    const int k0 = kt * 32;
#pragma unroll
    for (int it = 0; it < 2; ++it) {
      const int c   = it * 256 + wid * 64 + lane;
      const int row = c >> 2, g = c & 3;
      const ushort* srcA = A + (size_t)(m0 + row) * K + (k0 + g * 8);
      ushort* dstA = &lds[buf][(it * 256 + wid * 64) * 8];
      __builtin_amdgcn_global_load_lds(
          (const __attribute__((address_space(1))) uint32_t*)srcA,
          (__attribute__((address_space(3))) uint32_t*)dstA, 16, 0, 0);
      const ushort* srcB = Wt + (size_t)(n0 + row) * K + (k0 + g * 8);
      ushort* dstB = &lds[buf][4096 + (it * 256 + wid * 64) * 8];
      __builtin_amdgcn_global_load_lds(
          (const __attribute__((address_space(1))) uint32_t*)srcB,
          (__attribute__((address_space(3))) uint32_t*)dstB, 16, 0, 0);
    }
  };

  stage(0, 0);
  __syncthreads();
  const int nk = K >> 5;
  for (int kt = 0; kt < nk; ++kt) {
    const int cur = kt & 1;
    if (kt + 1 < nk) stage(kt + 1, cur ^ 1);
    const ushort* As = &lds[cur][0];
    const ushort* Bs = &lds[cur][4096];
    bfx8 af[4], bv[4];
#pragma unroll
    for (int m = 0; m < 4; ++m)
      af[m] = *(const bfx8*)(As + (wm * 64 + m * 16 + lr) * 32 + lk * 8);
#pragma unroll
    for (int n = 0; n < 4; ++n)
      bv[n] = *(const bfx8*)(Bs + (wn * 64 + n * 16 + lr) * 32 + lk * 8);
#pragma unroll
    for (int m = 0; m < 4; ++m)
#pragma unroll
      for (int n = 0; n < 4; ++n)
        acc[m][n] = __builtin_amdgcn_mfma_f32_16x16x32_bf16(af[m], bv[n], acc[m][n], 0, 0, 0);
    __syncthreads();
  }

#pragma unroll
  for (int n = 0; n < 4; ++n) {
    const int col = n0 + wn * 64 + n * 16 + lr;
    const float bcol = bias[col];
#pragma unroll
    for (int m = 0; m < 4; ++m) {
      const int rbase = m0 + wm * 64 + m * 16 + lk * 4;
#pragma unroll
      for (int i = 0; i < 4; ++i)
        Cout[(size_t)(rbase + i) * N + col] = acc[m][n][i] + bcol;
    }
  }
}

// ---------------- softmax over 12 + pack sampling params --------------------
__global__ void softmax_pack(const float* __restrict__ raw,
                             const float* __restrict__ refp,
                             float4* __restrict__ params) {
  const int t = blockIdx.x * 256 + threadIdx.x;       // [0, MQ*NHD)
  const int h = t % NHD, nq = t / NHD;
  const float* p = raw + (size_t)nq * CAT_N + AW_OFF + h * 12;
  float v[12], m = -1e30f;
#pragma unroll
  for (int j = 0; j < 12; ++j) { v[j] = p[j]; m = fmaxf(m, v[j]); }
  float s = 0.f;
#pragma unroll
  for (int j = 0; j < 12; ++j) { v[j] = __expf(v[j] - m); s += v[j]; }
  const float inv = 1.f / s;
  const float* op = raw + (size_t)nq * CAT_N + h * 24;
  const float* rp = refp + (size_t)nq * (NLVL * 2);
  float4* out = params + (size_t)t * 12;
  const float Wf[3] = {128.f, 64.f, 32.f};
#pragma unroll
  for (int l = 0; l < NLVL; ++l) {
    const float rxw = rp[2 * l] * Wf[l] - 0.5f;
    const float ryw = rp[2 * l + 1] * Wf[l] - 0.5f;
#pragma unroll
    for (int pt = 0; pt < NPT; ++pt) {
      float4 o4;
      o4.x = rxw + op[(l * 4 + pt) * 2 + 0];
      o4.y = ryw + op[(l * 4 + pt) * 2 + 1];
      o4.z = v[l * 4 + pt] * inv;
      o4.w = 0.f;
      out[l * 4 + pt] = o4;
    }
  }
}

// ------------- deformable sampling: 16 channels/lane, fp8 ------------------
__global__ __launch_bounds__(256) void deform_grp16(
    const char* __restrict__ vbytes, const float4* __restrict__ params,
    char* __restrict__ samp)
{
  const int j = blockIdx.x;                   // 3072 blocks
  const int x = j & 7, k = j >> 3;            // k in [0,384)
  const int g = x + ((k >> 6) << 3);          // plane, pinned to XCD x
  const int i = k & 63;                       // block within group
  const int n = g / NHD, h = g - n * NHD;
  const int wid = threadIdx.x >> 6, lane = threadIdx.x & 63;
  const int qi = lane >> 2, ci = lane & 3;
  const int q  = i * 64 + wid * 16 + qi;      // [0, 4096)
  const int nq = n * LQ + q;
  const float4* __restrict__ pp = params + ((size_t)nq * NHD + h) * 12;
  const uint32_t base0 = (uint32_t)g * (uint32_t)(LIN * 64)
                       + ((uint32_t)ci << 4);

  float acc[16];
#pragma unroll
  for (int c = 0; c < 16; ++c) acc[c] = 0.f;

  const int      Wl[3]  = {128, 64, 32};
  const uint32_t STb[3] = {0u, 16384u * 64u, 20480u * 64u};

#pragma unroll
  for (int l = 0; l < NLVL; ++l) {
    const int W_ = Wl[l];
    const uint32_t base = base0 + STb[l];
#pragma unroll
    for (int p = 0; p < NPT; ++p) {
      const float4 pt = pp[l * 4 + p];
      const float fx = floorf(pt.x), fy = floorf(pt.y);
      const float tx = pt.x - fx,   ty = pt.y - fy;
      const int x0 = (int)fx, y0 = (int)fy;
      const int x1 = x0 + 1,  y1 = y0 + 1;
      const float wx0 = ((uint32_t)x0 < (uint32_t)W_) ? (1.f - tx) : 0.f;
      const float wx1 = ((uint32_t)x1 < (uint32_t)W_) ? tx : 0.f;
      const float wy0 = ((uint32_t)y0 < (uint32_t)W_) ? pt.z * (1.f - ty) : 0.f;
      const float wy1 = ((uint32_t)y1 < (uint32_t)W_) ? pt.z * ty : 0.f;
      const int xc0 = min(max(x0, 0), W_ - 1);
      const int xc1 = min(max(x1, 0), W_ - 1);
      const int yr0 = min(max(y0, 0), W_ - 1) * W_;
      const int yr1 = min(max(y1, 0), W_ - 1) * W_;
      const float cw[4] = {wy0 * wx0, wy0 * wx1, wy1 * wx0, wy1 * wx1};
      const uint4 G0 = *(const uint4*)(vbytes + base + (uint32_t)(yr0 + xc0) * 64u);
      const uint4 G1 = *(const uint4*)(vbytes + base + (uint32_t)(yr0 + xc1) * 64u);
      const uint4 G2 = *(const uint4*)(vbytes + base + (uint32_t)(yr1 + xc0) * 64u);
      const uint4 G3 = *(const uint4*)(vbytes + base + (uint32_t)(yr1 + xc1) * 64u);
      const uint4 GG[4] = {G0, G1, G2, G3};
#pragma unroll
      for (int cnr = 0; cnr < 4; ++cnr) {
        const uint32_t wds[4] = {GG[cnr].x, GG[cnr].y, GG[cnr].z, GG[cnr].w};
        const float wgt = cw[cnr];
#pragma unroll
        for (int wd = 0; wd < 4; ++wd) {
          f32x2 lo = __builtin_amdgcn_cvt_pk_f32_fp8(wds[wd], false);
          f32x2 hi = __builtin_amdgcn_cvt_pk_f32_fp8(wds[wd], true);
          acc[wd * 4 + 0] += lo[0] * wgt;
          acc[wd * 4 + 1] += lo[1] * wgt;
          acc[wd * 4 + 2] += hi[0] * wgt;
          acc[wd * 4 + 3] += hi[1] * wgt;
        }
      }
    }
  }

  uint32_t out[4];
#pragma unroll
  for (int wd = 0; wd < 4; ++wd) {
    uint32_t pk = 0;
    pk = __builtin_amdgcn_cvt_pk_fp8_f32(acc[wd*4+0], acc[wd*4+1], pk, false);
    pk = __builtin_amdgcn_cvt_pk_fp8_f32(acc[wd*4+2], acc[wd*4+3], pk, true);
    out[wd] = pk;
  }
  *(uint4*)(samp + (size_t)nq * CDIM + h * HDIM + ci * 16) = *(uint4*)out;
}

// ---------------- host ------------------------------------------------------
extern "C" void kernel_launch(void* const* d_in, const int* in_sizes, int n_in,
                              void* d_out, int out_size, void* d_ws, size_t ws_size,
                              hipStream_t stream) {
  const float* query = (const float*)d_in[0];
  const float* refp  = (const float*)d_in[1];
  const float* feat  = (const float*)d_in[2];
  const float* qn_w  = (const float*)d_in[3];
  const float* qn_b  = (const float*)d_in[4];
  const float* fn_w  = (const float*)d_in[5];
  const float* fn_b  = (const float*)d_in[6];
  const float* gamma = (const float*)d_in[7];
  const float* so_w  = (const float*)d_in[8];
  const float* so_b  = (const float*)d_in[9];
  const float* aw_w  = (const float*)d_in[10];
  const float* aw_b  = (const float*)d_in[11];
  const float* vp_w  = (const float*)d_in[12];
  const float* vp_b  = (const float*)d_in[13];
  const float* op_w  = (const float*)d_in[14];
  const float* op_b  = (const float*)d_in[15];

  char* ws = (char*)d_ws;
  size_t off = 0;
  auto alloc = [&](size_t bytes) {
    char* p = ws + off;
    off = (off + bytes + 255) & ~(size_t)255;
    return p;
  };
  ushort* q_bf   = (ushort*)alloc((size_t)MQ * CDIM * 2);
  char*   val_f8 = (char*)alloc((size_t)MF * CDIM);        // [48][LIN][64] e4m3
  char*   vp_w8  = (char*)alloc((size_t)CDIM * CDIM);
  char*   op_w8  = (char*)alloc((size_t)CDIM * CDIM);
  ushort* cat_wT = (ushort*)alloc((size_t)CAT_N * CDIM * 2);
  float*  cat_bp = (float*)alloc(CAT_N * 4);

  // region R: f_f8 (phase A) aliases the phase-B buffers
  const size_t r = off;
  char* f_f8 = ws + r;
  const size_t f_end = r + (size_t)MF * CDIM;
  size_t o2 = r;
  float*  raw     = (float*)(ws + o2);  o2 += (size_t)MQ * CAT_N * 4;
  float4* params  = (float4*)(ws + o2); o2 += (size_t)MQ * NHD * 12 * 16;
  char*   samp8   = (char*)(ws + o2);   o2 += (size_t)MQ * CDIM;
  const size_t need = (f_end > o2) ? f_end : o2;
  if (ws_size < need) return;   // ~180 MB required

  // 1) weights: vp/op -> fp8 transposed; cat (so|aw) -> bf16 transposed
  transpose_tile<1><<<24 * 24, 256, 0, stream>>>(vp_w, vp_w8, CDIM, CDIM, CDIM);
  transpose_tile<1><<<24 * 24, 256, 0, stream>>>(op_w, op_w8, CDIM, CDIM, CDIM);
  transpose_tile<0><<<24 * 9,  256, 0, stream>>>(so_w, cat_wT, CDIM, 288, AW_OFF);
  transpose_tile<0><<<24 * 7,  256, 0, stream>>>(
      aw_w, cat_wT + (size_t)AW_OFF * CDIM, CDIM, 144, CAT_N - AW_OFF);
  pad_bias<<<2, 256, 0, stream>>>(so_b, cat_bp, 288, AW_OFF);
  pad_bias<<<1, 256, 0, stream>>>(aw_b, cat_bp + AW_OFF, 144, CAT_N - AW_OFF);

  // 2) layernorms (1 wave/row): query -> bf16, feat -> fp8
  ln_wave<0><<<MQ / 4, 256, 0, stream>>>(query, qn_w, qn_b, q_bf);
  ln_wave<1><<<MF / 4, 256, 0, stream>>>(feat, fn_w, fn_b, f_f8);

  // 3) value = LN(feat) @ vp_w + vp_b   (MX-scaled 32x32x64 fp8, unity scales)
  gemm_mx<<<(MF / 128) * (CDIM / 128), 256, 0, stream>>>(
      f_f8, vp_w8, vp_b, val_f8, MF, CDIM, CDIM, CDIM / 128);

  // 4) fused sampling-offset | attn-weight GEMM  (bf16 2-phase, f32 out)
  gemm_bt<<<(MQ / 128) * (CAT_N / 128), 256, 0, stream>>>(
      q_bf, cat_wT, cat_bp, raw, MQ, CAT_N, CDIM, CAT_N / 128);

  // 5) softmax + pack {px,py,a} per (q,h,l,p)
  softmax_pack<<<(MQ * NHD) / 256, 256, 0, stream>>>(raw, refp, params);

  // 6) deformable sampling -> samp fp8 [MQ][768]  (16 ch/lane)
  deform_grp16<<<48 * 64, 256, 0, stream>>>(val_f8, params, samp8);

  // 7) out = query + gamma * (samp @ op_w + op_b)   (fp8 GEMM, fused epi)
  gemm8_f8<2><<<(MQ / 256) * (CDIM / 256), 512, 0, stream>>>(
      samp8, op_w8, op_b, (float*)d_out, MQ, CDIM, CDIM, CDIM / 256, query, gamma);
}

// Round 12
// 299.430 us; speedup vs baseline: 1.7328x; 1.2016x over previous
//
#include <hip/hip_runtime.h>
#include <hip/hip_bf16.h>
#include <stdint.h>

// ---------------- problem constants (fixed by setup_inputs) ----------------
#define NHD   12        // heads
#define NPT   4         // points
#define CDIM  768
#define HDIM  64
#define NLVL  3
#define LQ    4096
#define NB    4
#define LIN   21504     // 128*128 + 64*64 + 32*32
#define MQ    (NB*LQ)   // 16384 query rows
#define MF    (NB*LIN)  // 86016 feat rows
#define CAT_N 512       // fused so(288) | aw(144 real + pad)
#define AW_OFF 288
#define WSCL  16.f      // so/aw weight pre-scale (fp8 denormal avoidance)

typedef float  f32x4  __attribute__((ext_vector_type(4)));
typedef float  f32x2  __attribute__((ext_vector_type(2)));
typedef float  f32x16 __attribute__((ext_vector_type(16)));
typedef int    i32x8  __attribute__((ext_vector_type(8)));

__device__ __forceinline__ ushort f2bf(float x) {
  union { float f; uint32_t u; } v; v.f = x;
  uint32_t r = v.u + 0x7fffu + ((v.u >> 16) & 1u);   // RNE
  return (ushort)(r >> 16);
}
__device__ __forceinline__ i32x8 mk8(uint4 lo, uint4 hi) {
  i32x8 v;
  v[0] = (int)lo.x; v[1] = (int)lo.y; v[2] = (int)lo.z; v[3] = (int)lo.w;
  v[4] = (int)hi.x; v[5] = (int)hi.y; v[6] = (int)hi.z; v[7] = (int)hi.w;
  return v;
}

// ---------------- LDS-tiled coalesced transpose + cast to fp8 --------------
// Wt[n][k] = e4m3(W[k][n] * scale). 32x32 tile, 256 thr (32x8).
__global__ __launch_bounds__(256) void transpose_f8(
    const float* __restrict__ W, char* __restrict__ Wt,
    int K, int Nsrc, float scale)
{
  __shared__ float t[32][33];
  const int nkt = K >> 5;
  const int k0 = (blockIdx.x % nkt) * 32;
  const int n0 = (blockIdx.x / nkt) * 32;
  const int tx = threadIdx.x & 31, ty = threadIdx.x >> 5;
#pragma unroll
  for (int i = ty; i < 32; i += 8) {
    const int n = n0 + tx;
    t[i][tx] = (n < Nsrc) ? W[(size_t)(k0 + i) * Nsrc + n] * scale : 0.f;
  }
  __syncthreads();
#pragma unroll
  for (int i = ty; i < 32; i += 8) {
    const int n = n0 + i;
    uint32_t pk = __builtin_amdgcn_cvt_pk_fp8_f32(t[tx][i], 0.f, 0, false);
    Wt[(size_t)n * K + k0 + tx] = (char)(pk & 0xff);
  }
}

__global__ void pad_bias(const float* __restrict__ src, float* __restrict__ dst,
                         int nReal, int nPad) {
  int i = blockIdx.x * 256 + threadIdx.x;
  if (i < nPad) dst[i] = (i < nReal) ? src[i] : 0.f;
}

// ---------------- LayerNorm, 1 wave/row, fp8 e4m3 out ----------------------
__global__ __launch_bounds__(256) void ln_wave(const float* __restrict__ x,
                                               const float* __restrict__ w,
                                               const float* __restrict__ b,
                                               char* __restrict__ y) {
  const int row  = blockIdx.x * 4 + (threadIdx.x >> 6);
  const int lane = threadIdx.x & 63;
  const float4* xr = (const float4*)(x + (size_t)row * CDIM);
  float4 v[3];
  v[0] = xr[lane]; v[1] = xr[lane + 64]; v[2] = xr[lane + 128];
  float s1 = 0.f, s2 = 0.f;
#pragma unroll
  for (int i = 0; i < 3; ++i) {
    s1 += v[i].x + v[i].y + v[i].z + v[i].w;
    s2 += v[i].x*v[i].x + v[i].y*v[i].y + v[i].z*v[i].z + v[i].w*v[i].w;
  }
#pragma unroll
  for (int o = 32; o > 0; o >>= 1) { s1 += __shfl_xor(s1, o); s2 += __shfl_xor(s2, o); }
  const float mu = s1 * (1.f / CDIM);
  const float rs = rsqrtf(s2 * (1.f / CDIM) - mu * mu + 1e-6f);
#pragma unroll
  for (int i = 0; i < 3; ++i) {
    const float4 w4 = ((const float4*)w)[lane + i * 64];
    const float4 b4 = ((const float4*)b)[lane + i * 64];
    const float o0 = (v[i].x - mu) * rs * w4.x + b4.x;
    const float o1 = (v[i].y - mu) * rs * w4.y + b4.y;
    const float o2 = (v[i].z - mu) * rs * w4.z + b4.z;
    const float o3 = (v[i].w - mu) * rs * w4.w + b4.w;
    uint32_t pk = 0;
    pk = __builtin_amdgcn_cvt_pk_fp8_f32(o0, o1, pk, false);
    pk = __builtin_amdgcn_cvt_pk_fp8_f32(o2, o3, pk, true);
    ((uint32_t*)(y + (size_t)row * CDIM))[lane + i * 64] = pk;
  }
}

// ======== 128x128 MX-scaled fp8 GEMM: 32x32x64, 4-buf counted pipeline ======
// C = A[M][K](e4m3) * Wt[N][K](e4m3)^T. Unity e8m0 scales (0x7F) = exact fp8.
// 256 thr = 4 waves (2M x 2N), per-wave 64x64 = 2x2 of 32x32.
// LDS: 4 bufs x 16 KB = 64 KB -> 2 blocks/CU. Stage 3 tiles ahead; one
// counted vmcnt(8)/tile (drains only in 2-tile tail). Chunk swizzle p^(r&3).
// Operand frag: lane l = row (l&31), k = (l>>5)*32 + e. C/D (m74/m101):
// col = lane&31, row = (reg&3)+8*(reg>>2)+4*(lane>>5)  [verified in-situ R11].
// MODE 0: fp8 head-major value store [n*NHD+head][LIN][64].
// MODE 1: f32 row-major, out = acc*oscale + bias.
// MODE 2: f32 row-major, out = resid + gamma*(acc+bias).
template<int MODE>
__global__ __launch_bounds__(256, 2) void gemm_mx(
    const char* __restrict__ A, const char* __restrict__ Wt,
    const float* __restrict__ bias, void* __restrict__ Cout,
    int M, int N, int K, int nTN, float oscale,
    const float* __restrict__ resid, const float* __restrict__ gammav)
{
  __shared__ __align__(16) char lds[65536];   // 4 x 16 KiB

  int bid = blockIdx.x;
  const int nwg = gridDim.x;
  if ((nwg & 7) == 0) {                 // XCD-chunked swizzle (bijective)
    const int chunk = nwg >> 3;
    bid = (bid & 7) * chunk + (bid >> 3);
  }
  const int mt = bid / nTN, ntl = bid - mt * nTN;
  const int m0 = mt * 128, n0 = ntl * 128;
  const int tid  = threadIdx.x;
  const int lane = tid & 63, wid = tid >> 6;
  const int wm = wid >> 1, wn = wid & 1;          // 2x2 wave grid
  const int lr31 = lane & 31, lkb = lane >> 5;

  f32x16 acc[2][2] = {};

  auto stage = [&](int kt, int buf, int ab) {
    const char* srcM = ab ? Wt : A;
    const int base0 = ab ? n0 : m0;
    const int k0 = kt * 64;
    char* dst0 = lds + buf * 16384 + ab * 8192;
#pragma unroll
    for (int it = 0; it < 2; ++it) {
      const int i = it * 256 + tid;              // chunk 0..511
      const int r = i >> 2, p = i & 3;
      const int c = p ^ (r & 3);                 // source chunk (involution)
      const char* src = srcM + (size_t)(base0 + r) * K + k0 + c * 16;
      char* dst = dst0 + (it * 256 + wid * 64) * 16;   // + lane*16 by HW
      __builtin_amdgcn_global_load_lds(
          (const __attribute__((address_space(1))) uint32_t*)src,
          (__attribute__((address_space(3))) uint32_t*)dst, 16, 0, 0);
    }
  };
  auto rdop = [&](int buf, int ab, int row) -> i32x8 {
    const char* base = lds + buf * 16384 + ab * 8192 + row * 64;
    const int s = row & 3;
    const uint4 lo = *(const uint4*)(base + ((2 * lkb)     ^ s) * 16);
    const uint4 hi = *(const uint4*)(base + ((2 * lkb + 1) ^ s) * 16);
    return mk8(lo, hi);
  };

  const int nk = K >> 6;                          // 12 K-tiles
#pragma unroll
  for (int t0 = 0; t0 < 3; ++t0) { stage(t0, t0, 0); stage(t0, t0, 1); }
  asm volatile("s_waitcnt vmcnt(8)" ::: "memory");  // tile 0 ready
  __builtin_amdgcn_s_barrier();
  asm volatile("" ::: "memory");

  for (int t = 0; t < nk; ++t) {
    const int cur = t & 3;
    const i32x8 a0 = rdop(cur, 0, wm * 64 + lr31);
    const i32x8 a1 = rdop(cur, 0, wm * 64 + 32 + lr31);
    const i32x8 b0 = rdop(cur, 1, wn * 64 + lr31);
    const i32x8 b1 = rdop(cur, 1, wn * 64 + 32 + lr31);
    if (t + 3 < nk) { stage(t + 3, (t + 3) & 3, 0); stage(t + 3, (t + 3) & 3, 1); }
    __builtin_amdgcn_s_setprio(1);
    acc[0][0] = __builtin_amdgcn_mfma_scale_f32_32x32x64_f8f6f4(
        a0, b0, acc[0][0], 0, 0, 0, 0x7F7F7F7F, 0, 0x7F7F7F7F);
    acc[0][1] = __builtin_amdgcn_mfma_scale_f32_32x32x64_f8f6f4(
        a0, b1, acc[0][1], 0, 0, 0, 0x7F7F7F7F, 0, 0x7F7F7F7F);
    acc[1][0] = __builtin_amdgcn_mfma_scale_f32_32x32x64_f8f6f4(
        a1, b0, acc[1][0], 0, 0, 0, 0x7F7F7F7F, 0, 0x7F7F7F7F);
    acc[1][1] = __builtin_amdgcn_mfma_scale_f32_32x32x64_f8f6f4(
        a1, b1, acc[1][1], 0, 0, 0, 0x7F7F7F7F, 0, 0x7F7F7F7F);
    __builtin_amdgcn_s_setprio(0);
    if (t + 3 < nk)      asm volatile("s_waitcnt vmcnt(8)" ::: "memory");
    else if (t + 2 < nk) asm volatile("s_waitcnt vmcnt(4)" ::: "memory");
    else if (t + 1 < nk) asm volatile("s_waitcnt vmcnt(0)" ::: "memory");
    __builtin_amdgcn_s_barrier();
    asm volatile("" ::: "memory");
  }

  // ---- epilogue ----
  if constexpr (MODE == 0) {
    // fp8 head-major value store via per-wave LDS staging
    const int head  = (n0 + wn * 64) >> 6;
    const int n_img = (unsigned)m0 / LIN;         // LIN%128==0: no crossing
    char* plane = (char*)Cout + ((size_t)(n_img * NHD + head) * LIN
                                 + (m0 - n_img * LIN)) * 64;
    float bcol[2];
#pragma unroll
    for (int nt2 = 0; nt2 < 2; ++nt2)
      bcol[nt2] = bias[n0 + wn * 64 + nt2 * 32 + lr31];
    float* my = (float*)(lds + wid * 16384);      // [32][68] f32 per wave
#pragma unroll
    for (int mt2 = 0; mt2 < 2; ++mt2) {
#pragma unroll
      for (int nt2 = 0; nt2 < 2; ++nt2)
#pragma unroll
        for (int reg = 0; reg < 16; ++reg) {
          const int row = (reg & 3) + 8 * (reg >> 2) + 4 * lkb;
          my[row * 68 + nt2 * 32 + lr31] = acc[mt2][nt2][reg] + bcol[nt2];
        }
#pragma unroll
      for (int it = 0; it < 2; ++it) {
        const int idx = it * 64 + lane;           // 0..127
        const int row = idx >> 2, seg = idx & 3;
        const float* s = my + row * 68 + seg * 16;
        uint32_t w[4];
#pragma unroll
        for (int q = 0; q < 4; ++q) {
          uint32_t pk = 0;
          pk = __builtin_amdgcn_cvt_pk_fp8_f32(s[q*4+0], s[q*4+1], pk, false);
          pk = __builtin_amdgcn_cvt_pk_fp8_f32(s[q*4+2], s[q*4+3], pk, true);
          w[q] = pk;
        }
        char* orow = plane + (size_t)(wm * 64 + mt2 * 32 + row) * 64 + seg * 16;
        *(uint4*)orow = *(uint4*)w;
      }
    }
  } else {
#pragma unroll
    for (int nt2 = 0; nt2 < 2; ++nt2) {
      const int col = n0 + wn * 64 + nt2 * 32 + lr31;
      const float bcol = bias[col];
      float gcol = 0.f;
      if constexpr (MODE == 2) gcol = gammav[col];
#pragma unroll
      for (int mt2 = 0; mt2 < 2; ++mt2)
#pragma unroll
        for (int reg = 0; reg < 16; ++reg) {
          const int row = m0 + wm * 64 + mt2 * 32
                        + (reg & 3) + 8 * (reg >> 2) + 4 * lkb;
          const size_t o = (size_t)row * N + col;
          if constexpr (MODE == 1)
            ((float*)Cout)[o] = acc[mt2][nt2][reg] * oscale + bcol;
          else
            ((float*)Cout)[o] = resid[o] + gcol * (acc[mt2][nt2][reg] + bcol);
        }
    }
  }
}

// ---------------- softmax over 12 + pack sampling params --------------------
__global__ void softmax_pack(const float* __restrict__ raw,
                             const float* __restrict__ refp,
                             float4* __restrict__ params) {
  const int t = blockIdx.x * 256 + threadIdx.x;       // [0, MQ*NHD)
  const int h = t % NHD, nq = t / NHD;
  const float* p = raw + (size_t)nq * CAT_N + AW_OFF + h * 12;
  float v[12], m = -1e30f;
#pragma unroll
  for (int j = 0; j < 12; ++j) { v[j] = p[j]; m = fmaxf(m, v[j]); }
  float s = 0.f;
#pragma unroll
  for (int j = 0; j < 12; ++j) { v[j] = __expf(v[j] - m); s += v[j]; }
  const float inv = 1.f / s;
  const float* op = raw + (size_t)nq * CAT_N + h * 24;
  const float* rp = refp + (size_t)nq * (NLVL * 2);
  float4* out = params + (size_t)t * 12;
  const float Wf[3] = {128.f, 64.f, 32.f};
#pragma unroll
  for (int l = 0; l < NLVL; ++l) {
    const float rxw = rp[2 * l] * Wf[l] - 0.5f;
    const float ryw = rp[2 * l + 1] * Wf[l] - 0.5f;
#pragma unroll
    for (int pt = 0; pt < NPT; ++pt) {
      float4 o4;
      o4.x = rxw + op[(l * 4 + pt) * 2 + 0];
      o4.y = ryw + op[(l * 4 + pt) * 2 + 1];
      o4.z = v[l * 4 + pt] * inv;
      o4.w = 0.f;
      out[l * 4 + pt] = o4;
    }
  }
}

// ------------- deformable sampling: 16 channels/lane, fp8 ------------------
__global__ __launch_bounds__(256) void deform_grp16(
    const char* __restrict__ vbytes, const float4* __restrict__ params,
    char* __restrict__ samp)
{
  const int j = blockIdx.x;                   // 3072 blocks
  const int x = j & 7, k = j >> 3;            // k in [0,384)
  const int g = x + ((k >> 6) << 3);          // plane, pinned to XCD x
  const int i = k & 63;                       // block within group
  const int n = g / NHD, h = g - n * NHD;
  const int wid = threadIdx.x >> 6, lane = threadIdx.x & 63;
  const int qi = lane >> 2, ci = lane & 3;
  const int q  = i * 64 + wid * 16 + qi;      // [0, 4096)
  const int nq = n * LQ + q;
  const float4* __restrict__ pp = params + ((size_t)nq * NHD + h) * 12;
  const uint32_t base0 = (uint32_t)g * (uint32_t)(LIN * 64)
                       + ((uint32_t)ci << 4);

  float acc[16];
#pragma unroll
  for (int c = 0; c < 16; ++c) acc[c] = 0.f;

  const int      Wl[3]  = {128, 64, 32};
  const uint32_t STb[3] = {0u, 16384u * 64u, 20480u * 64u};

#pragma unroll
  for (int l = 0; l < NLVL; ++l) {
    const int W_ = Wl[l];
    const uint32_t base = base0 + STb[l];
#pragma unroll
    for (int p = 0; p < NPT; ++p) {
      const float4 pt = pp[l * 4 + p];
      const float fx = floorf(pt.x), fy = floorf(pt.y);
      const float tx = pt.x - fx,   ty = pt.y - fy;
      const int x0 = (int)fx, y0 = (int)fy;
      const int x1 = x0 + 1,  y1 = y0 + 1;
      const float wx0 = ((uint32_t)x0 < (uint32_t)W_) ? (1.f - tx) : 0.f;
      const float wx1 = ((uint32_t)x1 < (uint32_t)W_) ? tx : 0.f;
      const float wy0 = ((uint32_t)y0 < (uint32_t)W_) ? pt.z * (1.f - ty) : 0.f;
      const float wy1 = ((uint32_t)y1 < (uint32_t)W_) ? pt.z * ty : 0.f;
      const int xc0 = min(max(x0, 0), W_ - 1);
      const int xc1 = min(max(x1, 0), W_ - 1);
      const int yr0 = min(max(y0, 0), W_ - 1) * W_;
      const int yr1 = min(max(y1, 0), W_ - 1) * W_;
      const float cw[4] = {wy0 * wx0, wy0 * wx1, wy1 * wx0, wy1 * wx1};
      const uint4 G0 = *(const uint4*)(vbytes + base + (uint32_t)(yr0 + xc0) * 64u);
      const uint4 G1 = *(const uint4*)(vbytes + base + (uint32_t)(yr0 + xc1) * 64u);
      const uint4 G2 = *(const uint4*)(vbytes + base + (uint32_t)(yr1 + xc0) * 64u);
      const uint4 G3 = *(const uint4*)(vbytes + base + (uint32_t)(yr1 + xc1) * 64u);
      const uint4 GG[4] = {G0, G1, G2, G3};
#pragma unroll
      for (int cnr = 0; cnr < 4; ++cnr) {
        const uint32_t wds[4] = {GG[cnr].x, GG[cnr].y, GG[cnr].z, GG[cnr].w};
        const float wgt = cw[cnr];
#pragma unroll
        for (int wd = 0; wd < 4; ++wd) {
          f32x2 lo = __builtin_amdgcn_cvt_pk_f32_fp8(wds[wd], false);
          f32x2 hi = __builtin_amdgcn_cvt_pk_f32_fp8(wds[wd], true);
          acc[wd * 4 + 0] += lo[0] * wgt;
          acc[wd * 4 + 1] += lo[1] * wgt;
          acc[wd * 4 + 2] += hi[0] * wgt;
          acc[wd * 4 + 3] += hi[1] * wgt;
        }
      }
    }
  }

  uint32_t out[4];
#pragma unroll
  for (int wd = 0; wd < 4; ++wd) {
    uint32_t pk = 0;
    pk = __builtin_amdgcn_cvt_pk_fp8_f32(acc[wd*4+0], acc[wd*4+1], pk, false);
    pk = __builtin_amdgcn_cvt_pk_fp8_f32(acc[wd*4+2], acc[wd*4+3], pk, true);
    out[wd] = pk;
  }
  *(uint4*)(samp + (size_t)nq * CDIM + h * HDIM + ci * 16) = *(uint4*)out;
}

// ---------------- host ------------------------------------------------------
extern "C" void kernel_launch(void* const* d_in, const int* in_sizes, int n_in,
                              void* d_out, int out_size, void* d_ws, size_t ws_size,
                              hipStream_t stream) {
  const float* query = (const float*)d_in[0];
  const float* refp  = (const float*)d_in[1];
  const float* feat  = (const float*)d_in[2];
  const float* qn_w  = (const float*)d_in[3];
  const float* qn_b  = (const float*)d_in[4];
  const float* fn_w  = (const float*)d_in[5];
  const float* fn_b  = (const float*)d_in[6];
  const float* gamma = (const float*)d_in[7];
  const float* so_w  = (const float*)d_in[8];
  const float* so_b  = (const float*)d_in[9];
  const float* aw_w  = (const float*)d_in[10];
  const float* aw_b  = (const float*)d_in[11];
  const float* vp_w  = (const float*)d_in[12];
  const float* vp_b  = (const float*)d_in[13];
  const float* op_w  = (const float*)d_in[14];
  const float* op_b  = (const float*)d_in[15];

  char* ws = (char*)d_ws;
  size_t off = 0;
  auto alloc = [&](size_t bytes) {
    char* p = ws + off;
    off = (off + bytes + 255) & ~(size_t)255;
    return p;
  };
  char*   q_f8   = (char*)alloc((size_t)MQ * CDIM);
  char*   val_f8 = (char*)alloc((size_t)MF * CDIM);        // [48][LIN][64] e4m3
  char*   vp_w8  = (char*)alloc((size_t)CDIM * CDIM);
  char*   op_w8  = (char*)alloc((size_t)CDIM * CDIM);
  char*   cat_w8 = (char*)alloc((size_t)CAT_N * CDIM);     // x16 pre-scaled
  float*  cat_bp = (float*)alloc(CAT_N * 4);

  // region R: f_f8 (phase A) aliases the phase-B buffers
  const size_t r = off;
  char* f_f8 = ws + r;
  const size_t f_end = r + (size_t)MF * CDIM;
  size_t o2 = r;
  float*  raw     = (float*)(ws + o2);  o2 += (size_t)MQ * CAT_N * 4;
  float4* params  = (float4*)(ws + o2); o2 += (size_t)MQ * NHD * 12 * 16;
  char*   samp8   = (char*)(ws + o2);   o2 += (size_t)MQ * CDIM;
  const size_t need = (f_end > o2) ? f_end : o2;
  if (ws_size < need) return;   // ~180 MB required

  // 1) weights -> fp8 transposed (so/aw pre-scaled x16 vs denormals)
  transpose_f8<<<24 * 24, 256, 0, stream>>>(vp_w, vp_w8, CDIM, CDIM, 1.f);
  transpose_f8<<<24 * 24, 256, 0, stream>>>(op_w, op_w8, CDIM, CDIM, 1.f);
  transpose_f8<<<24 * 9,  256, 0, stream>>>(so_w, cat_w8, CDIM, 288, WSCL);
  transpose_f8<<<24 * 7,  256, 0, stream>>>(
      aw_w, cat_w8 + (size_t)AW_OFF * CDIM, CDIM, 144, WSCL);
  pad_bias<<<2, 256, 0, stream>>>(so_b, cat_bp, 288, AW_OFF);
  pad_bias<<<1, 256, 0, stream>>>(aw_b, cat_bp + AW_OFF, 144, CAT_N - AW_OFF);

  // 2) layernorms (1 wave/row) -> fp8
  ln_wave<<<MQ / 4, 256, 0, stream>>>(query, qn_w, qn_b, q_f8);
  ln_wave<<<MF / 4, 256, 0, stream>>>(feat, fn_w, fn_b, f_f8);

  // 3) value = LN(feat) @ vp_w + vp_b   (MX 32x32x64, fp8 head-major out)
  gemm_mx<0><<<(MF / 128) * (CDIM / 128), 256, 0, stream>>>(
      f_f8, vp_w8, vp_b, val_f8, MF, CDIM, CDIM, CDIM / 128,
      1.f, nullptr, nullptr);

  // 4) fused so|aw GEMM (MX, f32 out, /16 descale)
  gemm_mx<1><<<(MQ / 128) * (CAT_N / 128), 256, 0, stream>>>(
      q_f8, cat_w8, cat_bp, raw, MQ, CAT_N, CDIM, CAT_N / 128,
      1.f / WSCL, nullptr, nullptr);

  // 5) softmax + pack {px,py,a} per (q,h,l,p)
  softmax_pack<<<(MQ * NHD) / 256, 256, 0, stream>>>(raw, refp, params);

  // 6) deformable sampling -> samp fp8 [MQ][768]  (16 ch/lane)
  deform_grp16<<<48 * 64, 256, 0, stream>>>(val_f8, params, samp8);

  // 7) out = query + gamma * (samp @ op_w + op_b)   (MX, fused f32 epilogue)
  gemm_mx<2><<<(MQ / 128) * (CDIM / 128), 256, 0, stream>>>(
      samp8, op_w8, op_b, (float*)d_out, MQ, CDIM, CDIM, CDIM / 128,
      1.f, query, gamma);
}

// Round 14
// 272.009 us; speedup vs baseline: 1.9075x; 1.1008x over previous
//
#include <hip/hip_runtime.h>
#include <hip/hip_bf16.h>
#include <stdint.h>

// ---------------- problem constants (fixed by setup_inputs) ----------------
#define NHD   12        // heads
#define NPT   4         // points
#define CDIM  768
#define HDIM  64
#define NLVL  3
#define LQ    4096
#define NB    4
#define LIN   21504     // 128*128 + 64*64 + 32*32
#define MQ    (NB*LQ)   // 16384 query rows
#define MF    (NB*LIN)  // 86016 feat rows
#define CAT_N 512       // fused so(288) | aw(144 real + pad)
#define AW_OFF 288
#define WSCL  16.f      // so/aw weight pre-scale (fp8 denormal avoidance)

typedef float  f32x4  __attribute__((ext_vector_type(4)));
typedef float  f32x2  __attribute__((ext_vector_type(2)));
typedef float  f32x16 __attribute__((ext_vector_type(16)));
typedef int    i32x8  __attribute__((ext_vector_type(8)));

__device__ __forceinline__ i32x8 mk8(uint4 lo, uint4 hi) {
  i32x8 v;
  v[0] = (int)lo.x; v[1] = (int)lo.y; v[2] = (int)lo.z; v[3] = (int)lo.w;
  v[4] = (int)hi.x; v[5] = (int)hi.y; v[6] = (int)hi.z; v[7] = (int)hi.w;
  return v;
}

// ------- merged weight prep: 4 transposes (fp8) + cat bias, 1 launch -------
// blocks [0,576): vp_w -> vp_w8 ; [576,1152): op_w -> op_w8 ;
// [1152,1368): so_w -> cat_w8 rows 0..287 (x16) ;
// [1368,1536): aw_w -> cat_w8 rows 288..511 (x16, zero-pad n>=144) ;
// block 1536: cat bias pack.
__global__ __launch_bounds__(256) void prep_weights(
    const float* __restrict__ vp_w, const float* __restrict__ op_w,
    const float* __restrict__ so_w, const float* __restrict__ aw_w,
    const float* __restrict__ so_b, const float* __restrict__ aw_b,
    char* __restrict__ vp_w8, char* __restrict__ op_w8,
    char* __restrict__ cat_w8, float* __restrict__ cat_bp)
{
  const int b = blockIdx.x;
  if (b == 1536) {
    const int i = threadIdx.x;
#pragma unroll
    for (int it = 0; it < 2; ++it) {
      const int idx = i + it * 256;
      float v = 0.f;
      if (idx < 288) v = so_b[idx];
      else if (idx < 432) v = aw_b[idx - AW_OFF];
      cat_bp[idx] = v;
    }
    return;
  }
  const float* W; char* Wt; int Nsrc, rowoff; float scale;
  int lb;
  if (b < 576)       { W = vp_w; Wt = vp_w8;  Nsrc = 768; rowoff = 0;   scale = 1.f;  lb = b; }
  else if (b < 1152) { W = op_w; Wt = op_w8;  Nsrc = 768; rowoff = 0;   scale = 1.f;  lb = b - 576; }
  else if (b < 1368) { W = so_w; Wt = cat_w8; Nsrc = 288; rowoff = 0;   scale = WSCL; lb = b - 1152; }
  else               { W = aw_w; Wt = cat_w8; Nsrc = 144; rowoff = 288; scale = WSCL; lb = b - 1368; }

  __shared__ float t[32][33];
  const int k0 = (lb % 24) * 32;
  const int n0 = (lb / 24) * 32;
  const int tx = threadIdx.x & 31, ty = threadIdx.x >> 5;
#pragma unroll
  for (int i = ty; i < 32; i += 8) {
    const int n = n0 + tx;
    t[i][tx] = (n < Nsrc) ? W[(size_t)(k0 + i) * Nsrc + n] * scale : 0.f;
  }
  __syncthreads();
#pragma unroll
  for (int i = ty; i < 32; i += 8) {
    const int n = rowoff + n0 + i;
    uint32_t pk = __builtin_amdgcn_cvt_pk_fp8_f32(t[tx][i], 0.f, 0, false);
    Wt[(size_t)n * CDIM + k0 + tx] = (char)(pk & 0xff);
  }
}

// ---------------- LayerNorm, 1 wave/row, fp8 e4m3 out ----------------------
__global__ __launch_bounds__(256) void ln_wave(const float* __restrict__ x,
                                               const float* __restrict__ w,
                                               const float* __restrict__ b,
                                               char* __restrict__ y) {
  const int row  = blockIdx.x * 4 + (threadIdx.x >> 6);
  const int lane = threadIdx.x & 63;
  const float4* xr = (const float4*)(x + (size_t)row * CDIM);
  float4 v[3];
  v[0] = xr[lane]; v[1] = xr[lane + 64]; v[2] = xr[lane + 128];
  float s1 = 0.f, s2 = 0.f;
#pragma unroll
  for (int i = 0; i < 3; ++i) {
    s1 += v[i].x + v[i].y + v[i].z + v[i].w;
    s2 += v[i].x*v[i].x + v[i].y*v[i].y + v[i].z*v[i].z + v[i].w*v[i].w;
  }
#pragma unroll
  for (int o = 32; o > 0; o >>= 1) { s1 += __shfl_xor(s1, o); s2 += __shfl_xor(s2, o); }
  const float mu = s1 * (1.f / CDIM);
  const float rs = rsqrtf(s2 * (1.f / CDIM) - mu * mu + 1e-6f);
#pragma unroll
  for (int i = 0; i < 3; ++i) {
    const float4 w4 = ((const float4*)w)[lane + i * 64];
    const float4 b4 = ((const float4*)b)[lane + i * 64];
    const float o0 = (v[i].x - mu) * rs * w4.x + b4.x;
    const float o1 = (v[i].y - mu) * rs * w4.y + b4.y;
    const float o2 = (v[i].z - mu) * rs * w4.z + b4.z;
    const float o3 = (v[i].w - mu) * rs * w4.w + b4.w;
    uint32_t pk = 0;
    pk = __builtin_amdgcn_cvt_pk_fp8_f32(o0, o1, pk, false);
    pk = __builtin_amdgcn_cvt_pk_fp8_f32(o2, o3, pk, true);
    ((uint32_t*)(y + (size_t)row * CDIM))[lane + i * 64] = pk;
  }
}

// ======== 128x128 MX-scaled fp8 GEMM: 32x32x64, 3-buf counted pipeline ======
// C = A[M][K](e4m3) * Wt[N][K](e4m3)^T. Unity e8m0 scales (0x7F) = exact fp8.
// 256 thr = 4 waves (2M x 2N), per-wave 64x64 = 2x2 of 32x32.
// LDS: 3 bufs x 16 KB = 48 KB -> 3 blocks/CU. One tile = 4 global_load_lds
// per wave (vmcnt +4). COUNTING (R13 bug fixed): prologue stages tiles 0,1
// (8 outstanding) then vmcnt(4) => tile 0 landed. Iter t stages tile t+2
// (outstanding: t+1 (<=4) + t+2 (4)); end-of-iter vmcnt(4) => tile t+1
// landed, only t+2 in flight. Tail: vmcnt(0) at t=nk-2, nothing at nk-1.
// Chunk swizzle p^(r&3). Operand frag: lane l = row (l&31), k = (l>>5)*32+e.
// C/D: col = lane&31, row = (reg&3)+8*(reg>>2)+4*(lane>>5) [verified R11].
// MODE 0: fp8 head-major value store [n*NHD+head][LIN][64].
// MODE 1: f32 row-major, out = acc*oscale + bias.
// MODE 2: f32 row-major, out = resid + gamma*(acc+bias).
template<int MODE>
__global__ __launch_bounds__(256, 3) void gemm_mx(
    const char* __restrict__ A, const char* __restrict__ Wt,
    const float* __restrict__ bias, void* __restrict__ Cout,
    int M, int N, int K, int nTN, float oscale,
    const float* __restrict__ resid, const float* __restrict__ gammav)
{
  __shared__ __align__(16) char lds[49152];   // 3 x 16 KiB

  int bid = blockIdx.x;
  const int nwg = gridDim.x;
  if ((nwg & 7) == 0) {                 // XCD-chunked swizzle (bijective)
    const int chunk = nwg >> 3;
    bid = (bid & 7) * chunk + (bid >> 3);
  }
  const int mt = bid / nTN, ntl = bid - mt * nTN;
  const int m0 = mt * 128, n0 = ntl * 128;
  const int tid  = threadIdx.x;
  const int lane = tid & 63, wid = tid >> 6;
  const int wm = wid >> 1, wn = wid & 1;          // 2x2 wave grid
  const int lr31 = lane & 31, lkb = lane >> 5;

  f32x16 acc[2][2] = {};

  auto stage = [&](int kt, int buf, int ab) {
    const char* srcM = ab ? Wt : A;
    const int base0 = ab ? n0 : m0;
    const int k0 = kt * 64;
    char* dst0 = lds + buf * 16384 + ab * 8192;
#pragma unroll
    for (int it = 0; it < 2; ++it) {
      const int i = it * 256 + tid;              // chunk 0..511
      const int r = i >> 2, p = i & 3;
      const int c = p ^ (r & 3);                 // source chunk (involution)
      const char* src = srcM + (size_t)(base0 + r) * K + k0 + c * 16;
      char* dst = dst0 + (it * 256 + wid * 64) * 16;   // + lane*16 by HW
      __builtin_amdgcn_global_load_lds(
          (const __attribute__((address_space(1))) uint32_t*)src,
          (__attribute__((address_space(3))) uint32_t*)dst, 16, 0, 0);
    }
  };
  auto rdop = [&](int buf, int ab, int row) -> i32x8 {
    const char* base = lds + buf * 16384 + ab * 8192 + row * 64;
    const int s = row & 3;
    const uint4 lo = *(const uint4*)(base + ((2 * lkb)     ^ s) * 16);
    const uint4 hi = *(const uint4*)(base + ((2 * lkb + 1) ^ s) * 16);
    return mk8(lo, hi);
  };

  const int nk = K >> 6;                          // 12 K-tiles
  // prologue: stage tiles 0,1 into bufs 0,1 (8 outstanding)
  stage(0, 0, 0); stage(0, 0, 1);
  stage(1, 1, 0); stage(1, 1, 1);
  asm volatile("s_waitcnt vmcnt(4)" ::: "memory");  // tile 0 landed
  __builtin_amdgcn_s_barrier();
  asm volatile("" ::: "memory");

  for (int t = 0; t < nk; ++t) {
    const int cur = t % 3;
    const i32x8 a0 = rdop(cur, 0, wm * 64 + lr31);
    const i32x8 a1 = rdop(cur, 0, wm * 64 + 32 + lr31);
    const i32x8 b0 = rdop(cur, 1, wn * 64 + lr31);
    const i32x8 b1 = rdop(cur, 1, wn * 64 + 32 + lr31);
    if (t + 2 < nk) { const int tb = (t + 2) % 3; stage(t + 2, tb, 0); stage(t + 2, tb, 1); }
    __builtin_amdgcn_s_setprio(1);
    acc[0][0] = __builtin_amdgcn_mfma_scale_f32_32x32x64_f8f6f4(
        a0, b0, acc[0][0], 0, 0, 0, 0x7F7F7F7F, 0, 0x7F7F7F7F);
    acc[0][1] = __builtin_amdgcn_mfma_scale_f32_32x32x64_f8f6f4(
        a0, b1, acc[0][1], 0, 0, 0, 0x7F7F7F7F, 0, 0x7F7F7F7F);
    acc[1][0] = __builtin_amdgcn_mfma_scale_f32_32x32x64_f8f6f4(
        a1, b0, acc[1][0], 0, 0, 0, 0x7F7F7F7F, 0, 0x7F7F7F7F);
    acc[1][1] = __builtin_amdgcn_mfma_scale_f32_32x32x64_f8f6f4(
        a1, b1, acc[1][1], 0, 0, 0, 0x7F7F7F7F, 0, 0x7F7F7F7F);
    __builtin_amdgcn_s_setprio(0);
    if (t + 2 < nk)      asm volatile("s_waitcnt vmcnt(4)" ::: "memory"); // t+1 landed
    else if (t + 1 < nk) asm volatile("s_waitcnt vmcnt(0)" ::: "memory"); // tail drain
    __builtin_amdgcn_s_barrier();
    asm volatile("" ::: "memory");
  }

  // ---- epilogue ----
  if constexpr (MODE == 0) {
    // fp8 head-major value store via per-wave LDS staging ([32][68] f32)
    const int head  = (n0 + wn * 64) >> 6;
    const int n_img = (unsigned)m0 / LIN;         // LIN%128==0: no crossing
    char* plane = (char*)Cout + ((size_t)(n_img * NHD + head) * LIN
                                 + (m0 - n_img * LIN)) * 64;
    float bcol[2];
#pragma unroll
    for (int nt2 = 0; nt2 < 2; ++nt2)
      bcol[nt2] = bias[n0 + wn * 64 + nt2 * 32 + lr31];
    float* my = (float*)(lds + wid * 8704);       // 4 x 8704 = 34816 <= 48K
#pragma unroll
    for (int mt2 = 0; mt2 < 2; ++mt2) {
#pragma unroll
      for (int nt2 = 0; nt2 < 2; ++nt2)
#pragma unroll
        for (int reg = 0; reg < 16; ++reg) {
          const int row = (reg & 3) + 8 * (reg >> 2) + 4 * lkb;
          my[row * 68 + nt2 * 32 + lr31] = acc[mt2][nt2][reg] + bcol[nt2];
        }
#pragma unroll
      for (int it = 0; it < 2; ++it) {
        const int idx = it * 64 + lane;           // 0..127
        const int row = idx >> 2, seg = idx & 3;
        const float* s = my + row * 68 + seg * 16;
        uint32_t w[4];
#pragma unroll
        for (int q = 0; q < 4; ++q) {
          uint32_t pk = 0;
          pk = __builtin_amdgcn_cvt_pk_fp8_f32(s[q*4+0], s[q*4+1], pk, false);
          pk = __builtin_amdgcn_cvt_pk_fp8_f32(s[q*4+2], s[q*4+3], pk, true);
          w[q] = pk;
        }
        char* orow = plane + (size_t)(wm * 64 + mt2 * 32 + row) * 64 + seg * 16;
        *(uint4*)orow = *(uint4*)w;
      }
    }
  } else {
#pragma unroll
    for (int nt2 = 0; nt2 < 2; ++nt2) {
      const int col = n0 + wn * 64 + nt2 * 32 + lr31;
      const float bcol = bias[col];
      float gcol = 0.f;
      if constexpr (MODE == 2) gcol = gammav[col];
#pragma unroll
      for (int mt2 = 0; mt2 < 2; ++mt2)
#pragma unroll
        for (int reg = 0; reg < 16; ++reg) {
          const int row = m0 + wm * 64 + mt2 * 32
                        + (reg & 3) + 8 * (reg >> 2) + 4 * lkb;
          const size_t o = (size_t)row * N + col;
          if constexpr (MODE == 1)
            ((float*)Cout)[o] = acc[mt2][nt2][reg] * oscale + bcol;
          else
            ((float*)Cout)[o] = resid[o] + gcol * (acc[mt2][nt2][reg] + bcol);
        }
    }
  }
}

// ---------------- softmax over 12 + pack sampling params --------------------
__global__ void softmax_pack(const float* __restrict__ raw,
                             const float* __restrict__ refp,
                             float4* __restrict__ params) {
  const int t = blockIdx.x * 256 + threadIdx.x;       // [0, MQ*NHD)
  const int h = t % NHD, nq = t / NHD;
  const float* p = raw + (size_t)nq * CAT_N + AW_OFF + h * 12;
  float v[12], m = -1e30f;
#pragma unroll
  for (int j = 0; j < 12; ++j) { v[j] = p[j]; m = fmaxf(m, v[j]); }
  float s = 0.f;
#pragma unroll
  for (int j = 0; j < 12; ++j) { v[j] = __expf(v[j] - m); s += v[j]; }
  const float inv = 1.f / s;
  const float* op = raw + (size_t)nq * CAT_N + h * 24;
  const float* rp = refp + (size_t)nq * (NLVL * 2);
  float4* out = params + (size_t)t * 12;
  const float Wf[3] = {128.f, 64.f, 32.f};
#pragma unroll
  for (int l = 0; l < NLVL; ++l) {
    const float rxw = rp[2 * l] * Wf[l] - 0.5f;
    const float ryw = rp[2 * l + 1] * Wf[l] - 0.5f;
#pragma unroll
    for (int pt = 0; pt < NPT; ++pt) {
      float4 o4;
      o4.x = rxw + op[(l * 4 + pt) * 2 + 0];
      o4.y = ryw + op[(l * 4 + pt) * 2 + 1];
      o4.z = v[l * 4 + pt] * inv;
      o4.w = 0.f;
      out[l * 4 + pt] = o4;
    }
  }
}

// ------------- deformable sampling: 16 channels/lane, fp8 ------------------
__global__ __launch_bounds__(256) void deform_grp16(
    const char* __restrict__ vbytes, const float4* __restrict__ params,
    char* __restrict__ samp)
{
  const int j = blockIdx.x;                   // 3072 blocks
  const int x = j & 7, k = j >> 3;            // k in [0,384)
  const int g = x + ((k >> 6) << 3);          // plane, pinned to XCD x
  const int i = k & 63;                       // block within group
  const int n = g / NHD, h = g - n * NHD;
  const int wid = threadIdx.x >> 6, lane = threadIdx.x & 63;
  const int qi = lane >> 2, ci = lane & 3;
  const int q  = i * 64 + wid * 16 + qi;      // [0, 4096)
  const int nq = n * LQ + q;
  const float4* __restrict__ pp = params + ((size_t)nq * NHD + h) * 12;
  const uint32_t base0 = (uint32_t)g * (uint32_t)(LIN * 64)
                       + ((uint32_t)ci << 4);

  float acc[16];
#pragma unroll
  for (int c = 0; c < 16; ++c) acc[c] = 0.f;

  const int      Wl[3]  = {128, 64, 32};
  const uint32_t STb[3] = {0u, 16384u * 64u, 20480u * 64u};

#pragma unroll
  for (int l = 0; l < NLVL; ++l) {
    const int W_ = Wl[l];
    const uint32_t base = base0 + STb[l];
#pragma unroll
    for (int p = 0; p < NPT; ++p) {
      const float4 pt = pp[l * 4 + p];
      const float fx = floorf(pt.x), fy = floorf(pt.y);
      const float tx = pt.x - fx,   ty = pt.y - fy;
      const int x0 = (int)fx, y0 = (int)fy;
      const int x1 = x0 + 1,  y1 = y0 + 1;
      const float wx0 = ((uint32_t)x0 < (uint32_t)W_) ? (1.f - tx) : 0.f;
      const float wx1 = ((uint32_t)x1 < (uint32_t)W_) ? tx : 0.f;
      const float wy0 = ((uint32_t)y0 < (uint32_t)W_) ? pt.z * (1.f - ty) : 0.f;
      const float wy1 = ((uint32_t)y1 < (uint32_t)W_) ? pt.z * ty : 0.f;
      const int xc0 = min(max(x0, 0), W_ - 1);
      const int xc1 = min(max(x1, 0), W_ - 1);
      const int yr0 = min(max(y0, 0), W_ - 1) * W_;
      const int yr1 = min(max(y1, 0), W_ - 1) * W_;
      const float cw[4] = {wy0 * wx0, wy0 * wx1, wy1 * wx0, wy1 * wx1};
      const uint4 G0 = *(const uint4*)(vbytes + base + (uint32_t)(yr0 + xc0) * 64u);
      const uint4 G1 = *(const uint4*)(vbytes + base + (uint32_t)(yr0 + xc1) * 64u);
      const uint4 G2 = *(const uint4*)(vbytes + base + (uint32_t)(yr1 + xc0) * 64u);
      const uint4 G3 = *(const uint4*)(vbytes + base + (uint32_t)(yr1 + xc1) * 64u);
      const uint4 GG[4] = {G0, G1, G2, G3};
#pragma unroll
      for (int cnr = 0; cnr < 4; ++cnr) {
        const uint32_t wds[4] = {GG[cnr].x, GG[cnr].y, GG[cnr].z, GG[cnr].w};
        const float wgt = cw[cnr];
#pragma unroll
        for (int wd = 0; wd < 4; ++wd) {
          f32x2 lo = __builtin_amdgcn_cvt_pk_f32_fp8(wds[wd], false);
          f32x2 hi = __builtin_amdgcn_cvt_pk_f32_fp8(wds[wd], true);
          acc[wd * 4 + 0] += lo[0] * wgt;
          acc[wd * 4 + 1] += lo[1] * wgt;
          acc[wd * 4 + 2] += hi[0] * wgt;
          acc[wd * 4 + 3] += hi[1] * wgt;
        }
      }
    }
  }

  uint32_t out[4];
#pragma unroll
  for (int wd = 0; wd < 4; ++wd) {
    uint32_t pk = 0;
    pk = __builtin_amdgcn_cvt_pk_fp8_f32(acc[wd*4+0], acc[wd*4+1], pk, false);
    pk = __builtin_amdgcn_cvt_pk_fp8_f32(acc[wd*4+2], acc[wd*4+3], pk, true);
    out[wd] = pk;
  }
  *(uint4*)(samp + (size_t)nq * CDIM + h * HDIM + ci * 16) = *(uint4*)out;
}

// ---------------- host ------------------------------------------------------
extern "C" void kernel_launch(void* const* d_in, const int* in_sizes, int n_in,
                              void* d_out, int out_size, void* d_ws, size_t ws_size,
                              hipStream_t stream) {
  const float* query = (const float*)d_in[0];
  const float* refp  = (const float*)d_in[1];
  const float* feat  = (const float*)d_in[2];
  const float* qn_w  = (const float*)d_in[3];
  const float* qn_b  = (const float*)d_in[4];
  const float* fn_w  = (const float*)d_in[5];
  const float* fn_b  = (const float*)d_in[6];
  const float* gamma = (const float*)d_in[7];
  const float* so_w  = (const float*)d_in[8];
  const float* so_b  = (const float*)d_in[9];
  const float* aw_w  = (const float*)d_in[10];
  const float* aw_b  = (const float*)d_in[11];
  const float* vp_w  = (const float*)d_in[12];
  const float* vp_b  = (const float*)d_in[13];
  const float* op_w  = (const float*)d_in[14];
  const float* op_b  = (const float*)d_in[15];

  char* ws = (char*)d_ws;
  size_t off = 0;
  auto alloc = [&](size_t bytes) {
    char* p = ws + off;
    off = (off + bytes + 255) & ~(size_t)255;
    return p;
  };
  char*   q_f8   = (char*)alloc((size_t)MQ * CDIM);
  char*   val_f8 = (char*)alloc((size_t)MF * CDIM);        // [48][LIN][64] e4m3
  char*   vp_w8  = (char*)alloc((size_t)CDIM * CDIM);
  char*   op_w8  = (char*)alloc((size_t)CDIM * CDIM);
  char*   cat_w8 = (char*)alloc((size_t)CAT_N * CDIM);     // x16 pre-scaled
  float*  cat_bp = (float*)alloc(CAT_N * 4);

  // region R: f_f8 (phase A) aliases the phase-B buffers
  const size_t r = off;
  char* f_f8 = ws + r;
  const size_t f_end = r + (size_t)MF * CDIM;
  size_t o2 = r;
  float*  raw     = (float*)(ws + o2);  o2 += (size_t)MQ * CAT_N * 4;
  float4* params  = (float4*)(ws + o2); o2 += (size_t)MQ * NHD * 12 * 16;
  char*   samp8   = (char*)(ws + o2);   o2 += (size_t)MQ * CDIM;
  const size_t need = (f_end > o2) ? f_end : o2;
  if (ws_size < need) return;   // ~180 MB required

  // 1) all weight prep in one launch (4 fp8 transposes + cat bias)
  prep_weights<<<1537, 256, 0, stream>>>(vp_w, op_w, so_w, aw_w, so_b, aw_b,
                                         vp_w8, op_w8, cat_w8, cat_bp);

  // 2) layernorms (1 wave/row) -> fp8
  ln_wave<<<MQ / 4, 256, 0, stream>>>(query, qn_w, qn_b, q_f8);
  ln_wave<<<MF / 4, 256, 0, stream>>>(feat, fn_w, fn_b, f_f8);

  // 3) value = LN(feat) @ vp_w + vp_b   (MX 32x32x64, fp8 head-major out)
  gemm_mx<0><<<(MF / 128) * (CDIM / 128), 256, 0, stream>>>(
      f_f8, vp_w8, vp_b, val_f8, MF, CDIM, CDIM, CDIM / 128,
      1.f, nullptr, nullptr);

  // 4) fused so|aw GEMM (MX, f32 out, /16 descale)
  gemm_mx<1><<<(MQ / 128) * (CAT_N / 128), 256, 0, stream>>>(
      q_f8, cat_w8, cat_bp, raw, MQ, CAT_N, CDIM, CAT_N / 128,
      1.f / WSCL, nullptr, nullptr);

  // 5) softmax + pack {px,py,a} per (q,h,l,p)
  softmax_pack<<<(MQ * NHD) / 256, 256, 0, stream>>>(raw, refp, params);

  // 6) deformable sampling -> samp fp8 [MQ][768]  (16 ch/lane)
  deform_grp16<<<48 * 64, 256, 0, stream>>>(val_f8, params, samp8);

  // 7) out = query + gamma * (samp @ op_w + op_b)   (MX, fused f32 epilogue)
  gemm_mx<2><<<(MQ / 128) * (CDIM / 128), 256, 0, stream>>>(
      samp8, op_w8, op_b, (float*)d_out, MQ, CDIM, CDIM, CDIM / 128,
      1.f, query, gamma);
}